// Round 8
// baseline (598.721 us; speedup 1.0000x reference)
//
#include <hip/hip_runtime.h>

#define NN   51200
#define EE   819200
#define GG   256
#define NN2  102400
#define AA   204800
#define EE2  409600
#define DD   64
#define LL   5

// bucket CSR build
#define NB1  100
#define NB2  200
#define CAP1 10240
#define CAP2 3072

typedef __attribute__((ext_vector_type(8))) short bf16x8;
typedef __attribute__((ext_vector_type(4))) float f32x4;
typedef unsigned short ushort_t;

// ---------------- workspace layout (bytes) ----------------
#define OFF_H      ((size_t)0)          // emb h; post-GIN: yrel; then agg (layer-2 gather)
#define OFF_AGG    ((size_t)13107200)   // GIN: h ping-pong buffer B
#define OFF_H2     ((size_t)26214400)   // GIN: buffer A; layer-4 output = h2 (alive to kpoolg)
#define OFF_XP     ((size_t)39321600)   // rec1/rec2 during CSR build; later xp
#define OFF_REC1   OFF_XP                       // 100*10240*8 = 8,192,000
#define OFF_REC2   ((size_t)47513600)           // 200*3072*8  = 4,915,200 (ends 52,428,800)
#define OFF_PERM   ((size_t)60293120)   // perm (200KB) inside xp region; dead before kgather2 writes xp
#define OFF_YROOT  ((size_t)65536000)   // GIN bf16 weights during GIN; yroot after; then xp2 (26MB, ends at OFF_OFFS1)
#define OFF_OFFS1  ((size_t)91750400)
#define OFF_COL1   ((size_t)91955216)
#define OFF_OFFS2  ((size_t)95232016)
#define OFF_COL2   ((size_t)95641632)
#define OFF_CNT1   ((size_t)97280032)   // zeroed region starts here; bucketCnt[300] lives here
#define OFF_BBASE  ((size_t)97282080)   // bucketBase[300] (inside zeroed region, harmless)
#define OFF_CUR1   ((size_t)97484832)   // pstat2[5][32][128] during GIN (zeroed by memset)
#define OFF_STATS  ((size_t)98508832)   // dbin[64], dcur[64] (zeroed)
#define ZERO_BYTES ((size_t)1231360)
#define OFF_ISO    ((size_t)98511392)
#define OFF_M      ((size_t)98920992)   // graphconv bf16 weight frags (64KB, die before kpoolg); then mbuf
#define WS_NEEDED  ((size_t)99052064)

__device__ __forceinline__ int waveInclScan(int v, int lane) {
#pragma unroll
    for (int off = 1; off < 64; off <<= 1) {
        int t = __shfl_up(v, off, 64);
        if (lane >= off) v += t;
    }
    return v;
}

// ---------------- split-bf16 helpers ----------------
__device__ __forceinline__ void bsplit(float x, ushort_t& hi, ushort_t& lo) {
    union { float f; unsigned u; } a; a.f = x;
    unsigned hb = (a.u + 0x7FFFu + ((a.u >> 16) & 1u)) >> 16;   // RNE to bf16
    union { unsigned u; float f; } h; h.u = hb << 16;
    float r = x - h.f;
    union { float f; unsigned u; } b; b.f = r;
    unsigned lb = (b.u + 0x7FFFu + ((b.u >> 16) & 1u)) >> 16;
    hi = (ushort_t)hb; lo = (ushort_t)lb;
}

// ---------------- bucket build phase A: scatter edges by dst>>9 ----------------
__global__ __launch_bounds__(256) void kbA(const int* __restrict__ src1, const int* __restrict__ dst1,
                                           const int* __restrict__ ea,
                                           const int* __restrict__ src2, const int* __restrict__ dst2,
                                           int* __restrict__ bucketCnt,
                                           int2* __restrict__ rec1, int2* __restrict__ rec2) {
    __shared__ int lhist[256];
    __shared__ int lbase[256];
    int tid = threadIdx.x, b = blockIdx.x;
    lhist[tid] = 0;
    __syncthreads();
    if (b < 400) {
        int i = (b * 256 + tid) * 8;
        int4 d0 = *(const int4*)(dst1 + i);
        int4 d1 = *(const int4*)(dst1 + i + 4);
        int dst[8] = {d0.x, d0.y, d0.z, d0.w, d1.x, d1.y, d1.z, d1.w};
        int bin[8], lr[8];
#pragma unroll
        for (int j = 0; j < 8; ++j) {
            bin[j] = dst[j] >> 9;
            lr[j] = atomicAdd(&lhist[bin[j]], 1);
        }
        __syncthreads();
        if (tid < NB1) {
            int c = lhist[tid];
            lbase[tid] = c ? atomicAdd(&bucketCnt[tid], c) : 0;
        }
        __syncthreads();
        int4 s0 = *(const int4*)(src1 + i);
        int4 s1 = *(const int4*)(src1 + i + 4);
        int src[8] = {s0.x, s0.y, s0.z, s0.w, s1.x, s1.y, s1.z, s1.w};
        int4 e0 = *(const int4*)(ea + 2 * i);
        int4 e1 = *(const int4*)(ea + 2 * i + 4);
        int4 e2 = *(const int4*)(ea + 2 * i + 8);
        int4 e3 = *(const int4*)(ea + 2 * i + 12);
        int code[8] = {e0.x * 3 + e0.y, e0.z * 3 + e0.w, e1.x * 3 + e1.y, e1.z * 3 + e1.w,
                       e2.x * 3 + e2.y, e2.z * 3 + e2.w, e3.x * 3 + e3.y, e3.z * 3 + e3.w};
#pragma unroll
        for (int j = 0; j < 8; ++j) {
            int pos = bin[j] * CAP1 + lbase[bin[j]] + lr[j];
            rec1[pos] = make_int2(src[j] | (code[j] << 16), dst[j]);
        }
    } else {
        int i = ((b - 400) * 256 + tid) * 8;
        int4 d0 = *(const int4*)(dst2 + i);
        int4 d1 = *(const int4*)(dst2 + i + 4);
        int dst[8] = {d0.x, d0.y, d0.z, d0.w, d1.x, d1.y, d1.z, d1.w};
        int bin[8], lr[8];
#pragma unroll
        for (int j = 0; j < 8; ++j) {
            bin[j] = dst[j] >> 9;
            lr[j] = atomicAdd(&lhist[bin[j]], 1);
        }
        __syncthreads();
        if (tid < NB2) {
            int c = lhist[tid];
            lbase[tid] = c ? atomicAdd(&bucketCnt[NB1 + tid], c) : 0;
        }
        __syncthreads();
        int4 s0 = *(const int4*)(src2 + i);
        int4 s1 = *(const int4*)(src2 + i + 4);
        int src[8] = {s0.x, s0.y, s0.z, s0.w, s1.x, s1.y, s1.z, s1.w};
#pragma unroll
        for (int j = 0; j < 8; ++j) {
            int pos = bin[j] * CAP2 + lbase[bin[j]] + lr[j];
            rec2[pos] = make_int2(src[j], dst[j]);
        }
    }
}

// exclusive scan of bucket counts (block 0: g1's 100, block 1: g2's 200)
__global__ void kbscan(const int* __restrict__ bucketCnt, int* __restrict__ bucketBase) {
    __shared__ int wsum[4];
    int tid = threadIdx.x, lane = tid & 63, wid = tid >> 6;
    int nb = blockIdx.x ? NB2 : NB1;
    const int* cnt = bucketCnt + (blockIdx.x ? NB1 : 0);
    int* base = bucketBase + (blockIdx.x ? NB1 : 0);
    int v = (tid < nb) ? cnt[tid] : 0;
    int incl = waveInclScan(v, lane);
    if (lane == 63) wsum[wid] = incl;
    __syncthreads();
    int woff = 0;
#pragma unroll
    for (int w = 0; w < 3; ++w) woff += (w < wid) ? wsum[w] : 0;
    if (tid < nb) base[tid] = woff + incl - v;
}

// ---------------- bucket build phase B: per-bucket CSR (LDS hist + scan + place) ----------------
__global__ __launch_bounds__(256) void kbB(const int* __restrict__ bucketCnt,
                                           const int* __restrict__ bucketBase,
                                           const int2* __restrict__ rec1, const int2* __restrict__ rec2,
                                           int* __restrict__ offs1, int* __restrict__ col1,
                                           int* __restrict__ offs2, int* __restrict__ col2,
                                           int* __restrict__ dbin) {
    __shared__ int nh[512];
    __shared__ int ncur[512];
    __shared__ int wsum[4];
    __shared__ int dhist[64];
    int tid = threadIdx.x, b = blockIdx.x;
    bool g1 = b < NB1;
    const int2* rec = g1 ? (rec1 + (size_t)b * CAP1) : (rec2 + (size_t)(b - NB1) * CAP2);
    int cnt = bucketCnt[b];
    int base = bucketBase[b];
    int* offs = g1 ? offs1 : offs2;
    int* col = g1 ? col1 : col2;
    int nodeBase = g1 ? b * 512 : (b - NB1) * 512;
    nh[tid] = 0; nh[tid + 256] = 0;
    if (tid < 64) dhist[tid] = 0;
    __syncthreads();
    for (int e = tid; e < cnt; e += 256) {
        int2 r = rec[e];
        atomicAdd(&nh[r.y & 511], 1);
    }
    __syncthreads();
    int v0 = nh[2 * tid], v1 = nh[2 * tid + 1];
    int s = v0 + v1;
    int lane = tid & 63, wid = tid >> 6;
    int incl = waveInclScan(s, lane);
    if (lane == 63) wsum[wid] = incl;
    __syncthreads();
    int woff = 0;
#pragma unroll
    for (int w = 0; w < 3; ++w) woff += (w < wid) ? wsum[w] : 0;
    int excl = woff + incl - s;
    ncur[2 * tid] = excl;
    ncur[2 * tid + 1] = excl + v0;
    offs[nodeBase + 2 * tid] = base + excl;
    offs[nodeBase + 2 * tid + 1] = base + excl + v0;
    if (g1) {
        atomicAdd(&dhist[v0 < 63 ? v0 : 63], 1);
        atomicAdd(&dhist[v1 < 63 ? v1 : 63], 1);
    }
    __syncthreads();
    for (int e = tid; e < cnt; e += 256) {
        int2 r = rec[e];
        int node = r.y & 511;
        int slot = base + atomicAdd(&ncur[node], 1);
        col[slot] = r.x;
    }
    if (g1 && tid < 64 && dhist[tid]) atomicAdd(&dbin[tid], dhist[tid]);
    if (tid == 0) {
        if (b == NB1 - 1) offs1[NN] = EE;
        if (b == NB1 + NB2 - 1) offs2[NN2] = EE2;
    }
}

// ---------------- iso argmax: LDS-staged coalesced reads ----------------
__global__ __launch_bounds__(256) void kiso(const float* __restrict__ iso, int* __restrict__ isoIdx) {
    __shared__ float srow[256 * 36];
    int tid = threadIdx.x;
    int base = blockIdx.x * 256;
    const float4* g4p = (const float4*)(iso + (size_t)base * 36);
#pragma unroll
    for (int i = tid; i < 2304; i += 256) ((float4*)srow)[i] = g4p[i];
    __syncthreads();
    const float* r = srow + tid * 36;
    int best = 0;
#pragma unroll
    for (int k = 0; k < 36; ++k)
        if (r[k] > 0.5f) best = k;
    isoIdx[base + tid] = best;
}

// ---------------- prep: embedding (float4 x loads) + GIN weight prep + GraphConv weight prep ----------------
__global__ void kprepx(const float* __restrict__ x, const float* __restrict__ embW,
                       const float* __restrict__ embB, float* __restrict__ h,
                       const float* __restrict__ gW1, const float* __restrict__ gW2,
                       ushort_t* __restrict__ w1h, ushort_t* __restrict__ w1l,
                       ushort_t* __restrict__ w2h, ushort_t* __restrict__ w2l,
                       const float* __restrict__ i1rW, const float* __restrict__ i1tW,
                       const float* __restrict__ i2rW, const float* __restrict__ i2tW,
                       ushort_t* __restrict__ gcwh, ushort_t* __restrict__ gcwl) {
    int b = blockIdx.x;
    if (b < 12800) {
        int t = b * 256 + threadIdx.x;
        int n = t >> 6, d = t & 63;
        float acc = embB[d];
        const float4* xr4 = (const float4*)(x + (size_t)n * 40);
#pragma unroll
        for (int k4 = 0; k4 < 10; ++k4) {
            float4 xv = xr4[k4];
            acc = fmaf(xv.x, embW[(4 * k4 + 0) * 64 + d], acc);
            acc = fmaf(xv.y, embW[(4 * k4 + 1) * 64 + d], acc);
            acc = fmaf(xv.z, embW[(4 * k4 + 2) * 64 + d], acc);
            acc = fmaf(xv.w, embW[(4 * k4 + 3) * 64 + d], acc);
        }
        h[(size_t)n * 64 + d] = fmaxf(acc, 0.f);
    } else if (b < 12840) {
        int t = (b - 12800) * 256 + threadIdx.x;
        int lane = t & 63, frag = t >> 6;
        int c15 = lane & 15, q = lane >> 4;
        if (frag < 80) {
            int kt = frag & 1, nt = (frag >> 1) & 7, l = frag >> 4;
            const float* W = gW1 + l * 8192;
            ushort_t* oh = w1h + ((size_t)frag * 64 + lane) * 8;
            ushort_t* ol = w1l + ((size_t)frag * 64 + lane) * 8;
            int kb = kt * 32 + q * 8, colw = nt * 16 + c15;
#pragma unroll
            for (int j = 0; j < 8; ++j) {
                ushort_t hi, lo; bsplit(W[(kb + j) * 128 + colw], hi, lo);
                oh[j] = hi; ol[j] = lo;
            }
        } else if (frag < 160) {
            int f = frag - 80;
            int kt = f & 3, nt = (f >> 2) & 3, l = f >> 4;
            const float* W = gW2 + l * 8192;
            ushort_t* oh = w2h + ((size_t)f * 64 + lane) * 8;
            ushort_t* ol = w2l + ((size_t)f * 64 + lane) * 8;
            int kb = kt * 32 + q * 8, colw = nt * 16 + c15;
#pragma unroll
            for (int j = 0; j < 8; ++j) {
                ushort_t hi, lo; bsplit(W[(kb + j) * 64 + colw], hi, lo);
                oh[j] = hi; ol[j] = lo;
            }
        }
    } else {
        // GraphConv weight prep: 4 matrices x 8 frags (K=64, N=64)
        int t = (b - 12840) * 256 + threadIdx.x;   // 0..2047
        int lane = t & 63, frag = t >> 6;          // frag 0..31
        int c15 = lane & 15, q = lane >> 4;
        int m = frag >> 3, f = frag & 7;
        int kt = f & 1, nt = f >> 1;
        const float* W = (m == 0) ? i1rW : (m == 1) ? i1tW : (m == 2) ? i2rW : i2tW;
        ushort_t* oh = gcwh + (size_t)m * 4096 + ((size_t)f * 64 + lane) * 8;
        ushort_t* ol = gcwl + (size_t)m * 4096 + ((size_t)f * 64 + lane) * 8;
        int kb = kt * 32 + q * 8, colw = nt * 16 + c15;
#pragma unroll
        for (int j = 0; j < 8; ++j) {
            ushort_t hi, lo; bsplit(W[(kb + j) * 64 + colw], hi, lo);
            oh[j] = hi; ol[j] = lo;
        }
    }
}

// two-level counting-sort placement; dstart computed inline from dbin (ascending)
__global__ __launch_bounds__(256) void kdegplace(const int* __restrict__ offs,
                                                 const int* __restrict__ dbin,
                                                 int* __restrict__ dcur,
                                                 int* __restrict__ perm) {
    __shared__ int lhist[64];
    __shared__ int lbase[64];
    __shared__ int sdstart[64];
    int tid = threadIdx.x;
    if (tid < 64) {
        lhist[tid] = 0;
        int v = dbin[tid];
        int incl = waveInclScan(v, tid);
        sdstart[tid] = incl - v;
    }
    __syncthreads();
    int n = blockIdx.x * 256 + tid;
    int d = offs[n + 1] - offs[n]; d = d < 63 ? d : 63;
    int lr = atomicAdd(&lhist[d], 1);
    __syncthreads();
    if (tid < 64) {
        int c = lhist[tid];
        lbase[tid] = c ? atomicAdd(&dcur[tid], c) : 0;
    }
    __syncthreads();
    perm[sdstart[d] + lbase[d] + lr] = n;
}

// ---------------- fused GIN layer: gather(16 perm'd nodes) -> LDS -> MFMA MLP -> hout + stats ----
// FOLD_BN: previous layer's BN+ReLU applied per loaded row (free — kernel is L2-fill bound,
// VALUBusy only 37%); deletes the ktrans pass entirely.
template <int FOLD_BN>
__global__ __launch_bounds__(256) void kglayer(
    const float* __restrict__ hin, float* __restrict__ hout,
    const int* __restrict__ perm,
    const int* __restrict__ offs, const int* __restrict__ col,
    const float* __restrict__ e1, const float* __restrict__ e2,
    const ushort_t* __restrict__ w1h, const ushort_t* __restrict__ w1l,
    const ushort_t* __restrict__ w2h, const ushort_t* __restrict__ w2l,
    const float* __restrict__ b1, const float* __restrict__ b2,
    const float* __restrict__ pst, const float* __restrict__ gamma,
    const float* __restrict__ beta, float* __restrict__ pstout) {
    __shared__ float etab[13 * 64];
    __shared__ int sPerm[16];
    __shared__ float sstat[128];
    __shared__ float sMLP[16 * 132];   // sA stride-68 aliases front; sH stride-132
    float* sA = sMLP;
    float* sH = sMLP;
    int tid = threadIdx.x;
    if (tid < 16) sPerm[tid] = perm[blockIdx.x * 16 + tid];
    for (int idx = tid; idx < 13 * 64; idx += 256) {
        int ci = idx >> 6, dd = idx & 63;
        etab[idx] = e1[(ci / 3) * 64 + dd] + e2[(ci % 3) * 64 + dd];
    }
    if (FOLD_BN && tid < 128) {
        float s = 0.f;
        const float* p = pst + tid;
#pragma unroll
        for (int i = 0; i < 32; ++i) s += p[i * 128];
        sstat[tid] = s;
    }
    __syncthreads();
    int lane = tid & 63, wv = tid >> 6;
    int c15 = lane & 15, q = lane >> 4;

    float sc0 = 1.f, sc1 = 1.f, sc2 = 1.f, sc3 = 1.f;
    float sh0 = 0.f, sh1 = 0.f, sh2 = 0.f, sh3 = 0.f;
    if (FOLD_BN) {
        int ch = 4 * c15;
        float mu, var;
        mu = sstat[ch] * (1.f / NN); var = sstat[64 + ch] * (1.f / NN) - mu * mu;
        sc0 = gamma[ch] * rsqrtf(var + 1e-5f); sh0 = beta[ch] - mu * sc0;
        mu = sstat[ch + 1] * (1.f / NN); var = sstat[65 + ch] * (1.f / NN) - mu * mu;
        sc1 = gamma[ch + 1] * rsqrtf(var + 1e-5f); sh1 = beta[ch + 1] - mu * sc1;
        mu = sstat[ch + 2] * (1.f / NN); var = sstat[66 + ch] * (1.f / NN) - mu * mu;
        sc2 = gamma[ch + 2] * rsqrtf(var + 1e-5f); sh2 = beta[ch + 2] - mu * sc2;
        mu = sstat[ch + 3] * (1.f / NN); var = sstat[67 + ch] * (1.f / NN) - mu * mu;
        sc3 = gamma[ch + 3] * rsqrtf(var + 1e-5f); sh3 = beta[ch + 3] - mu * sc3;
    }

    // ---- gather node n into sA ----
    {
        int n = sPerm[wv * 4 + q];
        int s0 = offs[n], s1 = offs[n + 1];
        float4 sx = *(const float4*)(hin + (size_t)n * 64 + 4 * c15);
        float4 et = *(const float4*)(etab + 12 * 64 + 4 * c15);
        float x0 = sx.x, x1 = sx.y, x2 = sx.z, x3 = sx.w;
        if (FOLD_BN) {
            x0 = fmaxf(fmaf(x0, sc0, sh0), 0.f); x1 = fmaxf(fmaf(x1, sc1, sh1), 0.f);
            x2 = fmaxf(fmaf(x2, sc2, sh2), 0.f); x3 = fmaxf(fmaf(x3, sc3, sh3), 0.f);
        }
        float a0 = x0 + et.x, a1 = x1 + et.y, a2 = x2 + et.z, a3 = x3 + et.w;
        int deg = s1 - s0;
        if (deg > 0) {
            const int* cp = col + s0;
            int nfull = deg >> 3, rem = deg & 7;
            int vv[8];
#pragma unroll
            for (int j = 0; j < 8; ++j) {
                int idx = j < deg ? j : deg - 1;
                vv[j] = cp[idx];
            }
            for (int it = 0; it < nfull; ++it) {
                float4 xv[8], tv[8];
#pragma unroll
                for (int j = 0; j < 8; ++j) {
                    xv[j] = *(const float4*)(hin + (size_t)(vv[j] & 0xFFFF) * 64 + 4 * c15);
                    tv[j] = *(const float4*)(etab + (vv[j] >> 16) * 64 + 4 * c15);
                }
                int e8 = (it + 1) * 8;
                bool more = e8 < deg;
                int nx[8];
                if (more) {
#pragma unroll
                    for (int j = 0; j < 8; ++j) {
                        int idx = e8 + j; idx = idx < deg ? idx : deg - 1;
                        nx[j] = cp[idx];
                    }
                }
#pragma unroll
                for (int j = 0; j < 8; ++j) {
                    float y0 = xv[j].x, y1 = xv[j].y, y2 = xv[j].z, y3 = xv[j].w;
                    if (FOLD_BN) {
                        y0 = fmaxf(fmaf(y0, sc0, sh0), 0.f);
                        y1 = fmaxf(fmaf(y1, sc1, sh1), 0.f);
                        y2 = fmaxf(fmaf(y2, sc2, sh2), 0.f);
                        y3 = fmaxf(fmaf(y3, sc3, sh3), 0.f);
                    }
                    a0 += y0 + tv[j].x;
                    a1 += y1 + tv[j].y;
                    a2 += y2 + tv[j].z;
                    a3 += y3 + tv[j].w;
                }
                if (more) {
#pragma unroll
                    for (int j = 0; j < 8; ++j) vv[j] = nx[j];
                }
            }
            if (rem) {
                float4 xv[8], tv[8];
#pragma unroll
                for (int j = 0; j < 8; ++j) {
                    xv[j] = *(const float4*)(hin + (size_t)(vv[j] & 0xFFFF) * 64 + 4 * c15);
                    tv[j] = *(const float4*)(etab + (vv[j] >> 16) * 64 + 4 * c15);
                }
#pragma unroll
                for (int j = 0; j < 8; ++j) {
                    float mm = (j < rem) ? 1.f : 0.f;
                    float y0 = xv[j].x, y1 = xv[j].y, y2 = xv[j].z, y3 = xv[j].w;
                    if (FOLD_BN) {
                        y0 = fmaxf(fmaf(y0, sc0, sh0), 0.f);
                        y1 = fmaxf(fmaf(y1, sc1, sh1), 0.f);
                        y2 = fmaxf(fmaf(y2, sc2, sh2), 0.f);
                        y3 = fmaxf(fmaf(y3, sc3, sh3), 0.f);
                    }
                    a0 = fmaf(y0 + tv[j].x, mm, a0);
                    a1 = fmaf(y1 + tv[j].y, mm, a1);
                    a2 = fmaf(y2 + tv[j].z, mm, a2);
                    a3 = fmaf(y3 + tv[j].w, mm, a3);
                }
            }
        }
        *(float4*)(sA + (wv * 4 + q) * 68 + 4 * c15) = make_float4(a0, a1, a2, a3);
    }
    __syncthreads();

    // ---- A-frags to regs (sA dies after next sync; sH aliases) ----
    bf16x8 ah[2], al[2];
#pragma unroll
    for (int kt = 0; kt < 2; ++kt) {
        const float* p = sA + c15 * 68 + kt * 32 + q * 8;
        float4 x0 = *(const float4*)p;
        float4 x1 = *(const float4*)(p + 4);
        float xs[8] = {x0.x, x0.y, x0.z, x0.w, x1.x, x1.y, x1.z, x1.w};
#pragma unroll
        for (int j = 0; j < 8; ++j) {
            ushort_t hi, lo; bsplit(xs[j], hi, lo);
            ah[kt][j] = (short)hi; al[kt][j] = (short)lo;
        }
    }
    __syncthreads();

    // ---- GEMM1: nt = 2wv+j ----
    f32x4 acc1[2];
#pragma unroll
    for (int j = 0; j < 2; ++j) { f32x4 z = {0.f, 0.f, 0.f, 0.f}; acc1[j] = z; }
#pragma unroll
    for (int kt = 0; kt < 2; ++kt) {
#pragma unroll
        for (int j = 0; j < 2; ++j) {
            int nt = 2 * wv + j;
            size_t fo = ((size_t)((nt * 2 + kt) * 64 + lane)) * 8;
            bf16x8 bh = *(const bf16x8*)(w1h + fo);
            bf16x8 bl = *(const bf16x8*)(w1l + fo);
            acc1[j] = __builtin_amdgcn_mfma_f32_16x16x32_bf16(ah[kt], bh, acc1[j], 0, 0, 0);
            acc1[j] = __builtin_amdgcn_mfma_f32_16x16x32_bf16(al[kt], bh, acc1[j], 0, 0, 0);
            acc1[j] = __builtin_amdgcn_mfma_f32_16x16x32_bf16(ah[kt], bl, acc1[j], 0, 0, 0);
        }
    }
#pragma unroll
    for (int j = 0; j < 2; ++j) {
        int nt = 2 * wv + j;
        float bias = b1[nt * 16 + c15];
#pragma unroll
        for (int rg = 0; rg < 4; ++rg)
            sH[(4 * q + rg) * 132 + nt * 16 + c15] = fmaxf(acc1[j][rg] + bias, 0.f);
    }
    __syncthreads();

    // ---- GEMM2: nt = wv ----
    f32x4 acc2 = {0.f, 0.f, 0.f, 0.f};
#pragma unroll
    for (int kt = 0; kt < 4; ++kt) {
        const float* p = sH + c15 * 132 + kt * 32 + q * 8;
        float4 x0 = *(const float4*)p;
        float4 x1 = *(const float4*)(p + 4);
        float xs[8] = {x0.x, x0.y, x0.z, x0.w, x1.x, x1.y, x1.z, x1.w};
        bf16x8 a2h, a2l;
#pragma unroll
        for (int j = 0; j < 8; ++j) {
            ushort_t hi, lo; bsplit(xs[j], hi, lo);
            a2h[j] = (short)hi; a2l[j] = (short)lo;
        }
        size_t fo = ((size_t)((wv * 4 + kt) * 64 + lane)) * 8;
        bf16x8 bh = *(const bf16x8*)(w2h + fo);
        bf16x8 bl = *(const bf16x8*)(w2l + fo);
        acc2 = __builtin_amdgcn_mfma_f32_16x16x32_bf16(a2h, bh, acc2, 0, 0, 0);
        acc2 = __builtin_amdgcn_mfma_f32_16x16x32_bf16(a2l, bh, acc2, 0, 0, 0);
        acc2 = __builtin_amdgcn_mfma_f32_16x16x32_bf16(a2h, bl, acc2, 0, 0, 0);
    }
    {
        float bias = b2[wv * 16 + c15];
        float s = 0.f, s2 = 0.f;
#pragma unroll
        for (int rg = 0; rg < 4; ++rg) {
            float v = acc2[rg] + bias;
            hout[(size_t)sPerm[4 * q + rg] * 64 + wv * 16 + c15] = v;
            s += v; s2 += v * v;
        }
        s += __shfl_xor(s, 16, 64);  s += __shfl_xor(s, 32, 64);
        s2 += __shfl_xor(s2, 16, 64); s2 += __shfl_xor(s2, 32, 64);
        if (q == 0) {
            float* ps = pstout + (size_t)(blockIdx.x & 31) * 128;
            atomicAdd(&ps[wv * 16 + c15], s);
            atomicAdd(&ps[64 + wv * 16 + c15], s2);
        }
    }
}

// ---------------- GraphConv1 GEMMs via split-bf16 MFMA (writes yrel,yroot) ----------------
__global__ __launch_bounds__(256) void kgcmm1(const ushort_t* __restrict__ grh,
                                              const ushort_t* __restrict__ grl,
                                              const ushort_t* __restrict__ gth,
                                              const ushort_t* __restrict__ gtl,
                                              const float* __restrict__ WrelIso,
                                              const float* __restrict__ WrootIso,
                                              const int* __restrict__ isoIdx,
                                              float* __restrict__ Yrel,
                                              float* __restrict__ Yroot,
                                              const float* __restrict__ pst,
                                              const float* __restrict__ g4,
                                              const float* __restrict__ b4,
                                              const int* __restrict__ a0g,
                                              const float* __restrict__ h2src) {
    __shared__ float sX[64 * 68];
    __shared__ float sstat[128];
    __shared__ float sSC[64], sSH[64];
    int tid = threadIdx.x, blk = blockIdx.x;
    if (tid < 128) {
        float s = 0.f;
        const float* p = pst + tid;
#pragma unroll
        for (int i = 0; i < 32; ++i) s += p[i * 128];
        sstat[tid] = s;
    }
    __syncthreads();
    if (tid < 64) {
        float mu = sstat[tid] * (1.f / NN);
        float var = sstat[64 + tid] * (1.f / NN) - mu * mu;
        float sc = g4[tid] * rsqrtf(var + 1e-5f);
        sSC[tid] = sc;
        sSH[tid] = b4[tid] - mu * sc;
    }
    __syncthreads();
#pragma unroll
    for (int i = tid; i < 1024; i += 256) {
        int row = i >> 4, c = (i & 15) << 2;
        int grow = blk * 64 + row;
        int na = a0g[2 * grow], nb = a0g[2 * grow + 1];
        float4 va = *(const float4*)(h2src + (size_t)na * 64 + c);
        float4 vb = *(const float4*)(h2src + (size_t)nb * 64 + c);
        float4 v;
        v.x = 0.5f * (va.x + vb.x); v.y = 0.5f * (va.y + vb.y);
        v.z = 0.5f * (va.z + vb.z); v.w = 0.5f * (va.w + vb.w);
        v.x = fmaf(v.x, sSC[c], sSH[c]);
        v.y = fmaf(v.y, sSC[c + 1], sSH[c + 1]);
        v.z = fmaf(v.z, sSC[c + 2], sSH[c + 2]);
        v.w = fmaf(v.w, sSC[c + 3], sSH[c + 3]);
        float* p = sX + row * 68 + c;
        p[0] = v.x; p[1] = v.y; p[2] = v.z; p[3] = v.w;
    }
    __syncthreads();
    int lane = tid & 63, wv = tid >> 6;
    int c15 = lane & 15, q = lane >> 4;

    bf16x8 ah[2], al[2];
#pragma unroll
    for (int kt = 0; kt < 2; ++kt) {
        const float* p = sX + (16 * wv + c15) * 68 + kt * 32 + q * 8;
        float4 x0 = *(const float4*)p;
        float4 x1 = *(const float4*)(p + 4);
        float xs[8] = {x0.x, x0.y, x0.z, x0.w, x1.x, x1.y, x1.z, x1.w};
#pragma unroll
        for (int j = 0; j < 8; ++j) {
            ushort_t hi, lo; bsplit(xs[j], hi, lo);
            ah[kt][j] = (short)hi; al[kt][j] = (short)lo;
        }
    }

    f32x4 accR[4], accT[4];
#pragma unroll
    for (int nt = 0; nt < 4; ++nt) {
        f32x4 z = {0.f, 0.f, 0.f, 0.f};
        accR[nt] = z; accT[nt] = z;
    }
#pragma unroll
    for (int nt = 0; nt < 4; ++nt) {
#pragma unroll
        for (int kt = 0; kt < 2; ++kt) {
            size_t fo = ((size_t)((nt * 2 + kt) * 64 + lane)) * 8;
            bf16x8 bh = *(const bf16x8*)(grh + fo);
            bf16x8 bl = *(const bf16x8*)(grl + fo);
            accR[nt] = __builtin_amdgcn_mfma_f32_16x16x32_bf16(ah[kt], bh, accR[nt], 0, 0, 0);
            accR[nt] = __builtin_amdgcn_mfma_f32_16x16x32_bf16(al[kt], bh, accR[nt], 0, 0, 0);
            accR[nt] = __builtin_amdgcn_mfma_f32_16x16x32_bf16(ah[kt], bl, accR[nt], 0, 0, 0);
            bf16x8 ch = *(const bf16x8*)(gth + fo);
            bf16x8 cl = *(const bf16x8*)(gtl + fo);
            accT[nt] = __builtin_amdgcn_mfma_f32_16x16x32_bf16(ah[kt], ch, accT[nt], 0, 0, 0);
            accT[nt] = __builtin_amdgcn_mfma_f32_16x16x32_bf16(al[kt], ch, accT[nt], 0, 0, 0);
            accT[nt] = __builtin_amdgcn_mfma_f32_16x16x32_bf16(ah[kt], cl, accT[nt], 0, 0, 0);
        }
    }

    int rbase = blk * 64 + 16 * wv + 4 * q;
#pragma unroll
    for (int rg = 0; rg < 4; ++rg) {
        int row = rbase + rg;
        int ii = isoIdx[row];
        float* yr = Yrel + (size_t)row * 64;
        float* yt = Yroot + (size_t)row * 64;
        const float* er = WrelIso + (size_t)ii * 64;
        const float* et = WrootIso + (size_t)ii * 64;
#pragma unroll
        for (int nt = 0; nt < 4; ++nt) {
            int cc = nt * 16 + c15;
            yr[cc] = accR[nt][rg] + er[cc];
            yt[cc] = accT[nt][rg] + et[cc];
        }
    }
}

// ---------------- GraphConv2 fused: OUT = relu(AGG @ Wrel + brel + XP @ Wroot) ----------------
__global__ __launch_bounds__(256) void kgcmm2(const float* __restrict__ AGG,
                                              const float* __restrict__ XP,
                                              const ushort_t* __restrict__ grh,
                                              const ushort_t* __restrict__ grl,
                                              const ushort_t* __restrict__ gth,
                                              const ushort_t* __restrict__ gtl,
                                              const float* __restrict__ brel,
                                              float* __restrict__ OUT) {
    __shared__ float sA[64 * 68];
    __shared__ float sB[64 * 68];
    int tid = threadIdx.x, blk = blockIdx.x;
#pragma unroll
    for (int i = tid; i < 1024; i += 256) {
        int row = i >> 4, c = (i & 15) << 2;
        float4 va = ((const float4*)(AGG + (size_t)blk * 4096))[i];
        float4 vb = ((const float4*)(XP + (size_t)blk * 4096))[i];
        float* pa = sA + row * 68 + c;
        float* pb = sB + row * 68 + c;
        pa[0] = va.x; pa[1] = va.y; pa[2] = va.z; pa[3] = va.w;
        pb[0] = vb.x; pb[1] = vb.y; pb[2] = vb.z; pb[3] = vb.w;
    }
    __syncthreads();
    int lane = tid & 63, wv = tid >> 6;
    int c15 = lane & 15, q = lane >> 4;

    bf16x8 aAh[2], aAl[2], aBh[2], aBl[2];
#pragma unroll
    for (int kt = 0; kt < 2; ++kt) {
        const float* pa = sA + (16 * wv + c15) * 68 + kt * 32 + q * 8;
        const float* pb = sB + (16 * wv + c15) * 68 + kt * 32 + q * 8;
        float4 a0 = *(const float4*)pa;
        float4 a1 = *(const float4*)(pa + 4);
        float4 b0 = *(const float4*)pb;
        float4 b1 = *(const float4*)(pb + 4);
        float as[8] = {a0.x, a0.y, a0.z, a0.w, a1.x, a1.y, a1.z, a1.w};
        float bs[8] = {b0.x, b0.y, b0.z, b0.w, b1.x, b1.y, b1.z, b1.w};
#pragma unroll
        for (int j = 0; j < 8; ++j) {
            ushort_t hi, lo;
            bsplit(as[j], hi, lo); aAh[kt][j] = (short)hi; aAl[kt][j] = (short)lo;
            bsplit(bs[j], hi, lo); aBh[kt][j] = (short)hi; aBl[kt][j] = (short)lo;
        }
    }

    f32x4 acc[4];
#pragma unroll
    for (int nt = 0; nt < 4; ++nt) { f32x4 z = {0.f, 0.f, 0.f, 0.f}; acc[nt] = z; }
#pragma unroll
    for (int nt = 0; nt < 4; ++nt) {
#pragma unroll
        for (int kt = 0; kt < 2; ++kt) {
            size_t fo = ((size_t)((nt * 2 + kt) * 64 + lane)) * 8;
            bf16x8 bh = *(const bf16x8*)(grh + fo);
            bf16x8 bl = *(const bf16x8*)(grl + fo);
            acc[nt] = __builtin_amdgcn_mfma_f32_16x16x32_bf16(aAh[kt], bh, acc[nt], 0, 0, 0);
            acc[nt] = __builtin_amdgcn_mfma_f32_16x16x32_bf16(aAl[kt], bh, acc[nt], 0, 0, 0);
            acc[nt] = __builtin_amdgcn_mfma_f32_16x16x32_bf16(aAh[kt], bl, acc[nt], 0, 0, 0);
            bf16x8 ch = *(const bf16x8*)(gth + fo);
            bf16x8 cl = *(const bf16x8*)(gtl + fo);
            acc[nt] = __builtin_amdgcn_mfma_f32_16x16x32_bf16(aBh[kt], ch, acc[nt], 0, 0, 0);
            acc[nt] = __builtin_amdgcn_mfma_f32_16x16x32_bf16(aBl[kt], ch, acc[nt], 0, 0, 0);
            acc[nt] = __builtin_amdgcn_mfma_f32_16x16x32_bf16(aBh[kt], cl, acc[nt], 0, 0, 0);
        }
    }

    int rbase = blk * 64 + 16 * wv + 4 * q;
#pragma unroll
    for (int rg = 0; rg < 4; ++rg) {
        int row = rbase + rg;
        float* yo = OUT + (size_t)row * 64;
#pragma unroll
        for (int nt = 0; nt < 4; ++nt) {
            int cc = nt * 16 + c15;
            yo[cc] = fmaxf(acc[nt][rg] + brel[cc], 0.f);
        }
    }
}

// ---------------- GraphConv gather layer1: root+bias+relu (reads yrel/yroot) ----------------
__global__ void kgather2(const float* __restrict__ yrel, const float* __restrict__ yroot,
                         const float* __restrict__ brel, const int* __restrict__ offs,
                         const int* __restrict__ col, float* __restrict__ out) {
    int t = blockIdx.x * 256 + threadIdx.x;
    int j = t >> 4, c = t & 15;
    int s0 = offs[j], s1 = offs[j + 1];
    float4 rt = *(const float4*)(yroot + (size_t)j * 64 + 4 * c);
    float4 bb = *(const float4*)(brel + 4 * c);
    float a0 = rt.x + bb.x, a1 = rt.y + bb.y, a2 = rt.z + bb.z, a3 = rt.w + bb.w;
    if (s0 < s1) {
        int vv[4];
#pragma unroll
        for (int jj = 0; jj < 4; ++jj) {
            int idx = s0 + jj; idx = idx < s1 ? idx : s1 - 1;
            vv[jj] = col[idx];
        }
        int e = s0;
        while (true) {
            int ne = e + 4;
            bool more = ne < s1;
            float4 xs[4];
#pragma unroll
            for (int jj = 0; jj < 4; ++jj)
                xs[jj] = *(const float4*)(yrel + (size_t)vv[jj] * 64 + 4 * c);
            int nx[4];
            if (more) {
#pragma unroll
                for (int jj = 0; jj < 4; ++jj) {
                    int idx = ne + jj; idx = idx < s1 ? idx : s1 - 1;
                    nx[jj] = col[idx];
                }
            }
#pragma unroll
            for (int jj = 0; jj < 4; ++jj) {
                float mm = (e + jj < s1) ? 1.f : 0.f;
                a0 = fmaf(xs[jj].x, mm, a0);
                a1 = fmaf(xs[jj].y, mm, a1);
                a2 = fmaf(xs[jj].z, mm, a2);
                a3 = fmaf(xs[jj].w, mm, a3);
            }
            if (!more) break;
            e = ne;
#pragma unroll
            for (int jj = 0; jj < 4; ++jj) vv[jj] = nx[jj];
        }
    }
    *(float4*)(out + (size_t)j * 64 + 4 * c) =
        make_float4(fmaxf(a0, 0.f), fmaxf(a1, 0.f), fmaxf(a2, 0.f), fmaxf(a3, 0.f));
}

// ---------------- GraphConv gather layer2: raw neighbor sums only ----------------
__global__ void kgather2raw(const float* __restrict__ xpsrc, const int* __restrict__ offs,
                            const int* __restrict__ col, float* __restrict__ agg) {
    int t = blockIdx.x * 256 + threadIdx.x;
    int j = t >> 4, c = t & 15;
    int s0 = offs[j], s1 = offs[j + 1];
    float a0 = 0.f, a1 = 0.f, a2 = 0.f, a3 = 0.f;
    if (s0 < s1) {
        int vv[4];
#pragma unroll
        for (int jj = 0; jj < 4; ++jj) {
            int idx = s0 + jj; idx = idx < s1 ? idx : s1 - 1;
            vv[jj] = col[idx];
        }
        int e = s0;
        while (true) {
            int ne = e + 4;
            bool more = ne < s1;
            float4 xs[4];
#pragma unroll
            for (int jj = 0; jj < 4; ++jj)
                xs[jj] = *(const float4*)(xpsrc + (size_t)vv[jj] * 64 + 4 * c);
            int nx[4];
            if (more) {
#pragma unroll
                for (int jj = 0; jj < 4; ++jj) {
                    int idx = ne + jj; idx = idx < s1 ? idx : s1 - 1;
                    nx[jj] = col[idx];
                }
            }
#pragma unroll
            for (int jj = 0; jj < 4; ++jj) {
                float mm = (e + jj < s1) ? 1.f : 0.f;
                a0 = fmaf(xs[jj].x, mm, a0);
                a1 = fmaf(xs[jj].y, mm, a1);
                a2 = fmaf(xs[jj].z, mm, a2);
                a3 = fmaf(xs[jj].w, mm, a3);
            }
            if (!more) break;
            e = ne;
#pragma unroll
            for (int jj = 0; jj < 4; ++jj) vv[jj] = nx[jj];
        }
    }
    *(float4*)(agg + (size_t)j * 64 + 4 * c) = make_float4(a0, a1, a2, a3);
}

// ---------------- per-graph mean pools (x1 gets final BN affine on the mean) ----------------
__global__ void kpoolg(const float* __restrict__ h2, const float* __restrict__ xp2,
                       const float* __restrict__ pst, const float* __restrict__ g4,
                       const float* __restrict__ b4, float* __restrict__ m) {
    __shared__ float sstat[128];
    __shared__ float red[4][64];
    int g = blockIdx.x, tid = threadIdx.x;
    if (tid < 128) {
        float s = 0.f;
        const float* p = pst + tid;
#pragma unroll
        for (int i = 0; i < 32; ++i) s += p[i * 128];
        sstat[tid] = s;
    }
    int wid = tid >> 6, d = tid & 63;
    float s1 = 0.f;
    for (int i = wid; i < 200; i += 4) s1 += h2[((size_t)g * 200 + i) * 64 + d];
    red[wid][d] = s1;
    __syncthreads();
    if (wid == 0) {
        float mean = (red[0][d] + red[1][d] + red[2][d] + red[3][d]) * (1.f / 200.f);
        float mu = sstat[d] * (1.f / NN);
        float var = sstat[64 + d] * (1.f / NN) - mu * mu;
        float sc = g4[d] * rsqrtf(var + 1e-5f);
        m[g * 128 + d] = fmaf(mean, sc, b4[d] - mu * sc);
    }
    __syncthreads();
    float s2 = 0.f;
    for (int i = wid; i < 400; i += 4) s2 += xp2[((size_t)g * 400 + i) * 64 + d];
    red[wid][d] = s2;
    __syncthreads();
    if (wid == 0) m[g * 128 + 64 + d] = (red[0][d] + red[1][d] + red[2][d] + red[3][d]) * (1.f / 400.f);
}

// ---------------- readout MLP ----------------
__global__ void kread(const float* __restrict__ m, const float* __restrict__ W0,
                      const float* __restrict__ b0, const float* __restrict__ W1,
                      const float* __restrict__ b1, const float* __restrict__ W2,
                      const float* __restrict__ b2, const float* __restrict__ lw,
                      const float* __restrict__ lb, float* __restrict__ out) {
    __shared__ float s0[64], s1[32], s2[16];
    int g = blockIdx.x, d = threadIdx.x;
    const float* mr = m + g * 128;
    float t = b0[d];
    for (int k = 0; k < 128; ++k) t = fmaf(mr[k], W0[k * 64 + d], t);
    s0[d] = fmaxf(t, 0.f);
    __syncthreads();
    if (d < 32) {
        float u = b1[d];
        for (int k = 0; k < 64; ++k) u = fmaf(s0[k], W1[k * 32 + d], u);
        s1[d] = fmaxf(u, 0.f);
    }
    __syncthreads();
    if (d < 16) {
        float u = b2[d];
        for (int k = 0; k < 32; ++k) u = fmaf(s1[k], W2[k * 16 + d], u);
        s2[d] = fmaxf(u, 0.f);
    }
    __syncthreads();
    if (d == 0) {
        float u = lb[0];
        for (int k = 0; k < 16; ++k) u = fmaf(s2[k], lw[k], u);
        out[g] = u;
    }
}

// ---------------- host ----------------
extern "C" void kernel_launch(void* const* d_in, const int* in_sizes, int n_in,
                              void* d_out, int out_size, void* d_ws, size_t ws_size,
                              hipStream_t stream) {
    if (ws_size < WS_NEEDED) return;

    const float* x    = (const float*)d_in[0];
    const int*   ei   = (const int*)d_in[1];
    const int*   ea   = (const int*)d_in[2];
    const float* iso  = (const float*)d_in[4];
    const int*   ei2  = (const int*)d_in[5];
    const int*   ai2  = (const int*)d_in[6];
    const float* embW = (const float*)d_in[8];
    const float* embB = (const float*)d_in[9];
    const float* gW1  = (const float*)d_in[10];
    const float* gB1  = (const float*)d_in[11];
    const float* gW2  = (const float*)d_in[12];
    const float* gB2  = (const float*)d_in[13];
    const float* ee1  = (const float*)d_in[14];
    const float* ee2  = (const float*)d_in[15];
    const float* bng  = (const float*)d_in[16];
    const float* bnb  = (const float*)d_in[17];
    const float* i1rW = (const float*)d_in[18];
    const float* i1rB = (const float*)d_in[19];
    const float* i1tW = (const float*)d_in[20];
    const float* i2rW = (const float*)d_in[21];
    const float* i2rB = (const float*)d_in[22];
    const float* i2tW = (const float*)d_in[23];
    const float* roW0 = (const float*)d_in[24];
    const float* roB0 = (const float*)d_in[25];
    const float* roW1 = (const float*)d_in[26];
    const float* roB1 = (const float*)d_in[27];
    const float* roW2 = (const float*)d_in[28];
    const float* roB2 = (const float*)d_in[29];
    const float* lW   = (const float*)d_in[30];
    const float* lB   = (const float*)d_in[31];
    float* out = (float*)d_out;

    char* ws = (char*)d_ws;
    float* h      = (float*)(ws + OFF_H);
    float* hB     = (float*)(ws + OFF_AGG);    // ping-pong buffer B
    float* hA     = (float*)(ws + OFF_H2);     // ping-pong buffer A; final h2
    float* h2     = hA;
    float* xp     = (float*)(ws + OFF_XP);
    float* yrel   = (float*)(ws + OFF_H);      // spans h+hB (both dead post-GIN); later agg
    float* yroot  = (float*)(ws + OFF_YROOT);
    float* aggb   = (float*)(ws + OFF_H);      // layer-2 raw gather output
    float* xp2    = (float*)(ws + OFF_YROOT);  // layer-2 final output (26MB, ends at OFF_OFFS1)
    int* offs1    = (int*)(ws + OFF_OFFS1);
    int* col1     = (int*)(ws + OFF_COL1);
    int* offs2    = (int*)(ws + OFF_OFFS2);
    int* col2     = (int*)(ws + OFF_COL2);
    int* isoIdx   = (int*)(ws + OFF_ISO);
    float* mbuf   = (float*)(ws + OFF_M);      // written by kpoolg AFTER gcw frags die
    ushort_t* w1h = (ushort_t*)(ws + OFF_YROOT);
    ushort_t* w1l = (ushort_t*)(ws + OFF_YROOT + 81920);
    ushort_t* w2h = (ushort_t*)(ws + OFF_YROOT + 163840);
    ushort_t* w2l = (ushort_t*)(ws + OFF_YROOT + 245760);
    ushort_t* gcwh = (ushort_t*)(ws + OFF_M);           // 4 matrices x 4096 ushorts
    ushort_t* gcwl = (ushort_t*)(ws + OFF_M + 32768);
    float* pstat2 = (float*)(ws + OFF_CUR1);   // zeroed by memset each launch
    int2* rec1    = (int2*)(ws + OFF_REC1);    // bucketed edge records (xp region; dead before xp writes)
    int2* rec2    = (int2*)(ws + OFF_REC2);
    int* bucketCnt  = (int*)(ws + OFF_CNT1);   // zeroed
    int* bucketBase = (int*)(ws + OFF_BBASE);
    int* perm     = (int*)(ws + OFF_PERM);     // inside xp span; dead before kgather2 writes xp
    int* dbin     = (int*)(ws + OFF_STATS);    // zeroed
    int* dcur     = dbin + 64;

    const int* src1 = ei;
    const int* dst1 = ei + EE;
    const int* src2 = ei2;
    const int* dst2 = ei2 + EE2;
    const int* a0   = ai2;

    hipMemsetAsync(ws + OFF_CNT1, 0, ZERO_BYTES, stream);

    // bucketed CSR build: LDS ranks + 90K global atomics
    kbA<<<600, 256, 0, stream>>>(src1, dst1, ea, src2, dst2, bucketCnt, rec1, rec2);
    kiso<<<NN2 / 256, 256, 0, stream>>>(iso, isoIdx);
    kprepx<<<12848, 256, 0, stream>>>(x, embW, embB, h, gW1, gW2,
                                      w1h, w1l, w2h, w2l,
                                      i1rW, i1tW, i2rW, i2tW, gcwh, gcwl);
    kbscan<<<2, 256, 0, stream>>>(bucketCnt, bucketBase);
    kbB<<<300, 256, 0, stream>>>(bucketCnt, bucketBase, rec1, rec2,
                                 offs1, col1, offs2, col2, dbin);
    kdegplace<<<NN / 256, 256, 0, stream>>>(offs1, dbin, dcur, perm);

    // GIN layers: fused gather+MLP with BN+ReLU folded into the gather (L2-fill bound -> free VALU);
    // h ping-pong (layer 4 lands in hA = h2, raw for the branch)
    for (int l = 0; l < LL; ++l) {
        const float* hin = (l == 0) ? h : ((l & 1) ? hA : hB);
        float* hout = (l & 1) ? hB : hA;
        if (l == 0) {
            kglayer<0><<<NN / 16, 256, 0, stream>>>(
                hin, hout, perm, offs1, col1, ee1, ee2,
                w1h, w1l, w2h, w2l, gB1, gB2,
                nullptr, nullptr, nullptr, pstat2);
        } else {
            kglayer<1><<<NN / 16, 256, 0, stream>>>(
                hin, hout, perm, offs1, col1, ee1 + l * 384, ee2 + l * 192,
                w1h + (size_t)l * 8192, w1l + (size_t)l * 8192,
                w2h + (size_t)l * 8192, w2l + (size_t)l * 8192,
                gB1 + l * 128, gB2 + l * 64,
                pstat2 + (size_t)(l - 1) * 4096,
                bng + (l - 1) * 64, bnb + (l - 1) * 64,
                pstat2 + (size_t)l * 4096);
        }
    }

    // 2-set branch, layer 1 (avg-pool + final-layer BN fused into kgcmm1 staging; MFMA GEMMs)
    kgcmm1<<<NN2 / 64, 256, 0, stream>>>(gcwh, gcwl, gcwh + 4096, gcwl + 4096,
                                         i1rW + 64 * 64, i1tW + 64 * 64, isoIdx,
                                         yrel, yroot,
                                         pstat2 + (size_t)4 * 4096,
                                         bng + 4 * 64, bnb + 4 * 64, a0, h2);
    kgather2<<<NN2 * 16 / 256, 256, 0, stream>>>(yrel, yroot, i1rB, offs2, col2, xp);
    // layer 2: gather-first (matches reference order), fused dual-GEMM single output
    kgather2raw<<<NN2 * 16 / 256, 256, 0, stream>>>(xp, offs2, col2, aggb);
    kgcmm2<<<NN2 / 64, 256, 0, stream>>>(aggb, xp,
                                         gcwh + 8192, gcwl + 8192, gcwh + 12288, gcwl + 12288,
                                         i2rB, xp2);

    // pools + readout
    kpoolg<<<GG, 256, 0, stream>>>(h2, xp2, pstat2 + (size_t)4 * 4096,
                                   bng + 4 * 64, bnb + 4 * 64, mbuf);
    kread<<<GG, 64, 0, stream>>>(mbuf, roW0, roB0, roW1, roB1, roW2, roB2, lW, lB, out);
}

// Round 9
// 568.324 us; speedup vs baseline: 1.0535x; 1.0535x over previous
//
#include <hip/hip_runtime.h>

#define NN   51200
#define EE   819200
#define GG   256
#define NN2  102400
#define AA   204800
#define EE2  409600
#define DD   64
#define LL   5

// bucket CSR build
#define NB1  100
#define NB2  200
#define CAP1 10240
#define CAP2 3072

typedef __attribute__((ext_vector_type(8))) short bf16x8;
typedef __attribute__((ext_vector_type(4))) float f32x4;
typedef unsigned short ushort_t;

// ---------------- workspace layout (bytes) ----------------
#define OFF_H      ((size_t)0)          // emb h; post-GIN: yrel; then agg (layer-2 gather)
#define OFF_AGG    ((size_t)13107200)   // GIN: h ping-pong buffer B
#define OFF_H2     ((size_t)26214400)   // GIN: buffer A; layer-4 output = h2 (alive to kpoolg)
#define OFF_XP     ((size_t)39321600)   // rec1/rec2 during CSR build; later xp
#define OFF_REC1   OFF_XP                       // 100*10240*8 = 8,192,000
#define OFF_REC2   ((size_t)47513600)           // 200*3072*8  = 4,915,200 (ends 52,428,800)
#define OFF_PERM   ((size_t)60293120)   // perm (200KB) inside xp region; dead before kgather2 writes xp
#define OFF_YROOT  ((size_t)65536000)   // GIN bf16 weights during GIN; yroot after; then xp2 (26MB, ends at OFF_OFFS1)
#define OFF_OFFS1  ((size_t)91750400)
#define OFF_COL1   ((size_t)91955216)
#define OFF_OFFS2  ((size_t)95232016)
#define OFF_COL2   ((size_t)95641632)
#define OFF_CNT1   ((size_t)97280032)   // zeroed region starts here; bucketCnt[300] lives here
#define OFF_BBASE  ((size_t)97282080)   // bucketBase[300] (inside zeroed region, harmless)
#define OFF_CUR1   ((size_t)97484832)   // pstat2[5][32][128] during GIN (zeroed by memset)
#define OFF_STATS  ((size_t)98508832)   // dbin[64], dcur[64] (zeroed)
#define ZERO_BYTES ((size_t)1231360)
#define OFF_ISO    ((size_t)98511392)
#define OFF_M      ((size_t)98920992)   // graphconv bf16 weight frags (64KB, die before kpoolg); then mbuf
#define WS_NEEDED  ((size_t)99052064)

__device__ __forceinline__ int waveInclScan(int v, int lane) {
#pragma unroll
    for (int off = 1; off < 64; off <<= 1) {
        int t = __shfl_up(v, off, 64);
        if (lane >= off) v += t;
    }
    return v;
}

// ---------------- split-bf16 helpers ----------------
__device__ __forceinline__ void bsplit(float x, ushort_t& hi, ushort_t& lo) {
    union { float f; unsigned u; } a; a.f = x;
    unsigned hb = (a.u + 0x7FFFu + ((a.u >> 16) & 1u)) >> 16;   // RNE to bf16
    union { unsigned u; float f; } h; h.u = hb << 16;
    float r = x - h.f;
    union { float f; unsigned u; } b; b.f = r;
    unsigned lb = (b.u + 0x7FFFu + ((b.u >> 16) & 1u)) >> 16;
    hi = (ushort_t)hb; lo = (ushort_t)lb;
}

// ---------------- bucket build phase A: scatter edges by dst>>9 ----------------
__global__ __launch_bounds__(256) void kbA(const int* __restrict__ src1, const int* __restrict__ dst1,
                                           const int* __restrict__ ea,
                                           const int* __restrict__ src2, const int* __restrict__ dst2,
                                           int* __restrict__ bucketCnt,
                                           int2* __restrict__ rec1, int2* __restrict__ rec2) {
    __shared__ int lhist[256];
    __shared__ int lbase[256];
    int tid = threadIdx.x, b = blockIdx.x;
    lhist[tid] = 0;
    __syncthreads();
    if (b < 400) {
        int i = (b * 256 + tid) * 8;
        int4 d0 = *(const int4*)(dst1 + i);
        int4 d1 = *(const int4*)(dst1 + i + 4);
        int dst[8] = {d0.x, d0.y, d0.z, d0.w, d1.x, d1.y, d1.z, d1.w};
        int bin[8], lr[8];
#pragma unroll
        for (int j = 0; j < 8; ++j) {
            bin[j] = dst[j] >> 9;
            lr[j] = atomicAdd(&lhist[bin[j]], 1);
        }
        __syncthreads();
        if (tid < NB1) {
            int c = lhist[tid];
            lbase[tid] = c ? atomicAdd(&bucketCnt[tid], c) : 0;
        }
        __syncthreads();
        int4 s0 = *(const int4*)(src1 + i);
        int4 s1 = *(const int4*)(src1 + i + 4);
        int src[8] = {s0.x, s0.y, s0.z, s0.w, s1.x, s1.y, s1.z, s1.w};
        int4 e0 = *(const int4*)(ea + 2 * i);
        int4 e1 = *(const int4*)(ea + 2 * i + 4);
        int4 e2 = *(const int4*)(ea + 2 * i + 8);
        int4 e3 = *(const int4*)(ea + 2 * i + 12);
        int code[8] = {e0.x * 3 + e0.y, e0.z * 3 + e0.w, e1.x * 3 + e1.y, e1.z * 3 + e1.w,
                       e2.x * 3 + e2.y, e2.z * 3 + e2.w, e3.x * 3 + e3.y, e3.z * 3 + e3.w};
#pragma unroll
        for (int j = 0; j < 8; ++j) {
            int pos = bin[j] * CAP1 + lbase[bin[j]] + lr[j];
            rec1[pos] = make_int2(src[j] | (code[j] << 16), dst[j]);
        }
    } else {
        int i = ((b - 400) * 256 + tid) * 8;
        int4 d0 = *(const int4*)(dst2 + i);
        int4 d1 = *(const int4*)(dst2 + i + 4);
        int dst[8] = {d0.x, d0.y, d0.z, d0.w, d1.x, d1.y, d1.z, d1.w};
        int bin[8], lr[8];
#pragma unroll
        for (int j = 0; j < 8; ++j) {
            bin[j] = dst[j] >> 9;
            lr[j] = atomicAdd(&lhist[bin[j]], 1);
        }
        __syncthreads();
        if (tid < NB2) {
            int c = lhist[tid];
            lbase[tid] = c ? atomicAdd(&bucketCnt[NB1 + tid], c) : 0;
        }
        __syncthreads();
        int4 s0 = *(const int4*)(src2 + i);
        int4 s1 = *(const int4*)(src2 + i + 4);
        int src[8] = {s0.x, s0.y, s0.z, s0.w, s1.x, s1.y, s1.z, s1.w};
#pragma unroll
        for (int j = 0; j < 8; ++j) {
            int pos = bin[j] * CAP2 + lbase[bin[j]] + lr[j];
            rec2[pos] = make_int2(src[j], dst[j]);
        }
    }
}

// exclusive scan of bucket counts (block 0: g1's 100, block 1: g2's 200)
__global__ void kbscan(const int* __restrict__ bucketCnt, int* __restrict__ bucketBase) {
    __shared__ int wsum[4];
    int tid = threadIdx.x, lane = tid & 63, wid = tid >> 6;
    int nb = blockIdx.x ? NB2 : NB1;
    const int* cnt = bucketCnt + (blockIdx.x ? NB1 : 0);
    int* base = bucketBase + (blockIdx.x ? NB1 : 0);
    int v = (tid < nb) ? cnt[tid] : 0;
    int incl = waveInclScan(v, lane);
    if (lane == 63) wsum[wid] = incl;
    __syncthreads();
    int woff = 0;
#pragma unroll
    for (int w = 0; w < 3; ++w) woff += (w < wid) ? wsum[w] : 0;
    if (tid < nb) base[tid] = woff + incl - v;
}

// ---------------- bucket build phase B: per-bucket CSR (LDS hist + scan + place) ----------------
__global__ __launch_bounds__(256) void kbB(const int* __restrict__ bucketCnt,
                                           const int* __restrict__ bucketBase,
                                           const int2* __restrict__ rec1, const int2* __restrict__ rec2,
                                           int* __restrict__ offs1, int* __restrict__ col1,
                                           int* __restrict__ offs2, int* __restrict__ col2,
                                           int* __restrict__ dbin) {
    __shared__ int nh[512];
    __shared__ int ncur[512];
    __shared__ int wsum[4];
    __shared__ int dhist[64];
    int tid = threadIdx.x, b = blockIdx.x;
    bool g1 = b < NB1;
    const int2* rec = g1 ? (rec1 + (size_t)b * CAP1) : (rec2 + (size_t)(b - NB1) * CAP2);
    int cnt = bucketCnt[b];
    int base = bucketBase[b];
    int* offs = g1 ? offs1 : offs2;
    int* col = g1 ? col1 : col2;
    int nodeBase = g1 ? b * 512 : (b - NB1) * 512;
    nh[tid] = 0; nh[tid + 256] = 0;
    if (tid < 64) dhist[tid] = 0;
    __syncthreads();
    for (int e = tid; e < cnt; e += 256) {
        int2 r = rec[e];
        atomicAdd(&nh[r.y & 511], 1);
    }
    __syncthreads();
    int v0 = nh[2 * tid], v1 = nh[2 * tid + 1];
    int s = v0 + v1;
    int lane = tid & 63, wid = tid >> 6;
    int incl = waveInclScan(s, lane);
    if (lane == 63) wsum[wid] = incl;
    __syncthreads();
    int woff = 0;
#pragma unroll
    for (int w = 0; w < 3; ++w) woff += (w < wid) ? wsum[w] : 0;
    int excl = woff + incl - s;
    ncur[2 * tid] = excl;
    ncur[2 * tid + 1] = excl + v0;
    offs[nodeBase + 2 * tid] = base + excl;
    offs[nodeBase + 2 * tid + 1] = base + excl + v0;
    if (g1) {
        atomicAdd(&dhist[v0 < 63 ? v0 : 63], 1);
        atomicAdd(&dhist[v1 < 63 ? v1 : 63], 1);
    }
    __syncthreads();
    for (int e = tid; e < cnt; e += 256) {
        int2 r = rec[e];
        int node = r.y & 511;
        int slot = base + atomicAdd(&ncur[node], 1);
        col[slot] = r.x;
    }
    if (g1 && tid < 64 && dhist[tid]) atomicAdd(&dbin[tid], dhist[tid]);
    if (tid == 0) {
        if (b == NB1 - 1) offs1[NN] = EE;
        if (b == NB1 + NB2 - 1) offs2[NN2] = EE2;
    }
}

// ---------------- iso argmax: LDS-staged coalesced reads ----------------
__global__ __launch_bounds__(256) void kiso(const float* __restrict__ iso, int* __restrict__ isoIdx) {
    __shared__ float srow[256 * 36];
    int tid = threadIdx.x;
    int base = blockIdx.x * 256;
    const float4* g4p = (const float4*)(iso + (size_t)base * 36);
#pragma unroll
    for (int i = tid; i < 2304; i += 256) ((float4*)srow)[i] = g4p[i];
    __syncthreads();
    const float* r = srow + tid * 36;
    int best = 0;
#pragma unroll
    for (int k = 0; k < 36; ++k)
        if (r[k] > 0.5f) best = k;
    isoIdx[base + tid] = best;
}

// ---------------- prep: embedding (float4 x loads) + GIN weight prep + GraphConv weight prep ----------------
__global__ void kprepx(const float* __restrict__ x, const float* __restrict__ embW,
                       const float* __restrict__ embB, float* __restrict__ h,
                       const float* __restrict__ gW1, const float* __restrict__ gW2,
                       ushort_t* __restrict__ w1h, ushort_t* __restrict__ w1l,
                       ushort_t* __restrict__ w2h, ushort_t* __restrict__ w2l,
                       const float* __restrict__ i1rW, const float* __restrict__ i1tW,
                       const float* __restrict__ i2rW, const float* __restrict__ i2tW,
                       ushort_t* __restrict__ gcwh, ushort_t* __restrict__ gcwl) {
    int b = blockIdx.x;
    if (b < 12800) {
        int t = b * 256 + threadIdx.x;
        int n = t >> 6, d = t & 63;
        float acc = embB[d];
        const float4* xr4 = (const float4*)(x + (size_t)n * 40);
#pragma unroll
        for (int k4 = 0; k4 < 10; ++k4) {
            float4 xv = xr4[k4];
            acc = fmaf(xv.x, embW[(4 * k4 + 0) * 64 + d], acc);
            acc = fmaf(xv.y, embW[(4 * k4 + 1) * 64 + d], acc);
            acc = fmaf(xv.z, embW[(4 * k4 + 2) * 64 + d], acc);
            acc = fmaf(xv.w, embW[(4 * k4 + 3) * 64 + d], acc);
        }
        h[(size_t)n * 64 + d] = fmaxf(acc, 0.f);
    } else if (b < 12840) {
        int t = (b - 12800) * 256 + threadIdx.x;
        int lane = t & 63, frag = t >> 6;
        int c15 = lane & 15, q = lane >> 4;
        if (frag < 80) {
            int kt = frag & 1, nt = (frag >> 1) & 7, l = frag >> 4;
            const float* W = gW1 + l * 8192;
            ushort_t* oh = w1h + ((size_t)frag * 64 + lane) * 8;
            ushort_t* ol = w1l + ((size_t)frag * 64 + lane) * 8;
            int kb = kt * 32 + q * 8, colw = nt * 16 + c15;
#pragma unroll
            for (int j = 0; j < 8; ++j) {
                ushort_t hi, lo; bsplit(W[(kb + j) * 128 + colw], hi, lo);
                oh[j] = hi; ol[j] = lo;
            }
        } else if (frag < 160) {
            int f = frag - 80;
            int kt = f & 3, nt = (f >> 2) & 3, l = f >> 4;
            const float* W = gW2 + l * 8192;
            ushort_t* oh = w2h + ((size_t)f * 64 + lane) * 8;
            ushort_t* ol = w2l + ((size_t)f * 64 + lane) * 8;
            int kb = kt * 32 + q * 8, colw = nt * 16 + c15;
#pragma unroll
            for (int j = 0; j < 8; ++j) {
                ushort_t hi, lo; bsplit(W[(kb + j) * 64 + colw], hi, lo);
                oh[j] = hi; ol[j] = lo;
            }
        }
    } else {
        // GraphConv weight prep: 4 matrices x 8 frags (K=64, N=64)
        int t = (b - 12840) * 256 + threadIdx.x;   // 0..2047
        int lane = t & 63, frag = t >> 6;          // frag 0..31
        int c15 = lane & 15, q = lane >> 4;
        int m = frag >> 3, f = frag & 7;
        int kt = f & 1, nt = f >> 1;
        const float* W = (m == 0) ? i1rW : (m == 1) ? i1tW : (m == 2) ? i2rW : i2tW;
        ushort_t* oh = gcwh + (size_t)m * 4096 + ((size_t)f * 64 + lane) * 8;
        ushort_t* ol = gcwl + (size_t)m * 4096 + ((size_t)f * 64 + lane) * 8;
        int kb = kt * 32 + q * 8, colw = nt * 16 + c15;
#pragma unroll
        for (int j = 0; j < 8; ++j) {
            ushort_t hi, lo; bsplit(W[(kb + j) * 64 + colw], hi, lo);
            oh[j] = hi; ol[j] = lo;
        }
    }
}

// two-level counting-sort placement; dstart computed inline from dbin (ascending)
__global__ __launch_bounds__(256) void kdegplace(const int* __restrict__ offs,
                                                 const int* __restrict__ dbin,
                                                 int* __restrict__ dcur,
                                                 int* __restrict__ perm) {
    __shared__ int lhist[64];
    __shared__ int lbase[64];
    __shared__ int sdstart[64];
    int tid = threadIdx.x;
    if (tid < 64) {
        lhist[tid] = 0;
        int v = dbin[tid];
        int incl = waveInclScan(v, tid);
        sdstart[tid] = incl - v;
    }
    __syncthreads();
    int n = blockIdx.x * 256 + tid;
    int d = offs[n + 1] - offs[n]; d = d < 63 ? d : 63;
    int lr = atomicAdd(&lhist[d], 1);
    __syncthreads();
    if (tid < 64) {
        int c = lhist[tid];
        lbase[tid] = c ? atomicAdd(&dcur[tid], c) : 0;
    }
    __syncthreads();
    perm[sdstart[d] + lbase[d] + lr] = n;
}

// ---------------- per-node BN+ReLU transform, in place (once per node, not per edge) ----------------
__global__ __launch_bounds__(256) void ktrans(float* __restrict__ h,
                                              const float* __restrict__ pst,
                                              const float* __restrict__ gamma,
                                              const float* __restrict__ beta) {
    __shared__ float sstat[128];
    __shared__ float sSC[64], sSH[64];
    int tid = threadIdx.x;
    if (tid < 128) {
        float s = 0.f;
        const float* p = pst + tid;
#pragma unroll
        for (int i = 0; i < 32; ++i) s += p[i * 128];
        sstat[tid] = s;
    }
    __syncthreads();
    if (tid < 64) {
        float mu = sstat[tid] * (1.f / NN);
        float var = sstat[64 + tid] * (1.f / NN) - mu * mu;
        float sc = gamma[tid] * rsqrtf(var + 1e-5f);
        sSC[tid] = sc; sSH[tid] = beta[tid] - mu * sc;
    }
    __syncthreads();
    int c = (tid & 15) * 4;
    float4 sc4 = *(const float4*)(sSC + c);
    float4 sh4 = *(const float4*)(sSH + c);
    float4* hp = (float4*)h;
    size_t base = (size_t)blockIdx.x * 1024 + tid;
#pragma unroll
    for (int r = 0; r < 4; ++r) {
        float4 v = hp[base + r * 256];
        v.x = fmaxf(fmaf(v.x, sc4.x, sh4.x), 0.f);
        v.y = fmaxf(fmaf(v.y, sc4.y, sh4.y), 0.f);
        v.z = fmaxf(fmaf(v.z, sc4.z, sh4.z), 0.f);
        v.w = fmaxf(fmaf(v.w, sc4.w, sh4.w), 0.f);
        hp[base + r * 256] = v;
    }
}

// ---------------- fused GIN layer: gather(16 perm'd nodes) -> LDS -> MFMA MLP -> hout + stats ----
// R7 structure: minimal gather dependent-chain (no per-edge transforms — measured 42 vs 58 µs).
__global__ __launch_bounds__(256) void kglayer(
    const float* __restrict__ hin, float* __restrict__ hout,
    const int* __restrict__ perm,
    const int* __restrict__ offs, const int* __restrict__ col,
    const float* __restrict__ e1, const float* __restrict__ e2,
    const ushort_t* __restrict__ w1h, const ushort_t* __restrict__ w1l,
    const ushort_t* __restrict__ w2h, const ushort_t* __restrict__ w2l,
    const float* __restrict__ b1, const float* __restrict__ b2,
    float* __restrict__ pstout) {
    __shared__ float etab[13 * 64];
    __shared__ int sPerm[16];
    __shared__ float sMLP[16 * 132];   // sA stride-68 aliases front; sH stride-132
    float* sA = sMLP;
    float* sH = sMLP;
    int tid = threadIdx.x;
    if (tid < 16) sPerm[tid] = perm[blockIdx.x * 16 + tid];
    for (int idx = tid; idx < 13 * 64; idx += 256) {
        int ci = idx >> 6, dd = idx & 63;
        etab[idx] = e1[(ci / 3) * 64 + dd] + e2[(ci % 3) * 64 + dd];
    }
    __syncthreads();
    int lane = tid & 63, wv = tid >> 6;
    int c15 = lane & 15, q = lane >> 4;

    // ---- gather node n into sA ----
    {
        int n = sPerm[wv * 4 + q];
        int s0 = offs[n], s1 = offs[n + 1];
        float4 sx = *(const float4*)(hin + (size_t)n * 64 + 4 * c15);
        float4 et = *(const float4*)(etab + 12 * 64 + 4 * c15);
        float a0 = sx.x + et.x, a1 = sx.y + et.y, a2 = sx.z + et.z, a3 = sx.w + et.w;
        int deg = s1 - s0;
        if (deg > 0) {
            const int* cp = col + s0;
            int nfull = deg >> 3, rem = deg & 7;
            int vv[8];
#pragma unroll
            for (int j = 0; j < 8; ++j) {
                int idx = j < deg ? j : deg - 1;
                vv[j] = cp[idx];
            }
            for (int it = 0; it < nfull; ++it) {
                float4 xv[8], tv[8];
#pragma unroll
                for (int j = 0; j < 8; ++j) {
                    xv[j] = *(const float4*)(hin + (size_t)(vv[j] & 0xFFFF) * 64 + 4 * c15);
                    tv[j] = *(const float4*)(etab + (vv[j] >> 16) * 64 + 4 * c15);
                }
                int e8 = (it + 1) * 8;
                bool more = e8 < deg;
                int nx[8];
                if (more) {
#pragma unroll
                    for (int j = 0; j < 8; ++j) {
                        int idx = e8 + j; idx = idx < deg ? idx : deg - 1;
                        nx[j] = cp[idx];
                    }
                }
#pragma unroll
                for (int j = 0; j < 8; ++j) {
                    a0 += xv[j].x + tv[j].x;
                    a1 += xv[j].y + tv[j].y;
                    a2 += xv[j].z + tv[j].z;
                    a3 += xv[j].w + tv[j].w;
                }
                if (more) {
#pragma unroll
                    for (int j = 0; j < 8; ++j) vv[j] = nx[j];
                }
            }
            if (rem) {
                float4 xv[8], tv[8];
#pragma unroll
                for (int j = 0; j < 8; ++j) {
                    xv[j] = *(const float4*)(hin + (size_t)(vv[j] & 0xFFFF) * 64 + 4 * c15);
                    tv[j] = *(const float4*)(etab + (vv[j] >> 16) * 64 + 4 * c15);
                }
#pragma unroll
                for (int j = 0; j < 8; ++j) {
                    float mm = (j < rem) ? 1.f : 0.f;
                    a0 = fmaf(xv[j].x + tv[j].x, mm, a0);
                    a1 = fmaf(xv[j].y + tv[j].y, mm, a1);
                    a2 = fmaf(xv[j].z + tv[j].z, mm, a2);
                    a3 = fmaf(xv[j].w + tv[j].w, mm, a3);
                }
            }
        }
        *(float4*)(sA + (wv * 4 + q) * 68 + 4 * c15) = make_float4(a0, a1, a2, a3);
    }
    __syncthreads();

    // ---- A-frags to regs (sA dies after next sync; sH aliases) ----
    bf16x8 ah[2], al[2];
#pragma unroll
    for (int kt = 0; kt < 2; ++kt) {
        const float* p = sA + c15 * 68 + kt * 32 + q * 8;
        float4 x0 = *(const float4*)p;
        float4 x1 = *(const float4*)(p + 4);
        float xs[8] = {x0.x, x0.y, x0.z, x0.w, x1.x, x1.y, x1.z, x1.w};
#pragma unroll
        for (int j = 0; j < 8; ++j) {
            ushort_t hi, lo; bsplit(xs[j], hi, lo);
            ah[kt][j] = (short)hi; al[kt][j] = (short)lo;
        }
    }
    __syncthreads();

    // ---- GEMM1: nt = 2wv+j ----
    f32x4 acc1[2];
#pragma unroll
    for (int j = 0; j < 2; ++j) { f32x4 z = {0.f, 0.f, 0.f, 0.f}; acc1[j] = z; }
#pragma unroll
    for (int kt = 0; kt < 2; ++kt) {
#pragma unroll
        for (int j = 0; j < 2; ++j) {
            int nt = 2 * wv + j;
            size_t fo = ((size_t)((nt * 2 + kt) * 64 + lane)) * 8;
            bf16x8 bh = *(const bf16x8*)(w1h + fo);
            bf16x8 bl = *(const bf16x8*)(w1l + fo);
            acc1[j] = __builtin_amdgcn_mfma_f32_16x16x32_bf16(ah[kt], bh, acc1[j], 0, 0, 0);
            acc1[j] = __builtin_amdgcn_mfma_f32_16x16x32_bf16(al[kt], bh, acc1[j], 0, 0, 0);
            acc1[j] = __builtin_amdgcn_mfma_f32_16x16x32_bf16(ah[kt], bl, acc1[j], 0, 0, 0);
        }
    }
#pragma unroll
    for (int j = 0; j < 2; ++j) {
        int nt = 2 * wv + j;
        float bias = b1[nt * 16 + c15];
#pragma unroll
        for (int rg = 0; rg < 4; ++rg)
            sH[(4 * q + rg) * 132 + nt * 16 + c15] = fmaxf(acc1[j][rg] + bias, 0.f);
    }
    __syncthreads();

    // ---- GEMM2: nt = wv ----
    f32x4 acc2 = {0.f, 0.f, 0.f, 0.f};
#pragma unroll
    for (int kt = 0; kt < 4; ++kt) {
        const float* p = sH + c15 * 132 + kt * 32 + q * 8;
        float4 x0 = *(const float4*)p;
        float4 x1 = *(const float4*)(p + 4);
        float xs[8] = {x0.x, x0.y, x0.z, x0.w, x1.x, x1.y, x1.z, x1.w};
        bf16x8 a2h, a2l;
#pragma unroll
        for (int j = 0; j < 8; ++j) {
            ushort_t hi, lo; bsplit(xs[j], hi, lo);
            a2h[j] = (short)hi; a2l[j] = (short)lo;
        }
        size_t fo = ((size_t)((wv * 4 + kt) * 64 + lane)) * 8;
        bf16x8 bh = *(const bf16x8*)(w2h + fo);
        bf16x8 bl = *(const bf16x8*)(w2l + fo);
        acc2 = __builtin_amdgcn_mfma_f32_16x16x32_bf16(a2h, bh, acc2, 0, 0, 0);
        acc2 = __builtin_amdgcn_mfma_f32_16x16x32_bf16(a2l, bh, acc2, 0, 0, 0);
        acc2 = __builtin_amdgcn_mfma_f32_16x16x32_bf16(a2h, bl, acc2, 0, 0, 0);
    }
    {
        float bias = b2[wv * 16 + c15];
        float s = 0.f, s2 = 0.f;
#pragma unroll
        for (int rg = 0; rg < 4; ++rg) {
            float v = acc2[rg] + bias;
            hout[(size_t)sPerm[4 * q + rg] * 64 + wv * 16 + c15] = v;
            s += v; s2 += v * v;
        }
        s += __shfl_xor(s, 16, 64);  s += __shfl_xor(s, 32, 64);
        s2 += __shfl_xor(s2, 16, 64); s2 += __shfl_xor(s2, 32, 64);
        if (q == 0) {
            float* ps = pstout + (size_t)(blockIdx.x & 31) * 128;
            atomicAdd(&ps[wv * 16 + c15], s);
            atomicAdd(&ps[64 + wv * 16 + c15], s2);
        }
    }
}

// ---------------- GraphConv1 GEMMs via split-bf16 MFMA (writes yrel,yroot) ----------------
__global__ __launch_bounds__(256) void kgcmm1(const ushort_t* __restrict__ grh,
                                              const ushort_t* __restrict__ grl,
                                              const ushort_t* __restrict__ gth,
                                              const ushort_t* __restrict__ gtl,
                                              const float* __restrict__ WrelIso,
                                              const float* __restrict__ WrootIso,
                                              const int* __restrict__ isoIdx,
                                              float* __restrict__ Yrel,
                                              float* __restrict__ Yroot,
                                              const float* __restrict__ pst,
                                              const float* __restrict__ g4,
                                              const float* __restrict__ b4,
                                              const int* __restrict__ a0g,
                                              const float* __restrict__ h2src) {
    __shared__ float sX[64 * 68];
    __shared__ float sstat[128];
    __shared__ float sSC[64], sSH[64];
    int tid = threadIdx.x, blk = blockIdx.x;
    if (tid < 128) {
        float s = 0.f;
        const float* p = pst + tid;
#pragma unroll
        for (int i = 0; i < 32; ++i) s += p[i * 128];
        sstat[tid] = s;
    }
    __syncthreads();
    if (tid < 64) {
        float mu = sstat[tid] * (1.f / NN);
        float var = sstat[64 + tid] * (1.f / NN) - mu * mu;
        float sc = g4[tid] * rsqrtf(var + 1e-5f);
        sSC[tid] = sc;
        sSH[tid] = b4[tid] - mu * sc;
    }
    __syncthreads();
#pragma unroll
    for (int i = tid; i < 1024; i += 256) {
        int row = i >> 4, c = (i & 15) << 2;
        int grow = blk * 64 + row;
        int na = a0g[2 * grow], nb = a0g[2 * grow + 1];
        float4 va = *(const float4*)(h2src + (size_t)na * 64 + c);
        float4 vb = *(const float4*)(h2src + (size_t)nb * 64 + c);
        float4 v;
        v.x = 0.5f * (va.x + vb.x); v.y = 0.5f * (va.y + vb.y);
        v.z = 0.5f * (va.z + vb.z); v.w = 0.5f * (va.w + vb.w);
        v.x = fmaf(v.x, sSC[c], sSH[c]);
        v.y = fmaf(v.y, sSC[c + 1], sSH[c + 1]);
        v.z = fmaf(v.z, sSC[c + 2], sSH[c + 2]);
        v.w = fmaf(v.w, sSC[c + 3], sSH[c + 3]);
        float* p = sX + row * 68 + c;
        p[0] = v.x; p[1] = v.y; p[2] = v.z; p[3] = v.w;
    }
    __syncthreads();
    int lane = tid & 63, wv = tid >> 6;
    int c15 = lane & 15, q = lane >> 4;

    bf16x8 ah[2], al[2];
#pragma unroll
    for (int kt = 0; kt < 2; ++kt) {
        const float* p = sX + (16 * wv + c15) * 68 + kt * 32 + q * 8;
        float4 x0 = *(const float4*)p;
        float4 x1 = *(const float4*)(p + 4);
        float xs[8] = {x0.x, x0.y, x0.z, x0.w, x1.x, x1.y, x1.z, x1.w};
#pragma unroll
        for (int j = 0; j < 8; ++j) {
            ushort_t hi, lo; bsplit(xs[j], hi, lo);
            ah[kt][j] = (short)hi; al[kt][j] = (short)lo;
        }
    }

    f32x4 accR[4], accT[4];
#pragma unroll
    for (int nt = 0; nt < 4; ++nt) {
        f32x4 z = {0.f, 0.f, 0.f, 0.f};
        accR[nt] = z; accT[nt] = z;
    }
#pragma unroll
    for (int nt = 0; nt < 4; ++nt) {
#pragma unroll
        for (int kt = 0; kt < 2; ++kt) {
            size_t fo = ((size_t)((nt * 2 + kt) * 64 + lane)) * 8;
            bf16x8 bh = *(const bf16x8*)(grh + fo);
            bf16x8 bl = *(const bf16x8*)(grl + fo);
            accR[nt] = __builtin_amdgcn_mfma_f32_16x16x32_bf16(ah[kt], bh, accR[nt], 0, 0, 0);
            accR[nt] = __builtin_amdgcn_mfma_f32_16x16x32_bf16(al[kt], bh, accR[nt], 0, 0, 0);
            accR[nt] = __builtin_amdgcn_mfma_f32_16x16x32_bf16(ah[kt], bl, accR[nt], 0, 0, 0);
            bf16x8 ch = *(const bf16x8*)(gth + fo);
            bf16x8 cl = *(const bf16x8*)(gtl + fo);
            accT[nt] = __builtin_amdgcn_mfma_f32_16x16x32_bf16(ah[kt], ch, accT[nt], 0, 0, 0);
            accT[nt] = __builtin_amdgcn_mfma_f32_16x16x32_bf16(al[kt], ch, accT[nt], 0, 0, 0);
            accT[nt] = __builtin_amdgcn_mfma_f32_16x16x32_bf16(ah[kt], cl, accT[nt], 0, 0, 0);
        }
    }

    int rbase = blk * 64 + 16 * wv + 4 * q;
#pragma unroll
    for (int rg = 0; rg < 4; ++rg) {
        int row = rbase + rg;
        int ii = isoIdx[row];
        float* yr = Yrel + (size_t)row * 64;
        float* yt = Yroot + (size_t)row * 64;
        const float* er = WrelIso + (size_t)ii * 64;
        const float* et = WrootIso + (size_t)ii * 64;
#pragma unroll
        for (int nt = 0; nt < 4; ++nt) {
            int cc = nt * 16 + c15;
            yr[cc] = accR[nt][rg] + er[cc];
            yt[cc] = accT[nt][rg] + et[cc];
        }
    }
}

// ---------------- GraphConv2 fused: OUT = relu(AGG @ Wrel + brel + XP @ Wroot) ----------------
__global__ __launch_bounds__(256) void kgcmm2(const float* __restrict__ AGG,
                                              const float* __restrict__ XP,
                                              const ushort_t* __restrict__ grh,
                                              const ushort_t* __restrict__ grl,
                                              const ushort_t* __restrict__ gth,
                                              const ushort_t* __restrict__ gtl,
                                              const float* __restrict__ brel,
                                              float* __restrict__ OUT) {
    __shared__ float sA[64 * 68];
    __shared__ float sB[64 * 68];
    int tid = threadIdx.x, blk = blockIdx.x;
#pragma unroll
    for (int i = tid; i < 1024; i += 256) {
        int row = i >> 4, c = (i & 15) << 2;
        float4 va = ((const float4*)(AGG + (size_t)blk * 4096))[i];
        float4 vb = ((const float4*)(XP + (size_t)blk * 4096))[i];
        float* pa = sA + row * 68 + c;
        float* pb = sB + row * 68 + c;
        pa[0] = va.x; pa[1] = va.y; pa[2] = va.z; pa[3] = va.w;
        pb[0] = vb.x; pb[1] = vb.y; pb[2] = vb.z; pb[3] = vb.w;
    }
    __syncthreads();
    int lane = tid & 63, wv = tid >> 6;
    int c15 = lane & 15, q = lane >> 4;

    bf16x8 aAh[2], aAl[2], aBh[2], aBl[2];
#pragma unroll
    for (int kt = 0; kt < 2; ++kt) {
        const float* pa = sA + (16 * wv + c15) * 68 + kt * 32 + q * 8;
        const float* pb = sB + (16 * wv + c15) * 68 + kt * 32 + q * 8;
        float4 a0 = *(const float4*)pa;
        float4 a1 = *(const float4*)(pa + 4);
        float4 b0 = *(const float4*)pb;
        float4 b1 = *(const float4*)(pb + 4);
        float as[8] = {a0.x, a0.y, a0.z, a0.w, a1.x, a1.y, a1.z, a1.w};
        float bs[8] = {b0.x, b0.y, b0.z, b0.w, b1.x, b1.y, b1.z, b1.w};
#pragma unroll
        for (int j = 0; j < 8; ++j) {
            ushort_t hi, lo;
            bsplit(as[j], hi, lo); aAh[kt][j] = (short)hi; aAl[kt][j] = (short)lo;
            bsplit(bs[j], hi, lo); aBh[kt][j] = (short)hi; aBl[kt][j] = (short)lo;
        }
    }

    f32x4 acc[4];
#pragma unroll
    for (int nt = 0; nt < 4; ++nt) { f32x4 z = {0.f, 0.f, 0.f, 0.f}; acc[nt] = z; }
#pragma unroll
    for (int nt = 0; nt < 4; ++nt) {
#pragma unroll
        for (int kt = 0; kt < 2; ++kt) {
            size_t fo = ((size_t)((nt * 2 + kt) * 64 + lane)) * 8;
            bf16x8 bh = *(const bf16x8*)(grh + fo);
            bf16x8 bl = *(const bf16x8*)(grl + fo);
            acc[nt] = __builtin_amdgcn_mfma_f32_16x16x32_bf16(aAh[kt], bh, acc[nt], 0, 0, 0);
            acc[nt] = __builtin_amdgcn_mfma_f32_16x16x32_bf16(aAl[kt], bh, acc[nt], 0, 0, 0);
            acc[nt] = __builtin_amdgcn_mfma_f32_16x16x32_bf16(aAh[kt], bl, acc[nt], 0, 0, 0);
            bf16x8 ch = *(const bf16x8*)(gth + fo);
            bf16x8 cl = *(const bf16x8*)(gtl + fo);
            acc[nt] = __builtin_amdgcn_mfma_f32_16x16x32_bf16(aBh[kt], ch, acc[nt], 0, 0, 0);
            acc[nt] = __builtin_amdgcn_mfma_f32_16x16x32_bf16(aBl[kt], ch, acc[nt], 0, 0, 0);
            acc[nt] = __builtin_amdgcn_mfma_f32_16x16x32_bf16(aBh[kt], cl, acc[nt], 0, 0, 0);
        }
    }

    int rbase = blk * 64 + 16 * wv + 4 * q;
#pragma unroll
    for (int rg = 0; rg < 4; ++rg) {
        int row = rbase + rg;
        float* yo = OUT + (size_t)row * 64;
#pragma unroll
        for (int nt = 0; nt < 4; ++nt) {
            int cc = nt * 16 + c15;
            yo[cc] = fmaxf(acc[nt][rg] + brel[cc], 0.f);
        }
    }
}

// ---------------- GraphConv gather layer1: root+bias+relu (reads yrel/yroot) ----------------
__global__ void kgather2(const float* __restrict__ yrel, const float* __restrict__ yroot,
                         const float* __restrict__ brel, const int* __restrict__ offs,
                         const int* __restrict__ col, float* __restrict__ out) {
    int t = blockIdx.x * 256 + threadIdx.x;
    int j = t >> 4, c = t & 15;
    int s0 = offs[j], s1 = offs[j + 1];
    float4 rt = *(const float4*)(yroot + (size_t)j * 64 + 4 * c);
    float4 bb = *(const float4*)(brel + 4 * c);
    float a0 = rt.x + bb.x, a1 = rt.y + bb.y, a2 = rt.z + bb.z, a3 = rt.w + bb.w;
    if (s0 < s1) {
        int vv[4];
#pragma unroll
        for (int jj = 0; jj < 4; ++jj) {
            int idx = s0 + jj; idx = idx < s1 ? idx : s1 - 1;
            vv[jj] = col[idx];
        }
        int e = s0;
        while (true) {
            int ne = e + 4;
            bool more = ne < s1;
            float4 xs[4];
#pragma unroll
            for (int jj = 0; jj < 4; ++jj)
                xs[jj] = *(const float4*)(yrel + (size_t)vv[jj] * 64 + 4 * c);
            int nx[4];
            if (more) {
#pragma unroll
                for (int jj = 0; jj < 4; ++jj) {
                    int idx = ne + jj; idx = idx < s1 ? idx : s1 - 1;
                    nx[jj] = col[idx];
                }
            }
#pragma unroll
            for (int jj = 0; jj < 4; ++jj) {
                float mm = (e + jj < s1) ? 1.f : 0.f;
                a0 = fmaf(xs[jj].x, mm, a0);
                a1 = fmaf(xs[jj].y, mm, a1);
                a2 = fmaf(xs[jj].z, mm, a2);
                a3 = fmaf(xs[jj].w, mm, a3);
            }
            if (!more) break;
            e = ne;
#pragma unroll
            for (int jj = 0; jj < 4; ++jj) vv[jj] = nx[jj];
        }
    }
    *(float4*)(out + (size_t)j * 64 + 4 * c) =
        make_float4(fmaxf(a0, 0.f), fmaxf(a1, 0.f), fmaxf(a2, 0.f), fmaxf(a3, 0.f));
}

// ---------------- GraphConv gather layer2: raw neighbor sums only ----------------
__global__ void kgather2raw(const float* __restrict__ xpsrc, const int* __restrict__ offs,
                            const int* __restrict__ col, float* __restrict__ agg) {
    int t = blockIdx.x * 256 + threadIdx.x;
    int j = t >> 4, c = t & 15;
    int s0 = offs[j], s1 = offs[j + 1];
    float a0 = 0.f, a1 = 0.f, a2 = 0.f, a3 = 0.f;
    if (s0 < s1) {
        int vv[4];
#pragma unroll
        for (int jj = 0; jj < 4; ++jj) {
            int idx = s0 + jj; idx = idx < s1 ? idx : s1 - 1;
            vv[jj] = col[idx];
        }
        int e = s0;
        while (true) {
            int ne = e + 4;
            bool more = ne < s1;
            float4 xs[4];
#pragma unroll
            for (int jj = 0; jj < 4; ++jj)
                xs[jj] = *(const float4*)(xpsrc + (size_t)vv[jj] * 64 + 4 * c);
            int nx[4];
            if (more) {
#pragma unroll
                for (int jj = 0; jj < 4; ++jj) {
                    int idx = ne + jj; idx = idx < s1 ? idx : s1 - 1;
                    nx[jj] = col[idx];
                }
            }
#pragma unroll
            for (int jj = 0; jj < 4; ++jj) {
                float mm = (e + jj < s1) ? 1.f : 0.f;
                a0 = fmaf(xs[jj].x, mm, a0);
                a1 = fmaf(xs[jj].y, mm, a1);
                a2 = fmaf(xs[jj].z, mm, a2);
                a3 = fmaf(xs[jj].w, mm, a3);
            }
            if (!more) break;
            e = ne;
#pragma unroll
            for (int jj = 0; jj < 4; ++jj) vv[jj] = nx[jj];
        }
    }
    *(float4*)(agg + (size_t)j * 64 + 4 * c) = make_float4(a0, a1, a2, a3);
}

// ---------------- per-graph mean pools (x1 gets final BN affine on the mean) ----------------
__global__ void kpoolg(const float* __restrict__ h2, const float* __restrict__ xp2,
                       const float* __restrict__ pst, const float* __restrict__ g4,
                       const float* __restrict__ b4, float* __restrict__ m) {
    __shared__ float sstat[128];
    __shared__ float red[4][64];
    int g = blockIdx.x, tid = threadIdx.x;
    if (tid < 128) {
        float s = 0.f;
        const float* p = pst + tid;
#pragma unroll
        for (int i = 0; i < 32; ++i) s += p[i * 128];
        sstat[tid] = s;
    }
    int wid = tid >> 6, d = tid & 63;
    float s1 = 0.f;
    for (int i = wid; i < 200; i += 4) s1 += h2[((size_t)g * 200 + i) * 64 + d];
    red[wid][d] = s1;
    __syncthreads();
    if (wid == 0) {
        float mean = (red[0][d] + red[1][d] + red[2][d] + red[3][d]) * (1.f / 200.f);
        float mu = sstat[d] * (1.f / NN);
        float var = sstat[64 + d] * (1.f / NN) - mu * mu;
        float sc = g4[d] * rsqrtf(var + 1e-5f);
        m[g * 128 + d] = fmaf(mean, sc, b4[d] - mu * sc);
    }
    __syncthreads();
    float s2 = 0.f;
    for (int i = wid; i < 400; i += 4) s2 += xp2[((size_t)g * 400 + i) * 64 + d];
    red[wid][d] = s2;
    __syncthreads();
    if (wid == 0) m[g * 128 + 64 + d] = (red[0][d] + red[1][d] + red[2][d] + red[3][d]) * (1.f / 400.f);
}

// ---------------- readout MLP ----------------
__global__ void kread(const float* __restrict__ m, const float* __restrict__ W0,
                      const float* __restrict__ b0, const float* __restrict__ W1,
                      const float* __restrict__ b1, const float* __restrict__ W2,
                      const float* __restrict__ b2, const float* __restrict__ lw,
                      const float* __restrict__ lb, float* __restrict__ out) {
    __shared__ float s0[64], s1[32], s2[16];
    int g = blockIdx.x, d = threadIdx.x;
    const float* mr = m + g * 128;
    float t = b0[d];
    for (int k = 0; k < 128; ++k) t = fmaf(mr[k], W0[k * 64 + d], t);
    s0[d] = fmaxf(t, 0.f);
    __syncthreads();
    if (d < 32) {
        float u = b1[d];
        for (int k = 0; k < 64; ++k) u = fmaf(s0[k], W1[k * 32 + d], u);
        s1[d] = fmaxf(u, 0.f);
    }
    __syncthreads();
    if (d < 16) {
        float u = b2[d];
        for (int k = 0; k < 32; ++k) u = fmaf(s1[k], W2[k * 16 + d], u);
        s2[d] = fmaxf(u, 0.f);
    }
    __syncthreads();
    if (d == 0) {
        float u = lb[0];
        for (int k = 0; k < 16; ++k) u = fmaf(s2[k], lw[k], u);
        out[g] = u;
    }
}

// ---------------- host ----------------
extern "C" void kernel_launch(void* const* d_in, const int* in_sizes, int n_in,
                              void* d_out, int out_size, void* d_ws, size_t ws_size,
                              hipStream_t stream) {
    if (ws_size < WS_NEEDED) return;

    const float* x    = (const float*)d_in[0];
    const int*   ei   = (const int*)d_in[1];
    const int*   ea   = (const int*)d_in[2];
    const float* iso  = (const float*)d_in[4];
    const int*   ei2  = (const int*)d_in[5];
    const int*   ai2  = (const int*)d_in[6];
    const float* embW = (const float*)d_in[8];
    const float* embB = (const float*)d_in[9];
    const float* gW1  = (const float*)d_in[10];
    const float* gB1  = (const float*)d_in[11];
    const float* gW2  = (const float*)d_in[12];
    const float* gB2  = (const float*)d_in[13];
    const float* ee1  = (const float*)d_in[14];
    const float* ee2  = (const float*)d_in[15];
    const float* bng  = (const float*)d_in[16];
    const float* bnb  = (const float*)d_in[17];
    const float* i1rW = (const float*)d_in[18];
    const float* i1rB = (const float*)d_in[19];
    const float* i1tW = (const float*)d_in[20];
    const float* i2rW = (const float*)d_in[21];
    const float* i2rB = (const float*)d_in[22];
    const float* i2tW = (const float*)d_in[23];
    const float* roW0 = (const float*)d_in[24];
    const float* roB0 = (const float*)d_in[25];
    const float* roW1 = (const float*)d_in[26];
    const float* roB1 = (const float*)d_in[27];
    const float* roW2 = (const float*)d_in[28];
    const float* roB2 = (const float*)d_in[29];
    const float* lW   = (const float*)d_in[30];
    const float* lB   = (const float*)d_in[31];
    float* out = (float*)d_out;

    char* ws = (char*)d_ws;
    float* h      = (float*)(ws + OFF_H);
    float* hB     = (float*)(ws + OFF_AGG);    // ping-pong buffer B
    float* hA     = (float*)(ws + OFF_H2);     // ping-pong buffer A; final h2
    float* h2     = hA;
    float* xp     = (float*)(ws + OFF_XP);
    float* yrel   = (float*)(ws + OFF_H);      // spans h+hB (both dead post-GIN); later agg
    float* yroot  = (float*)(ws + OFF_YROOT);
    float* aggb   = (float*)(ws + OFF_H);      // layer-2 raw gather output
    float* xp2    = (float*)(ws + OFF_YROOT);  // layer-2 final output (26MB, ends at OFF_OFFS1)
    int* offs1    = (int*)(ws + OFF_OFFS1);
    int* col1     = (int*)(ws + OFF_COL1);
    int* offs2    = (int*)(ws + OFF_OFFS2);
    int* col2     = (int*)(ws + OFF_COL2);
    int* isoIdx   = (int*)(ws + OFF_ISO);
    float* mbuf   = (float*)(ws + OFF_M);      // written by kpoolg AFTER gcw frags die
    ushort_t* w1h = (ushort_t*)(ws + OFF_YROOT);
    ushort_t* w1l = (ushort_t*)(ws + OFF_YROOT + 81920);
    ushort_t* w2h = (ushort_t*)(ws + OFF_YROOT + 163840);
    ushort_t* w2l = (ushort_t*)(ws + OFF_YROOT + 245760);
    ushort_t* gcwh = (ushort_t*)(ws + OFF_M);           // 4 matrices x 4096 ushorts
    ushort_t* gcwl = (ushort_t*)(ws + OFF_M + 32768);
    float* pstat2 = (float*)(ws + OFF_CUR1);   // zeroed by memset each launch
    int2* rec1    = (int2*)(ws + OFF_REC1);    // bucketed edge records (xp region; dead before xp writes)
    int2* rec2    = (int2*)(ws + OFF_REC2);
    int* bucketCnt  = (int*)(ws + OFF_CNT1);   // zeroed
    int* bucketBase = (int*)(ws + OFF_BBASE);
    int* perm     = (int*)(ws + OFF_PERM);     // inside xp span; dead before kgather2 writes xp
    int* dbin     = (int*)(ws + OFF_STATS);    // zeroed
    int* dcur     = dbin + 64;

    const int* src1 = ei;
    const int* dst1 = ei + EE;
    const int* src2 = ei2;
    const int* dst2 = ei2 + EE2;
    const int* a0   = ai2;

    hipMemsetAsync(ws + OFF_CNT1, 0, ZERO_BYTES, stream);

    // bucketed CSR build: LDS ranks + 90K global atomics
    kbA<<<600, 256, 0, stream>>>(src1, dst1, ea, src2, dst2, bucketCnt, rec1, rec2);
    kiso<<<NN2 / 256, 256, 0, stream>>>(iso, isoIdx);
    kprepx<<<12848, 256, 0, stream>>>(x, embW, embB, h, gW1, gW2,
                                      w1h, w1l, w2h, w2l,
                                      i1rW, i1tW, i2rW, i2tW, gcwh, gcwl);
    kbscan<<<2, 256, 0, stream>>>(bucketCnt, bucketBase);
    kbB<<<300, 256, 0, stream>>>(bucketCnt, bucketBase, rec1, rec2,
                                 offs1, col1, offs2, col2, dbin);
    kdegplace<<<NN / 256, 256, 0, stream>>>(offs1, dbin, dcur, perm);

    // GIN layers: fused gather+MLP (minimal gather chain); ktrans streaming BN between layers;
    // h ping-pong (layer 4 lands in hA = h2, raw for the branch)
    for (int l = 0; l < LL; ++l) {
        const float* hin = (l == 0) ? h : ((l & 1) ? hA : hB);
        float* hout = (l & 1) ? hB : hA;
        kglayer<<<NN / 16, 256, 0, stream>>>(
            hin, hout, perm, offs1, col1, ee1 + l * 384, ee2 + l * 192,
            w1h + (size_t)l * 8192, w1l + (size_t)l * 8192,
            w2h + (size_t)l * 8192, w2l + (size_t)l * 8192,
            gB1 + l * 128, gB2 + l * 64,
            pstat2 + (size_t)l * 4096);
        if (l < LL - 1)
            ktrans<<<800, 256, 0, stream>>>(hout, pstat2 + (size_t)l * 4096,
                                            bng + l * 64, bnb + l * 64);
    }

    // 2-set branch, layer 1 (avg-pool + final-layer BN fused into kgcmm1 staging; MFMA GEMMs)
    kgcmm1<<<NN2 / 64, 256, 0, stream>>>(gcwh, gcwl, gcwh + 4096, gcwl + 4096,
                                         i1rW + 64 * 64, i1tW + 64 * 64, isoIdx,
                                         yrel, yroot,
                                         pstat2 + (size_t)4 * 4096,
                                         bng + 4 * 64, bnb + 4 * 64, a0, h2);
    kgather2<<<NN2 * 16 / 256, 256, 0, stream>>>(yrel, yroot, i1rB, offs2, col2, xp);
    // layer 2: gather-first (matches reference order), fused dual-GEMM single output
    kgather2raw<<<NN2 * 16 / 256, 256, 0, stream>>>(xp, offs2, col2, aggb);
    kgcmm2<<<NN2 / 64, 256, 0, stream>>>(aggb, xp,
                                         gcwh + 8192, gcwl + 8192, gcwh + 12288, gcwl + 12288,
                                         i2rB, xp2);

    // pools + readout
    kpoolg<<<GG, 256, 0, stream>>>(h2, xp2, pstat2 + (size_t)4 * 4096,
                                   bng + 4 * 64, bnb + 4 * 64, mbuf);
    kread<<<GG, 64, 0, stream>>>(mbuf, roW0, roB0, roW1, roB1, roW2, roB2, lW, lB, out);
}

// Round 10
// 529.289 us; speedup vs baseline: 1.1312x; 1.0738x over previous
//
#include <hip/hip_runtime.h>

#define NN   51200
#define EE   819200
#define GG   256
#define NN2  102400
#define AA   204800
#define EE2  409600
#define DD   64
#define LL   5

// bucket CSR build
#define NB1  100
#define NB2  200
#define CAP1 10240
#define CAP2 3072

typedef __attribute__((ext_vector_type(8))) short bf16x8;
typedef __attribute__((ext_vector_type(4))) float f32x4;
typedef unsigned short ushort_t;

// ---------------- workspace layout (bytes) ----------------
#define OFF_H      ((size_t)0)          // bf16 h (6.5MB); post-GIN: bf16 yrel (13MB); then fp32 agg (26MB)
#define OFF_AGG    ((size_t)13107200)   // GIN: raw fp32 layer output (consumed by ktrans)
#define OFF_H2     ((size_t)26214400)   // layer-4 raw fp32 output = h2 (alive to kpoolg)
#define OFF_XP     ((size_t)39321600)   // rec1/rec2 during CSR build; later bf16 xp (13MB)
#define OFF_REC1   OFF_XP                       // 100*10240*8 = 8,192,000
#define OFF_REC2   ((size_t)47513600)           // 200*3072*8  = 4,915,200 (ends 52,428,800)
#define OFF_PERM   ((size_t)60293120)   // perm (200KB); dead region between rec end and OFF_YROOT
#define OFF_YROOT  ((size_t)65536000)   // GIN bf16 weights during GIN; yroot after; then xp2 (26MB)
#define OFF_OFFS1  ((size_t)91750400)
#define OFF_COL1   ((size_t)91955216)
#define OFF_OFFS2  ((size_t)95232016)
#define OFF_COL2   ((size_t)95641632)
#define OFF_CNT1   ((size_t)97280032)   // zeroed region starts here; bucketCnt[300] lives here
#define OFF_BBASE  ((size_t)97282080)   // bucketBase[300]
#define OFF_CUR1   ((size_t)97484832)   // pstat2[5][32][128] (zeroed by memset)
#define OFF_STATS  ((size_t)98508832)   // dbin[64], dcur[64] (zeroed)
#define ZERO_BYTES ((size_t)1231360)
#define OFF_ISO    ((size_t)98511392)
#define OFF_M      ((size_t)98920992)   // graphconv bf16 weight frags (64KB, die before kpoolg); then mbuf
#define WS_NEEDED  ((size_t)99052064)

__device__ __forceinline__ int waveInclScan(int v, int lane) {
#pragma unroll
    for (int off = 1; off < 64; off <<= 1) {
        int t = __shfl_up(v, off, 64);
        if (lane >= off) v += t;
    }
    return v;
}

// ---------------- bf16 helpers ----------------
__device__ __forceinline__ void bsplit(float x, ushort_t& hi, ushort_t& lo) {
    union { float f; unsigned u; } a; a.f = x;
    unsigned hb = (a.u + 0x7FFFu + ((a.u >> 16) & 1u)) >> 16;   // RNE to bf16
    union { unsigned u; float f; } h; h.u = hb << 16;
    float r = x - h.f;
    union { float f; unsigned u; } b; b.f = r;
    unsigned lb = (b.u + 0x7FFFu + ((b.u >> 16) & 1u)) >> 16;
    hi = (ushort_t)hb; lo = (ushort_t)lb;
}
__device__ __forceinline__ ushort_t f2bf(float x) {
    union { float f; unsigned u; } a; a.f = x;
    return (ushort_t)((a.u + 0x7FFFu + ((a.u >> 16) & 1u)) >> 16);
}
__device__ __forceinline__ float bf2f(ushort_t v) {
    union { unsigned u; float f; } t; t.u = (unsigned)v << 16; return t.f;
}

// ---------------- bucket build phase A: scatter edges by dst>>9 ----------------
__global__ __launch_bounds__(256) void kbA(const int* __restrict__ src1, const int* __restrict__ dst1,
                                           const int* __restrict__ ea,
                                           const int* __restrict__ src2, const int* __restrict__ dst2,
                                           int* __restrict__ bucketCnt,
                                           int2* __restrict__ rec1, int2* __restrict__ rec2) {
    __shared__ int lhist[256];
    __shared__ int lbase[256];
    int tid = threadIdx.x, b = blockIdx.x;
    lhist[tid] = 0;
    __syncthreads();
    if (b < 400) {
        int i = (b * 256 + tid) * 8;
        int4 d0 = *(const int4*)(dst1 + i);
        int4 d1 = *(const int4*)(dst1 + i + 4);
        int dst[8] = {d0.x, d0.y, d0.z, d0.w, d1.x, d1.y, d1.z, d1.w};
        int bin[8], lr[8];
#pragma unroll
        for (int j = 0; j < 8; ++j) {
            bin[j] = dst[j] >> 9;
            lr[j] = atomicAdd(&lhist[bin[j]], 1);
        }
        __syncthreads();
        if (tid < NB1) {
            int c = lhist[tid];
            lbase[tid] = c ? atomicAdd(&bucketCnt[tid], c) : 0;
        }
        __syncthreads();
        int4 s0 = *(const int4*)(src1 + i);
        int4 s1 = *(const int4*)(src1 + i + 4);
        int src[8] = {s0.x, s0.y, s0.z, s0.w, s1.x, s1.y, s1.z, s1.w};
        int4 e0 = *(const int4*)(ea + 2 * i);
        int4 e1 = *(const int4*)(ea + 2 * i + 4);
        int4 e2 = *(const int4*)(ea + 2 * i + 8);
        int4 e3 = *(const int4*)(ea + 2 * i + 12);
        int code[8] = {e0.x * 3 + e0.y, e0.z * 3 + e0.w, e1.x * 3 + e1.y, e1.z * 3 + e1.w,
                       e2.x * 3 + e2.y, e2.z * 3 + e2.w, e3.x * 3 + e3.y, e3.z * 3 + e3.w};
#pragma unroll
        for (int j = 0; j < 8; ++j) {
            int pos = bin[j] * CAP1 + lbase[bin[j]] + lr[j];
            rec1[pos] = make_int2(src[j] | (code[j] << 16), dst[j]);
        }
    } else {
        int i = ((b - 400) * 256 + tid) * 8;
        int4 d0 = *(const int4*)(dst2 + i);
        int4 d1 = *(const int4*)(dst2 + i + 4);
        int dst[8] = {d0.x, d0.y, d0.z, d0.w, d1.x, d1.y, d1.z, d1.w};
        int bin[8], lr[8];
#pragma unroll
        for (int j = 0; j < 8; ++j) {
            bin[j] = dst[j] >> 9;
            lr[j] = atomicAdd(&lhist[bin[j]], 1);
        }
        __syncthreads();
        if (tid < NB2) {
            int c = lhist[tid];
            lbase[tid] = c ? atomicAdd(&bucketCnt[NB1 + tid], c) : 0;
        }
        __syncthreads();
        int4 s0 = *(const int4*)(src2 + i);
        int4 s1 = *(const int4*)(src2 + i + 4);
        int src[8] = {s0.x, s0.y, s0.z, s0.w, s1.x, s1.y, s1.z, s1.w};
#pragma unroll
        for (int j = 0; j < 8; ++j) {
            int pos = bin[j] * CAP2 + lbase[bin[j]] + lr[j];
            rec2[pos] = make_int2(src[j], dst[j]);
        }
    }
}

// exclusive scan of bucket counts (block 0: g1's 100, block 1: g2's 200)
__global__ void kbscan(const int* __restrict__ bucketCnt, int* __restrict__ bucketBase) {
    __shared__ int wsum[4];
    int tid = threadIdx.x, lane = tid & 63, wid = tid >> 6;
    int nb = blockIdx.x ? NB2 : NB1;
    const int* cnt = bucketCnt + (blockIdx.x ? NB1 : 0);
    int* base = bucketBase + (blockIdx.x ? NB1 : 0);
    int v = (tid < nb) ? cnt[tid] : 0;
    int incl = waveInclScan(v, lane);
    if (lane == 63) wsum[wid] = incl;
    __syncthreads();
    int woff = 0;
#pragma unroll
    for (int w = 0; w < 3; ++w) woff += (w < wid) ? wsum[w] : 0;
    if (tid < nb) base[tid] = woff + incl - v;
}

// ---------------- bucket build phase B: per-bucket CSR (LDS hist + scan + place) ----------------
__global__ __launch_bounds__(256) void kbB(const int* __restrict__ bucketCnt,
                                           const int* __restrict__ bucketBase,
                                           const int2* __restrict__ rec1, const int2* __restrict__ rec2,
                                           int* __restrict__ offs1, int* __restrict__ col1,
                                           int* __restrict__ offs2, int* __restrict__ col2,
                                           int* __restrict__ dbin) {
    __shared__ int nh[512];
    __shared__ int ncur[512];
    __shared__ int wsum[4];
    __shared__ int dhist[64];
    int tid = threadIdx.x, b = blockIdx.x;
    bool g1 = b < NB1;
    const int2* rec = g1 ? (rec1 + (size_t)b * CAP1) : (rec2 + (size_t)(b - NB1) * CAP2);
    int cnt = bucketCnt[b];
    int base = bucketBase[b];
    int* offs = g1 ? offs1 : offs2;
    int* col = g1 ? col1 : col2;
    int nodeBase = g1 ? b * 512 : (b - NB1) * 512;
    nh[tid] = 0; nh[tid + 256] = 0;
    if (tid < 64) dhist[tid] = 0;
    __syncthreads();
    for (int e = tid; e < cnt; e += 256) {
        int2 r = rec[e];
        atomicAdd(&nh[r.y & 511], 1);
    }
    __syncthreads();
    int v0 = nh[2 * tid], v1 = nh[2 * tid + 1];
    int s = v0 + v1;
    int lane = tid & 63, wid = tid >> 6;
    int incl = waveInclScan(s, lane);
    if (lane == 63) wsum[wid] = incl;
    __syncthreads();
    int woff = 0;
#pragma unroll
    for (int w = 0; w < 3; ++w) woff += (w < wid) ? wsum[w] : 0;
    int excl = woff + incl - s;
    ncur[2 * tid] = excl;
    ncur[2 * tid + 1] = excl + v0;
    offs[nodeBase + 2 * tid] = base + excl;
    offs[nodeBase + 2 * tid + 1] = base + excl + v0;
    if (g1) {
        atomicAdd(&dhist[v0 < 63 ? v0 : 63], 1);
        atomicAdd(&dhist[v1 < 63 ? v1 : 63], 1);
    }
    __syncthreads();
    for (int e = tid; e < cnt; e += 256) {
        int2 r = rec[e];
        int node = r.y & 511;
        int slot = base + atomicAdd(&ncur[node], 1);
        col[slot] = r.x;
    }
    if (g1 && tid < 64 && dhist[tid]) atomicAdd(&dbin[tid], dhist[tid]);
    if (tid == 0) {
        if (b == NB1 - 1) offs1[NN] = EE;
        if (b == NB1 + NB2 - 1) offs2[NN2] = EE2;
    }
}

// ---------------- iso argmax: LDS-staged coalesced reads ----------------
__global__ __launch_bounds__(256) void kiso(const float* __restrict__ iso, int* __restrict__ isoIdx) {
    __shared__ float srow[256 * 36];
    int tid = threadIdx.x;
    int base = blockIdx.x * 256;
    const float4* g4p = (const float4*)(iso + (size_t)base * 36);
#pragma unroll
    for (int i = tid; i < 2304; i += 256) ((float4*)srow)[i] = g4p[i];
    __syncthreads();
    const float* r = srow + tid * 36;
    int best = 0;
#pragma unroll
    for (int k = 0; k < 36; ++k)
        if (r[k] > 0.5f) best = k;
    isoIdx[base + tid] = best;
}

// ---------------- prep: embedding (bf16 out) + GIN weight prep + GraphConv weight prep ----------------
__global__ void kprepx(const float* __restrict__ x, const float* __restrict__ embW,
                       const float* __restrict__ embB, ushort_t* __restrict__ hbf,
                       const float* __restrict__ gW1, const float* __restrict__ gW2,
                       ushort_t* __restrict__ w1h, ushort_t* __restrict__ w1l,
                       ushort_t* __restrict__ w2h, ushort_t* __restrict__ w2l,
                       const float* __restrict__ i1rW, const float* __restrict__ i1tW,
                       const float* __restrict__ i2rW, const float* __restrict__ i2tW,
                       ushort_t* __restrict__ gcwh, ushort_t* __restrict__ gcwl) {
    int b = blockIdx.x;
    if (b < 12800) {
        int t = b * 256 + threadIdx.x;
        int n = t >> 6, d = t & 63;
        float acc = embB[d];
        const float4* xr4 = (const float4*)(x + (size_t)n * 40);
#pragma unroll
        for (int k4 = 0; k4 < 10; ++k4) {
            float4 xv = xr4[k4];
            acc = fmaf(xv.x, embW[(4 * k4 + 0) * 64 + d], acc);
            acc = fmaf(xv.y, embW[(4 * k4 + 1) * 64 + d], acc);
            acc = fmaf(xv.z, embW[(4 * k4 + 2) * 64 + d], acc);
            acc = fmaf(xv.w, embW[(4 * k4 + 3) * 64 + d], acc);
        }
        hbf[(size_t)n * 64 + d] = f2bf(fmaxf(acc, 0.f));
    } else if (b < 12840) {
        int t = (b - 12800) * 256 + threadIdx.x;
        int lane = t & 63, frag = t >> 6;
        int c15 = lane & 15, q = lane >> 4;
        if (frag < 80) {
            int kt = frag & 1, nt = (frag >> 1) & 7, l = frag >> 4;
            const float* W = gW1 + l * 8192;
            ushort_t* oh = w1h + ((size_t)frag * 64 + lane) * 8;
            ushort_t* ol = w1l + ((size_t)frag * 64 + lane) * 8;
            int kb = kt * 32 + q * 8, colw = nt * 16 + c15;
#pragma unroll
            for (int j = 0; j < 8; ++j) {
                ushort_t hi, lo; bsplit(W[(kb + j) * 128 + colw], hi, lo);
                oh[j] = hi; ol[j] = lo;
            }
        } else if (frag < 160) {
            int f = frag - 80;
            int kt = f & 3, nt = (f >> 2) & 3, l = f >> 4;
            const float* W = gW2 + l * 8192;
            ushort_t* oh = w2h + ((size_t)f * 64 + lane) * 8;
            ushort_t* ol = w2l + ((size_t)f * 64 + lane) * 8;
            int kb = kt * 32 + q * 8, colw = nt * 16 + c15;
#pragma unroll
            for (int j = 0; j < 8; ++j) {
                ushort_t hi, lo; bsplit(W[(kb + j) * 64 + colw], hi, lo);
                oh[j] = hi; ol[j] = lo;
            }
        }
    } else {
        // GraphConv weight prep: 4 matrices x 8 frags (K=64, N=64)
        int t = (b - 12840) * 256 + threadIdx.x;   // 0..2047
        int lane = t & 63, frag = t >> 6;          // frag 0..31
        int c15 = lane & 15, q = lane >> 4;
        int m = frag >> 3, f = frag & 7;
        int kt = f & 1, nt = f >> 1;
        const float* W = (m == 0) ? i1rW : (m == 1) ? i1tW : (m == 2) ? i2rW : i2tW;
        ushort_t* oh = gcwh + (size_t)m * 4096 + ((size_t)f * 64 + lane) * 8;
        ushort_t* ol = gcwl + (size_t)m * 4096 + ((size_t)f * 64 + lane) * 8;
        int kb = kt * 32 + q * 8, colw = nt * 16 + c15;
#pragma unroll
        for (int j = 0; j < 8; ++j) {
            ushort_t hi, lo; bsplit(W[(kb + j) * 64 + colw], hi, lo);
            oh[j] = hi; ol[j] = lo;
        }
    }
}

// two-level counting-sort placement; dstart computed inline from dbin (ascending)
__global__ __launch_bounds__(256) void kdegplace(const int* __restrict__ offs,
                                                 const int* __restrict__ dbin,
                                                 int* __restrict__ dcur,
                                                 int* __restrict__ perm) {
    __shared__ int lhist[64];
    __shared__ int lbase[64];
    __shared__ int sdstart[64];
    int tid = threadIdx.x;
    if (tid < 64) {
        lhist[tid] = 0;
        int v = dbin[tid];
        int incl = waveInclScan(v, tid);
        sdstart[tid] = incl - v;
    }
    __syncthreads();
    int n = blockIdx.x * 256 + tid;
    int d = offs[n + 1] - offs[n]; d = d < 63 ? d : 63;
    int lr = atomicAdd(&lhist[d], 1);
    __syncthreads();
    if (tid < 64) {
        int c = lhist[tid];
        lbase[tid] = c ? atomicAdd(&dcur[tid], c) : 0;
    }
    __syncthreads();
    perm[sdstart[d] + lbase[d] + lr] = n;
}

// ---------------- per-node BN+ReLU transform: fp32 raw -> bf16 (for next layer's gather) ----------------
__global__ __launch_bounds__(256) void ktrans(const float* __restrict__ hraw,
                                              ushort_t* __restrict__ hbf,
                                              const float* __restrict__ pst,
                                              const float* __restrict__ gamma,
                                              const float* __restrict__ beta) {
    __shared__ float sstat[128];
    __shared__ float sSC[64], sSH[64];
    int tid = threadIdx.x;
    if (tid < 128) {
        float s = 0.f;
        const float* p = pst + tid;
#pragma unroll
        for (int i = 0; i < 32; ++i) s += p[i * 128];
        sstat[tid] = s;
    }
    __syncthreads();
    if (tid < 64) {
        float mu = sstat[tid] * (1.f / NN);
        float var = sstat[64 + tid] * (1.f / NN) - mu * mu;
        float sc = gamma[tid] * rsqrtf(var + 1e-5f);
        sSC[tid] = sc; sSH[tid] = beta[tid] - mu * sc;
    }
    __syncthreads();
    int c = (tid & 15) * 4;
    float4 sc4 = *(const float4*)(sSC + c);
    float4 sh4 = *(const float4*)(sSH + c);
    const float4* hp = (const float4*)hraw;
    ushort4* op = (ushort4*)hbf;
    size_t base = (size_t)blockIdx.x * 1024 + tid;
#pragma unroll
    for (int r = 0; r < 4; ++r) {
        float4 v = hp[base + r * 256];
        ushort4 o;
        o.x = f2bf(fmaxf(fmaf(v.x, sc4.x, sh4.x), 0.f));
        o.y = f2bf(fmaxf(fmaf(v.y, sc4.y, sh4.y), 0.f));
        o.z = f2bf(fmaxf(fmaf(v.z, sc4.z, sh4.z), 0.f));
        o.w = f2bf(fmaxf(fmaf(v.w, sc4.w, sh4.w), 0.f));
        op[base + r * 256] = o;
    }
}

// ---------------- fused GIN layer: bf16 gather(16 perm'd nodes) -> LDS -> MFMA MLP -> fp32 hout + stats ----
__global__ __launch_bounds__(256) void kglayer(
    const ushort_t* __restrict__ hin, float* __restrict__ hout,
    const int* __restrict__ perm,
    const int* __restrict__ offs, const int* __restrict__ col,
    const float* __restrict__ e1, const float* __restrict__ e2,
    const ushort_t* __restrict__ w1h, const ushort_t* __restrict__ w1l,
    const ushort_t* __restrict__ w2h, const ushort_t* __restrict__ w2l,
    const float* __restrict__ b1, const float* __restrict__ b2,
    float* __restrict__ pstout) {
    __shared__ float etab[13 * 64];
    __shared__ int sPerm[16];
    __shared__ float sMLP[16 * 132];   // sA stride-68 aliases front; sH stride-132
    float* sA = sMLP;
    float* sH = sMLP;
    int tid = threadIdx.x;
    if (tid < 16) sPerm[tid] = perm[blockIdx.x * 16 + tid];
    for (int idx = tid; idx < 13 * 64; idx += 256) {
        int ci = idx >> 6, dd = idx & 63;
        etab[idx] = e1[(ci / 3) * 64 + dd] + e2[(ci % 3) * 64 + dd];
    }
    __syncthreads();
    int lane = tid & 63, wv = tid >> 6;
    int c15 = lane & 15, q = lane >> 4;

    // ---- gather node n into sA (bf16 rows, 128 B each) ----
    {
        int n = sPerm[wv * 4 + q];
        int s0 = offs[n], s1 = offs[n + 1];
        ushort4 sx = *(const ushort4*)(hin + (size_t)n * 64 + 4 * c15);
        float4 et = *(const float4*)(etab + 12 * 64 + 4 * c15);
        float a0 = bf2f(sx.x) + et.x, a1 = bf2f(sx.y) + et.y;
        float a2 = bf2f(sx.z) + et.z, a3 = bf2f(sx.w) + et.w;
        int deg = s1 - s0;
        if (deg > 0) {
            const int* cp = col + s0;
            int nfull = deg >> 3, rem = deg & 7;
            int vv[8];
#pragma unroll
            for (int j = 0; j < 8; ++j) {
                int idx = j < deg ? j : deg - 1;
                vv[j] = cp[idx];
            }
            for (int it = 0; it < nfull; ++it) {
                ushort4 xv[8];
                float4 tv[8];
#pragma unroll
                for (int j = 0; j < 8; ++j) {
                    xv[j] = *(const ushort4*)(hin + (size_t)(vv[j] & 0xFFFF) * 64 + 4 * c15);
                    tv[j] = *(const float4*)(etab + (vv[j] >> 16) * 64 + 4 * c15);
                }
                int e8 = (it + 1) * 8;
                bool more = e8 < deg;
                int nx[8];
                if (more) {
#pragma unroll
                    for (int j = 0; j < 8; ++j) {
                        int idx = e8 + j; idx = idx < deg ? idx : deg - 1;
                        nx[j] = cp[idx];
                    }
                }
#pragma unroll
                for (int j = 0; j < 8; ++j) {
                    a0 += bf2f(xv[j].x) + tv[j].x;
                    a1 += bf2f(xv[j].y) + tv[j].y;
                    a2 += bf2f(xv[j].z) + tv[j].z;
                    a3 += bf2f(xv[j].w) + tv[j].w;
                }
                if (more) {
#pragma unroll
                    for (int j = 0; j < 8; ++j) vv[j] = nx[j];
                }
            }
            if (rem) {
                ushort4 xv[8];
                float4 tv[8];
#pragma unroll
                for (int j = 0; j < 8; ++j) {
                    xv[j] = *(const ushort4*)(hin + (size_t)(vv[j] & 0xFFFF) * 64 + 4 * c15);
                    tv[j] = *(const float4*)(etab + (vv[j] >> 16) * 64 + 4 * c15);
                }
#pragma unroll
                for (int j = 0; j < 8; ++j) {
                    float mm = (j < rem) ? 1.f : 0.f;
                    a0 = fmaf(bf2f(xv[j].x) + tv[j].x, mm, a0);
                    a1 = fmaf(bf2f(xv[j].y) + tv[j].y, mm, a1);
                    a2 = fmaf(bf2f(xv[j].z) + tv[j].z, mm, a2);
                    a3 = fmaf(bf2f(xv[j].w) + tv[j].w, mm, a3);
                }
            }
        }
        *(float4*)(sA + (wv * 4 + q) * 68 + 4 * c15) = make_float4(a0, a1, a2, a3);
    }
    __syncthreads();

    // ---- A-frags to regs (sA dies after next sync; sH aliases) ----
    bf16x8 ah[2], al[2];
#pragma unroll
    for (int kt = 0; kt < 2; ++kt) {
        const float* p = sA + c15 * 68 + kt * 32 + q * 8;
        float4 x0 = *(const float4*)p;
        float4 x1 = *(const float4*)(p + 4);
        float xs[8] = {x0.x, x0.y, x0.z, x0.w, x1.x, x1.y, x1.z, x1.w};
#pragma unroll
        for (int j = 0; j < 8; ++j) {
            ushort_t hi, lo; bsplit(xs[j], hi, lo);
            ah[kt][j] = (short)hi; al[kt][j] = (short)lo;
        }
    }
    __syncthreads();

    // ---- GEMM1: nt = 2wv+j ----
    f32x4 acc1[2];
#pragma unroll
    for (int j = 0; j < 2; ++j) { f32x4 z = {0.f, 0.f, 0.f, 0.f}; acc1[j] = z; }
#pragma unroll
    for (int kt = 0; kt < 2; ++kt) {
#pragma unroll
        for (int j = 0; j < 2; ++j) {
            int nt = 2 * wv + j;
            size_t fo = ((size_t)((nt * 2 + kt) * 64 + lane)) * 8;
            bf16x8 bh = *(const bf16x8*)(w1h + fo);
            bf16x8 bl = *(const bf16x8*)(w1l + fo);
            acc1[j] = __builtin_amdgcn_mfma_f32_16x16x32_bf16(ah[kt], bh, acc1[j], 0, 0, 0);
            acc1[j] = __builtin_amdgcn_mfma_f32_16x16x32_bf16(al[kt], bh, acc1[j], 0, 0, 0);
            acc1[j] = __builtin_amdgcn_mfma_f32_16x16x32_bf16(ah[kt], bl, acc1[j], 0, 0, 0);
        }
    }
#pragma unroll
    for (int j = 0; j < 2; ++j) {
        int nt = 2 * wv + j;
        float bias = b1[nt * 16 + c15];
#pragma unroll
        for (int rg = 0; rg < 4; ++rg)
            sH[(4 * q + rg) * 132 + nt * 16 + c15] = fmaxf(acc1[j][rg] + bias, 0.f);
    }
    __syncthreads();

    // ---- GEMM2: nt = wv ----
    f32x4 acc2 = {0.f, 0.f, 0.f, 0.f};
#pragma unroll
    for (int kt = 0; kt < 4; ++kt) {
        const float* p = sH + c15 * 132 + kt * 32 + q * 8;
        float4 x0 = *(const float4*)p;
        float4 x1 = *(const float4*)(p + 4);
        float xs[8] = {x0.x, x0.y, x0.z, x0.w, x1.x, x1.y, x1.z, x1.w};
        bf16x8 a2h, a2l;
#pragma unroll
        for (int j = 0; j < 8; ++j) {
            ushort_t hi, lo; bsplit(xs[j], hi, lo);
            a2h[j] = (short)hi; a2l[j] = (short)lo;
        }
        size_t fo = ((size_t)((wv * 4 + kt) * 64 + lane)) * 8;
        bf16x8 bh = *(const bf16x8*)(w2h + fo);
        bf16x8 bl = *(const bf16x8*)(w2l + fo);
        acc2 = __builtin_amdgcn_mfma_f32_16x16x32_bf16(a2h, bh, acc2, 0, 0, 0);
        acc2 = __builtin_amdgcn_mfma_f32_16x16x32_bf16(a2l, bh, acc2, 0, 0, 0);
        acc2 = __builtin_amdgcn_mfma_f32_16x16x32_bf16(a2h, bl, acc2, 0, 0, 0);
    }
    {
        float bias = b2[wv * 16 + c15];
        float s = 0.f, s2 = 0.f;
#pragma unroll
        for (int rg = 0; rg < 4; ++rg) {
            float v = acc2[rg] + bias;
            hout[(size_t)sPerm[4 * q + rg] * 64 + wv * 16 + c15] = v;
            s += v; s2 += v * v;
        }
        s += __shfl_xor(s, 16, 64);  s += __shfl_xor(s, 32, 64);
        s2 += __shfl_xor(s2, 16, 64); s2 += __shfl_xor(s2, 32, 64);
        if (q == 0) {
            float* ps = pstout + (size_t)(blockIdx.x & 31) * 128;
            atomicAdd(&ps[wv * 16 + c15], s);
            atomicAdd(&ps[64 + wv * 16 + c15], s2);
        }
    }
}

// ---------------- GraphConv1 GEMMs via split-bf16 MFMA (writes bf16 yrel, fp32 yroot) ----------------
__global__ __launch_bounds__(256) void kgcmm1(const ushort_t* __restrict__ grh,
                                              const ushort_t* __restrict__ grl,
                                              const ushort_t* __restrict__ gth,
                                              const ushort_t* __restrict__ gtl,
                                              const float* __restrict__ WrelIso,
                                              const float* __restrict__ WrootIso,
                                              const int* __restrict__ isoIdx,
                                              ushort_t* __restrict__ Yrel,
                                              float* __restrict__ Yroot,
                                              const float* __restrict__ pst,
                                              const float* __restrict__ g4,
                                              const float* __restrict__ b4,
                                              const int* __restrict__ a0g,
                                              const float* __restrict__ h2src) {
    __shared__ float sX[64 * 68];
    __shared__ float sstat[128];
    __shared__ float sSC[64], sSH[64];
    int tid = threadIdx.x, blk = blockIdx.x;
    if (tid < 128) {
        float s = 0.f;
        const float* p = pst + tid;
#pragma unroll
        for (int i = 0; i < 32; ++i) s += p[i * 128];
        sstat[tid] = s;
    }
    __syncthreads();
    if (tid < 64) {
        float mu = sstat[tid] * (1.f / NN);
        float var = sstat[64 + tid] * (1.f / NN) - mu * mu;
        float sc = g4[tid] * rsqrtf(var + 1e-5f);
        sSC[tid] = sc;
        sSH[tid] = b4[tid] - mu * sc;
    }
    __syncthreads();
#pragma unroll
    for (int i = tid; i < 1024; i += 256) {
        int row = i >> 4, c = (i & 15) << 2;
        int grow = blk * 64 + row;
        int na = a0g[2 * grow], nb = a0g[2 * grow + 1];
        float4 va = *(const float4*)(h2src + (size_t)na * 64 + c);
        float4 vb = *(const float4*)(h2src + (size_t)nb * 64 + c);
        float4 v;
        v.x = 0.5f * (va.x + vb.x); v.y = 0.5f * (va.y + vb.y);
        v.z = 0.5f * (va.z + vb.z); v.w = 0.5f * (va.w + vb.w);
        v.x = fmaf(v.x, sSC[c], sSH[c]);
        v.y = fmaf(v.y, sSC[c + 1], sSH[c + 1]);
        v.z = fmaf(v.z, sSC[c + 2], sSH[c + 2]);
        v.w = fmaf(v.w, sSC[c + 3], sSH[c + 3]);
        float* p = sX + row * 68 + c;
        p[0] = v.x; p[1] = v.y; p[2] = v.z; p[3] = v.w;
    }
    __syncthreads();
    int lane = tid & 63, wv = tid >> 6;
    int c15 = lane & 15, q = lane >> 4;

    bf16x8 ah[2], al[2];
#pragma unroll
    for (int kt = 0; kt < 2; ++kt) {
        const float* p = sX + (16 * wv + c15) * 68 + kt * 32 + q * 8;
        float4 x0 = *(const float4*)p;
        float4 x1 = *(const float4*)(p + 4);
        float xs[8] = {x0.x, x0.y, x0.z, x0.w, x1.x, x1.y, x1.z, x1.w};
#pragma unroll
        for (int j = 0; j < 8; ++j) {
            ushort_t hi, lo; bsplit(xs[j], hi, lo);
            ah[kt][j] = (short)hi; al[kt][j] = (short)lo;
        }
    }

    f32x4 accR[4], accT[4];
#pragma unroll
    for (int nt = 0; nt < 4; ++nt) {
        f32x4 z = {0.f, 0.f, 0.f, 0.f};
        accR[nt] = z; accT[nt] = z;
    }
#pragma unroll
    for (int nt = 0; nt < 4; ++nt) {
#pragma unroll
        for (int kt = 0; kt < 2; ++kt) {
            size_t fo = ((size_t)((nt * 2 + kt) * 64 + lane)) * 8;
            bf16x8 bh = *(const bf16x8*)(grh + fo);
            bf16x8 bl = *(const bf16x8*)(grl + fo);
            accR[nt] = __builtin_amdgcn_mfma_f32_16x16x32_bf16(ah[kt], bh, accR[nt], 0, 0, 0);
            accR[nt] = __builtin_amdgcn_mfma_f32_16x16x32_bf16(al[kt], bh, accR[nt], 0, 0, 0);
            accR[nt] = __builtin_amdgcn_mfma_f32_16x16x32_bf16(ah[kt], bl, accR[nt], 0, 0, 0);
            bf16x8 ch = *(const bf16x8*)(gth + fo);
            bf16x8 cl = *(const bf16x8*)(gtl + fo);
            accT[nt] = __builtin_amdgcn_mfma_f32_16x16x32_bf16(ah[kt], ch, accT[nt], 0, 0, 0);
            accT[nt] = __builtin_amdgcn_mfma_f32_16x16x32_bf16(al[kt], ch, accT[nt], 0, 0, 0);
            accT[nt] = __builtin_amdgcn_mfma_f32_16x16x32_bf16(ah[kt], cl, accT[nt], 0, 0, 0);
        }
    }

    int rbase = blk * 64 + 16 * wv + 4 * q;
#pragma unroll
    for (int rg = 0; rg < 4; ++rg) {
        int row = rbase + rg;
        int ii = isoIdx[row];
        ushort_t* yr = Yrel + (size_t)row * 64;
        float* yt = Yroot + (size_t)row * 64;
        const float* er = WrelIso + (size_t)ii * 64;
        const float* et = WrootIso + (size_t)ii * 64;
#pragma unroll
        for (int nt = 0; nt < 4; ++nt) {
            int cc = nt * 16 + c15;
            yr[cc] = f2bf(accR[nt][rg] + er[cc]);
            yt[cc] = accT[nt][rg] + et[cc];
        }
    }
}

// ---------------- GraphConv2 fused: OUT = relu(AGG @ Wrel + brel + XP @ Wroot), XP is bf16 ----------------
__global__ __launch_bounds__(256) void kgcmm2(const float* __restrict__ AGG,
                                              const ushort_t* __restrict__ XP,
                                              const ushort_t* __restrict__ grh,
                                              const ushort_t* __restrict__ grl,
                                              const ushort_t* __restrict__ gth,
                                              const ushort_t* __restrict__ gtl,
                                              const float* __restrict__ brel,
                                              float* __restrict__ OUT) {
    __shared__ float sA[64 * 68];
    __shared__ float sB[64 * 68];
    int tid = threadIdx.x, blk = blockIdx.x;
#pragma unroll
    for (int i = tid; i < 1024; i += 256) {
        int row = i >> 4, c = (i & 15) << 2;
        float4 va = ((const float4*)(AGG + (size_t)blk * 4096))[i];
        ushort4 vb4 = ((const ushort4*)(XP + (size_t)blk * 4096))[i];
        float* pa = sA + row * 68 + c;
        float* pb = sB + row * 68 + c;
        pa[0] = va.x; pa[1] = va.y; pa[2] = va.z; pa[3] = va.w;
        pb[0] = bf2f(vb4.x); pb[1] = bf2f(vb4.y); pb[2] = bf2f(vb4.z); pb[3] = bf2f(vb4.w);
    }
    __syncthreads();
    int lane = tid & 63, wv = tid >> 6;
    int c15 = lane & 15, q = lane >> 4;

    bf16x8 aAh[2], aAl[2], aBh[2];
#pragma unroll
    for (int kt = 0; kt < 2; ++kt) {
        const float* pa = sA + (16 * wv + c15) * 68 + kt * 32 + q * 8;
        const float* pb = sB + (16 * wv + c15) * 68 + kt * 32 + q * 8;
        float4 a0 = *(const float4*)pa;
        float4 a1 = *(const float4*)(pa + 4);
        float4 b0 = *(const float4*)pb;
        float4 b1 = *(const float4*)(pb + 4);
        float as[8] = {a0.x, a0.y, a0.z, a0.w, a1.x, a1.y, a1.z, a1.w};
        float bs[8] = {b0.x, b0.y, b0.z, b0.w, b1.x, b1.y, b1.z, b1.w};
#pragma unroll
        for (int j = 0; j < 8; ++j) {
            ushort_t hi, lo;
            bsplit(as[j], hi, lo); aAh[kt][j] = (short)hi; aAl[kt][j] = (short)lo;
            aBh[kt][j] = (short)f2bf(bs[j]);   // XP values are bf16-exact: lo plane is zero
        }
    }

    f32x4 acc[4];
#pragma unroll
    for (int nt = 0; nt < 4; ++nt) { f32x4 z = {0.f, 0.f, 0.f, 0.f}; acc[nt] = z; }
#pragma unroll
    for (int nt = 0; nt < 4; ++nt) {
#pragma unroll
        for (int kt = 0; kt < 2; ++kt) {
            size_t fo = ((size_t)((nt * 2 + kt) * 64 + lane)) * 8;
            bf16x8 bh = *(const bf16x8*)(grh + fo);
            bf16x8 bl = *(const bf16x8*)(grl + fo);
            acc[nt] = __builtin_amdgcn_mfma_f32_16x16x32_bf16(aAh[kt], bh, acc[nt], 0, 0, 0);
            acc[nt] = __builtin_amdgcn_mfma_f32_16x16x32_bf16(aAl[kt], bh, acc[nt], 0, 0, 0);
            acc[nt] = __builtin_amdgcn_mfma_f32_16x16x32_bf16(aAh[kt], bl, acc[nt], 0, 0, 0);
            bf16x8 ch = *(const bf16x8*)(gth + fo);
            bf16x8 cl = *(const bf16x8*)(gtl + fo);
            acc[nt] = __builtin_amdgcn_mfma_f32_16x16x32_bf16(aBh[kt], ch, acc[nt], 0, 0, 0);
            acc[nt] = __builtin_amdgcn_mfma_f32_16x16x32_bf16(aBh[kt], cl, acc[nt], 0, 0, 0);
        }
    }

    int rbase = blk * 64 + 16 * wv + 4 * q;
#pragma unroll
    for (int rg = 0; rg < 4; ++rg) {
        int row = rbase + rg;
        float* yo = OUT + (size_t)row * 64;
#pragma unroll
        for (int nt = 0; nt < 4; ++nt) {
            int cc = nt * 16 + c15;
            yo[cc] = fmaxf(acc[nt][rg] + brel[cc], 0.f);
        }
    }
}

// ---------------- GraphConv gather layer1: bf16 yrel gather + fp32 root+bias+relu -> bf16 xp ----------------
__global__ void kgather2(const ushort_t* __restrict__ yrel, const float* __restrict__ yroot,
                         const float* __restrict__ brel, const int* __restrict__ offs,
                         const int* __restrict__ col, ushort_t* __restrict__ out) {
    int t = blockIdx.x * 256 + threadIdx.x;
    int j = t >> 4, c = t & 15;
    int s0 = offs[j], s1 = offs[j + 1];
    float4 rt = *(const float4*)(yroot + (size_t)j * 64 + 4 * c);
    float4 bb = *(const float4*)(brel + 4 * c);
    float a0 = rt.x + bb.x, a1 = rt.y + bb.y, a2 = rt.z + bb.z, a3 = rt.w + bb.w;
    if (s0 < s1) {
        int vv[4];
#pragma unroll
        for (int jj = 0; jj < 4; ++jj) {
            int idx = s0 + jj; idx = idx < s1 ? idx : s1 - 1;
            vv[jj] = col[idx];
        }
        int e = s0;
        while (true) {
            int ne = e + 4;
            bool more = ne < s1;
            ushort4 xs[4];
#pragma unroll
            for (int jj = 0; jj < 4; ++jj)
                xs[jj] = *(const ushort4*)(yrel + (size_t)vv[jj] * 64 + 4 * c);
            int nx[4];
            if (more) {
#pragma unroll
                for (int jj = 0; jj < 4; ++jj) {
                    int idx = ne + jj; idx = idx < s1 ? idx : s1 - 1;
                    nx[jj] = col[idx];
                }
            }
#pragma unroll
            for (int jj = 0; jj < 4; ++jj) {
                float mm = (e + jj < s1) ? 1.f : 0.f;
                a0 = fmaf(bf2f(xs[jj].x), mm, a0);
                a1 = fmaf(bf2f(xs[jj].y), mm, a1);
                a2 = fmaf(bf2f(xs[jj].z), mm, a2);
                a3 = fmaf(bf2f(xs[jj].w), mm, a3);
            }
            if (!more) break;
            e = ne;
#pragma unroll
            for (int jj = 0; jj < 4; ++jj) vv[jj] = nx[jj];
        }
    }
    ushort4 o;
    o.x = f2bf(fmaxf(a0, 0.f));
    o.y = f2bf(fmaxf(a1, 0.f));
    o.z = f2bf(fmaxf(a2, 0.f));
    o.w = f2bf(fmaxf(a3, 0.f));
    *(ushort4*)(out + (size_t)j * 64 + 4 * c) = o;
}

// ---------------- GraphConv gather layer2: raw neighbor sums of bf16 xp -> fp32 agg ----------------
__global__ void kgather2raw(const ushort_t* __restrict__ xpsrc, const int* __restrict__ offs,
                            const int* __restrict__ col, float* __restrict__ agg) {
    int t = blockIdx.x * 256 + threadIdx.x;
    int j = t >> 4, c = t & 15;
    int s0 = offs[j], s1 = offs[j + 1];
    float a0 = 0.f, a1 = 0.f, a2 = 0.f, a3 = 0.f;
    if (s0 < s1) {
        int vv[4];
#pragma unroll
        for (int jj = 0; jj < 4; ++jj) {
            int idx = s0 + jj; idx = idx < s1 ? idx : s1 - 1;
            vv[jj] = col[idx];
        }
        int e = s0;
        while (true) {
            int ne = e + 4;
            bool more = ne < s1;
            ushort4 xs[4];
#pragma unroll
            for (int jj = 0; jj < 4; ++jj)
                xs[jj] = *(const ushort4*)(xpsrc + (size_t)vv[jj] * 64 + 4 * c);
            int nx[4];
            if (more) {
#pragma unroll
                for (int jj = 0; jj < 4; ++jj) {
                    int idx = ne + jj; idx = idx < s1 ? idx : s1 - 1;
                    nx[jj] = col[idx];
                }
            }
#pragma unroll
            for (int jj = 0; jj < 4; ++jj) {
                float mm = (e + jj < s1) ? 1.f : 0.f;
                a0 = fmaf(bf2f(xs[jj].x), mm, a0);
                a1 = fmaf(bf2f(xs[jj].y), mm, a1);
                a2 = fmaf(bf2f(xs[jj].z), mm, a2);
                a3 = fmaf(bf2f(xs[jj].w), mm, a3);
            }
            if (!more) break;
            e = ne;
#pragma unroll
            for (int jj = 0; jj < 4; ++jj) vv[jj] = nx[jj];
        }
    }
    *(float4*)(agg + (size_t)j * 64 + 4 * c) = make_float4(a0, a1, a2, a3);
}

// ---------------- per-graph mean pools (x1 gets final BN affine on the mean) ----------------
__global__ void kpoolg(const float* __restrict__ h2, const float* __restrict__ xp2,
                       const float* __restrict__ pst, const float* __restrict__ g4,
                       const float* __restrict__ b4, float* __restrict__ m) {
    __shared__ float sstat[128];
    __shared__ float red[4][64];
    int g = blockIdx.x, tid = threadIdx.x;
    if (tid < 128) {
        float s = 0.f;
        const float* p = pst + tid;
#pragma unroll
        for (int i = 0; i < 32; ++i) s += p[i * 128];
        sstat[tid] = s;
    }
    int wid = tid >> 6, d = tid & 63;
    float s1 = 0.f;
    for (int i = wid; i < 200; i += 4) s1 += h2[((size_t)g * 200 + i) * 64 + d];
    red[wid][d] = s1;
    __syncthreads();
    if (wid == 0) {
        float mean = (red[0][d] + red[1][d] + red[2][d] + red[3][d]) * (1.f / 200.f);
        float mu = sstat[d] * (1.f / NN);
        float var = sstat[64 + d] * (1.f / NN) - mu * mu;
        float sc = g4[d] * rsqrtf(var + 1e-5f);
        m[g * 128 + d] = fmaf(mean, sc, b4[d] - mu * sc);
    }
    __syncthreads();
    float s2 = 0.f;
    for (int i = wid; i < 400; i += 4) s2 += xp2[((size_t)g * 400 + i) * 64 + d];
    red[wid][d] = s2;
    __syncthreads();
    if (wid == 0) m[g * 128 + 64 + d] = (red[0][d] + red[1][d] + red[2][d] + red[3][d]) * (1.f / 400.f);
}

// ---------------- readout MLP ----------------
__global__ void kread(const float* __restrict__ m, const float* __restrict__ W0,
                      const float* __restrict__ b0, const float* __restrict__ W1,
                      const float* __restrict__ b1, const float* __restrict__ W2,
                      const float* __restrict__ b2, const float* __restrict__ lw,
                      const float* __restrict__ lb, float* __restrict__ out) {
    __shared__ float s0[64], s1[32], s2[16];
    int g = blockIdx.x, d = threadIdx.x;
    const float* mr = m + g * 128;
    float t = b0[d];
    for (int k = 0; k < 128; ++k) t = fmaf(mr[k], W0[k * 64 + d], t);
    s0[d] = fmaxf(t, 0.f);
    __syncthreads();
    if (d < 32) {
        float u = b1[d];
        for (int k = 0; k < 64; ++k) u = fmaf(s0[k], W1[k * 32 + d], u);
        s1[d] = fmaxf(u, 0.f);
    }
    __syncthreads();
    if (d < 16) {
        float u = b2[d];
        for (int k = 0; k < 32; ++k) u = fmaf(s1[k], W2[k * 16 + d], u);
        s2[d] = fmaxf(u, 0.f);
    }
    __syncthreads();
    if (d == 0) {
        float u = lb[0];
        for (int k = 0; k < 16; ++k) u = fmaf(s2[k], lw[k], u);
        out[g] = u;
    }
}

// ---------------- host ----------------
extern "C" void kernel_launch(void* const* d_in, const int* in_sizes, int n_in,
                              void* d_out, int out_size, void* d_ws, size_t ws_size,
                              hipStream_t stream) {
    if (ws_size < WS_NEEDED) return;

    const float* x    = (const float*)d_in[0];
    const int*   ei   = (const int*)d_in[1];
    const int*   ea   = (const int*)d_in[2];
    const float* iso  = (const float*)d_in[4];
    const int*   ei2  = (const int*)d_in[5];
    const int*   ai2  = (const int*)d_in[6];
    const float* embW = (const float*)d_in[8];
    const float* embB = (const float*)d_in[9];
    const float* gW1  = (const float*)d_in[10];
    const float* gB1  = (const float*)d_in[11];
    const float* gW2  = (const float*)d_in[12];
    const float* gB2  = (const float*)d_in[13];
    const float* ee1  = (const float*)d_in[14];
    const float* ee2  = (const float*)d_in[15];
    const float* bng  = (const float*)d_in[16];
    const float* bnb  = (const float*)d_in[17];
    const float* i1rW = (const float*)d_in[18];
    const float* i1rB = (const float*)d_in[19];
    const float* i1tW = (const float*)d_in[20];
    const float* i2rW = (const float*)d_in[21];
    const float* i2rB = (const float*)d_in[22];
    const float* i2tW = (const float*)d_in[23];
    const float* roW0 = (const float*)d_in[24];
    const float* roB0 = (const float*)d_in[25];
    const float* roW1 = (const float*)d_in[26];
    const float* roB1 = (const float*)d_in[27];
    const float* roW2 = (const float*)d_in[28];
    const float* roB2 = (const float*)d_in[29];
    const float* lW   = (const float*)d_in[30];
    const float* lB   = (const float*)d_in[31];
    float* out = (float*)d_out;

    char* ws = (char*)d_ws;
    ushort_t* hbf = (ushort_t*)(ws + OFF_H);   // bf16 gather source (BN+ReLU'd)
    float* hraw   = (float*)(ws + OFF_AGG);    // raw fp32 layer output
    float* h2     = (float*)(ws + OFF_H2);     // layer-4 raw fp32 output
    ushort_t* yrelb = (ushort_t*)(ws + OFF_H); // post-GIN: bf16 yrel (hbf dead)
    float* yroot  = (float*)(ws + OFF_YROOT);
    float* aggb   = (float*)(ws + OFF_H);      // layer-2 raw gather output (yrelb dead)
    ushort_t* xpb = (ushort_t*)(ws + OFF_XP);  // bf16 xp
    float* xp2    = (float*)(ws + OFF_YROOT);  // layer-2 final output (26MB)
    int* offs1    = (int*)(ws + OFF_OFFS1);
    int* col1     = (int*)(ws + OFF_COL1);
    int* offs2    = (int*)(ws + OFF_OFFS2);
    int* col2     = (int*)(ws + OFF_COL2);
    int* isoIdx   = (int*)(ws + OFF_ISO);
    float* mbuf   = (float*)(ws + OFF_M);      // written by kpoolg AFTER gcw frags die
    ushort_t* w1h = (ushort_t*)(ws + OFF_YROOT);
    ushort_t* w1l = (ushort_t*)(ws + OFF_YROOT + 81920);
    ushort_t* w2h = (ushort_t*)(ws + OFF_YROOT + 163840);
    ushort_t* w2l = (ushort_t*)(ws + OFF_YROOT + 245760);
    ushort_t* gcwh = (ushort_t*)(ws + OFF_M);           // 4 matrices x 4096 ushorts
    ushort_t* gcwl = (ushort_t*)(ws + OFF_M + 32768);
    float* pstat2 = (float*)(ws + OFF_CUR1);   // zeroed by memset each launch
    int2* rec1    = (int2*)(ws + OFF_REC1);    // bucketed edge records (dead before xpb writes)
    int2* rec2    = (int2*)(ws + OFF_REC2);
    int* bucketCnt  = (int*)(ws + OFF_CNT1);   // zeroed
    int* bucketBase = (int*)(ws + OFF_BBASE);
    int* perm     = (int*)(ws + OFF_PERM);
    int* dbin     = (int*)(ws + OFF_STATS);    // zeroed
    int* dcur     = dbin + 64;

    const int* src1 = ei;
    const int* dst1 = ei + EE;
    const int* src2 = ei2;
    const int* dst2 = ei2 + EE2;
    const int* a0   = ai2;

    hipMemsetAsync(ws + OFF_CNT1, 0, ZERO_BYTES, stream);

    // bucketed CSR build: LDS ranks + 90K global atomics
    kbA<<<600, 256, 0, stream>>>(src1, dst1, ea, src2, dst2, bucketCnt, rec1, rec2);
    kiso<<<NN2 / 256, 256, 0, stream>>>(iso, isoIdx);
    kprepx<<<12848, 256, 0, stream>>>(x, embW, embB, hbf, gW1, gW2,
                                      w1h, w1l, w2h, w2l,
                                      i1rW, i1tW, i2rW, i2tW, gcwh, gcwl);
    kbscan<<<2, 256, 0, stream>>>(bucketCnt, bucketBase);
    kbB<<<300, 256, 0, stream>>>(bucketCnt, bucketBase, rec1, rec2,
                                 offs1, col1, offs2, col2, dbin);
    kdegplace<<<NN / 256, 256, 0, stream>>>(offs1, dbin, dcur, perm);

    // GIN layers: bf16 gather (half the L2-fill footprint) + MFMA MLP -> fp32 raw;
    // ktrans converts raw -> bf16 (BN+ReLU) for the next layer. Layer 4 raw -> h2 for branch.
    for (int l = 0; l < LL; ++l) {
        float* hout = (l == LL - 1) ? h2 : hraw;
        kglayer<<<NN / 16, 256, 0, stream>>>(
            hbf, hout, perm, offs1, col1, ee1 + l * 384, ee2 + l * 192,
            w1h + (size_t)l * 8192, w1l + (size_t)l * 8192,
            w2h + (size_t)l * 8192, w2l + (size_t)l * 8192,
            gB1 + l * 128, gB2 + l * 64,
            pstat2 + (size_t)l * 4096);
        if (l < LL - 1)
            ktrans<<<800, 256, 0, stream>>>(hraw, hbf, pstat2 + (size_t)l * 4096,
                                            bng + l * 64, bnb + l * 64);
    }

    // 2-set branch, layer 1 (avg-pool + final-layer BN fused into kgcmm1 staging; MFMA GEMMs)
    kgcmm1<<<NN2 / 64, 256, 0, stream>>>(gcwh, gcwl, gcwh + 4096, gcwl + 4096,
                                         i1rW + 64 * 64, i1tW + 64 * 64, isoIdx,
                                         yrelb, yroot,
                                         pstat2 + (size_t)4 * 4096,
                                         bng + 4 * 64, bnb + 4 * 64, a0, h2);
    kgather2<<<NN2 * 16 / 256, 256, 0, stream>>>(yrelb, yroot, i1rB, offs2, col2, xpb);
    // layer 2: gather-first, fused dual-GEMM single output
    kgather2raw<<<NN2 * 16 / 256, 256, 0, stream>>>(xpb, offs2, col2, aggb);
    kgcmm2<<<NN2 / 64, 256, 0, stream>>>(aggb, xpb,
                                         gcwh + 8192, gcwl + 8192, gcwh + 12288, gcwl + 12288,
                                         i2rB, xp2);

    // pools + readout
    kpoolg<<<GG, 256, 0, stream>>>(h2, xp2, pstat2 + (size_t)4 * 4096,
                                   bng + 4 * 64, bnb + 4 * 64, mbuf);
    kread<<<GG, 64, 0, stream>>>(mbuf, roW0, roB0, roW1, roB1, roW2, roB2, lW, lB, out);
}

// Round 11
// 524.314 us; speedup vs baseline: 1.1419x; 1.0095x over previous
//
#include <hip/hip_runtime.h>

#define NN   51200
#define EE   819200
#define GG   256
#define NN2  102400
#define AA   204800
#define EE2  409600
#define DD   64
#define LL   5

// bucket CSR build
#define NB1  100
#define NB2  200
#define CAP1 10240
#define CAP2 3072

typedef __attribute__((ext_vector_type(8))) short bf16x8;
typedef __attribute__((ext_vector_type(4))) float f32x4;
typedef unsigned short ushort_t;

// ---------------- workspace layout (bytes) ----------------
#define OFF_H      ((size_t)0)          // bf16 h (6.5MB); post-GIN: bf16 yrel (13MB); then bf16 agg (13MB)
#define OFF_AGG    ((size_t)13107200)   // GIN: raw bf16 layer output (consumed by ktrans)
#define OFF_H2     ((size_t)26214400)   // layer-4 raw fp32 output = h2 (alive to kpoolg)
#define OFF_XP     ((size_t)39321600)   // rec1/rec2 during CSR build; later bf16 xp (13MB)
#define OFF_REC1   OFF_XP                       // 100*10240*8 = 8,192,000
#define OFF_REC2   ((size_t)47513600)           // 200*3072*8  = 4,915,200 (ends 52,428,800)
#define OFF_PERM   ((size_t)60293120)   // perm (200KB); dead region between rec end and OFF_YROOT
#define OFF_YROOT  ((size_t)65536000)   // GIN bf16 weights during GIN; yroot after; then xp2 (26MB)
#define OFF_OFFS1  ((size_t)91750400)
#define OFF_COL1   ((size_t)91955216)
#define OFF_OFFS2  ((size_t)95232016)
#define OFF_COL2   ((size_t)95641632)
#define OFF_CNT1   ((size_t)97280032)   // zeroed region starts here; bucketCnt[300] lives here
#define OFF_CUR1   ((size_t)97484832)   // pstat2[5][32][128] (zeroed by memset)
#define OFF_STATS  ((size_t)98508832)   // dbin[64], dcur[64] (zeroed)
#define ZERO_BYTES ((size_t)1231360)
#define OFF_ISO    ((size_t)98511392)
#define OFF_M      ((size_t)98920992)   // graphconv bf16 weight frags (64KB, die before kpoolg); then mbuf
#define WS_NEEDED  ((size_t)99052064)

__device__ __forceinline__ int waveInclScan(int v, int lane) {
#pragma unroll
    for (int off = 1; off < 64; off <<= 1) {
        int t = __shfl_up(v, off, 64);
        if (lane >= off) v += t;
    }
    return v;
}

// ---------------- bf16 helpers ----------------
__device__ __forceinline__ void bsplit(float x, ushort_t& hi, ushort_t& lo) {
    union { float f; unsigned u; } a; a.f = x;
    unsigned hb = (a.u + 0x7FFFu + ((a.u >> 16) & 1u)) >> 16;   // RNE to bf16
    union { unsigned u; float f; } h; h.u = hb << 16;
    float r = x - h.f;
    union { float f; unsigned u; } b; b.f = r;
    unsigned lb = (b.u + 0x7FFFu + ((b.u >> 16) & 1u)) >> 16;
    hi = (ushort_t)hb; lo = (ushort_t)lb;
}
__device__ __forceinline__ ushort_t f2bf(float x) {
    union { float f; unsigned u; } a; a.f = x;
    return (ushort_t)((a.u + 0x7FFFu + ((a.u >> 16) & 1u)) >> 16);
}
__device__ __forceinline__ float bf2f(ushort_t v) {
    union { unsigned u; float f; } t; t.u = (unsigned)v << 16; return t.f;
}

// ---------------- bucket build phase A: scatter edges by dst>>9 ----------------
__global__ __launch_bounds__(256) void kbA(const int* __restrict__ src1, const int* __restrict__ dst1,
                                           const int* __restrict__ ea,
                                           const int* __restrict__ src2, const int* __restrict__ dst2,
                                           int* __restrict__ bucketCnt,
                                           int2* __restrict__ rec1, int2* __restrict__ rec2) {
    __shared__ int lhist[256];
    __shared__ int lbase[256];
    int tid = threadIdx.x, b = blockIdx.x;
    lhist[tid] = 0;
    __syncthreads();
    if (b < 400) {
        int i = (b * 256 + tid) * 8;
        int4 d0 = *(const int4*)(dst1 + i);
        int4 d1 = *(const int4*)(dst1 + i + 4);
        int dst[8] = {d0.x, d0.y, d0.z, d0.w, d1.x, d1.y, d1.z, d1.w};
        int bin[8], lr[8];
#pragma unroll
        for (int j = 0; j < 8; ++j) {
            bin[j] = dst[j] >> 9;
            lr[j] = atomicAdd(&lhist[bin[j]], 1);
        }
        __syncthreads();
        if (tid < NB1) {
            int c = lhist[tid];
            lbase[tid] = c ? atomicAdd(&bucketCnt[tid], c) : 0;
        }
        __syncthreads();
        int4 s0 = *(const int4*)(src1 + i);
        int4 s1 = *(const int4*)(src1 + i + 4);
        int src[8] = {s0.x, s0.y, s0.z, s0.w, s1.x, s1.y, s1.z, s1.w};
        int4 e0 = *(const int4*)(ea + 2 * i);
        int4 e1 = *(const int4*)(ea + 2 * i + 4);
        int4 e2 = *(const int4*)(ea + 2 * i + 8);
        int4 e3 = *(const int4*)(ea + 2 * i + 12);
        int code[8] = {e0.x * 3 + e0.y, e0.z * 3 + e0.w, e1.x * 3 + e1.y, e1.z * 3 + e1.w,
                       e2.x * 3 + e2.y, e2.z * 3 + e2.w, e3.x * 3 + e3.y, e3.z * 3 + e3.w};
#pragma unroll
        for (int j = 0; j < 8; ++j) {
            int pos = bin[j] * CAP1 + lbase[bin[j]] + lr[j];
            rec1[pos] = make_int2(src[j] | (code[j] << 16), dst[j]);
        }
    } else {
        int i = ((b - 400) * 256 + tid) * 8;
        int4 d0 = *(const int4*)(dst2 + i);
        int4 d1 = *(const int4*)(dst2 + i + 4);
        int dst[8] = {d0.x, d0.y, d0.z, d0.w, d1.x, d1.y, d1.z, d1.w};
        int bin[8], lr[8];
#pragma unroll
        for (int j = 0; j < 8; ++j) {
            bin[j] = dst[j] >> 9;
            lr[j] = atomicAdd(&lhist[bin[j]], 1);
        }
        __syncthreads();
        if (tid < NB2) {
            int c = lhist[tid];
            lbase[tid] = c ? atomicAdd(&bucketCnt[NB1 + tid], c) : 0;
        }
        __syncthreads();
        int4 s0 = *(const int4*)(src2 + i);
        int4 s1 = *(const int4*)(src2 + i + 4);
        int src[8] = {s0.x, s0.y, s0.z, s0.w, s1.x, s1.y, s1.z, s1.w};
#pragma unroll
        for (int j = 0; j < 8; ++j) {
            int pos = bin[j] * CAP2 + lbase[bin[j]] + lr[j];
            rec2[pos] = make_int2(src[j], dst[j]);
        }
    }
}

// ---------------- bucket build phase B: per-bucket CSR (inline base scan + LDS hist + place) ----------------
__global__ __launch_bounds__(256) void kbB(const int* __restrict__ bucketCnt,
                                           const int2* __restrict__ rec1, const int2* __restrict__ rec2,
                                           int* __restrict__ offs1, int* __restrict__ col1,
                                           int* __restrict__ offs2, int* __restrict__ col2,
                                           int* __restrict__ dbin) {
    __shared__ int nh[512];
    __shared__ int ncur[512];
    __shared__ int wsum[4];
    __shared__ int dhist[64];
    __shared__ int sbase;
    int tid = threadIdx.x, b = blockIdx.x;
    bool g1 = b < NB1;
    int lane = tid & 63, wid = tid >> 6;
    // inline exclusive scan of this graph's bucket counts -> base for bucket b
    {
        int nb = g1 ? NB1 : NB2;
        const int* cntA = bucketCnt + (g1 ? 0 : NB1);
        int myIdx = g1 ? b : b - NB1;
        int v = (tid < nb) ? cntA[tid] : 0;
        int incl = waveInclScan(v, lane);
        if (lane == 63) wsum[wid] = incl;
        __syncthreads();
        int woff = 0;
#pragma unroll
        for (int w = 0; w < 3; ++w) woff += (w < wid) ? wsum[w] : 0;
        if (tid == myIdx) sbase = woff + incl - v;
        __syncthreads();
    }
    int base = sbase;
    const int2* rec = g1 ? (rec1 + (size_t)b * CAP1) : (rec2 + (size_t)(b - NB1) * CAP2);
    int cnt = bucketCnt[b];
    int* offs = g1 ? offs1 : offs2;
    int* col = g1 ? col1 : col2;
    int nodeBase = g1 ? b * 512 : (b - NB1) * 512;
    nh[tid] = 0; nh[tid + 256] = 0;
    if (tid < 64) dhist[tid] = 0;
    __syncthreads();
    for (int e = tid; e < cnt; e += 256) {
        int2 r = rec[e];
        atomicAdd(&nh[r.y & 511], 1);
    }
    __syncthreads();
    int v0 = nh[2 * tid], v1 = nh[2 * tid + 1];
    int s = v0 + v1;
    int incl = waveInclScan(s, lane);
    if (lane == 63) wsum[wid] = incl;
    __syncthreads();
    int woff = 0;
#pragma unroll
    for (int w = 0; w < 3; ++w) woff += (w < wid) ? wsum[w] : 0;
    int excl = woff + incl - s;
    ncur[2 * tid] = excl;
    ncur[2 * tid + 1] = excl + v0;
    offs[nodeBase + 2 * tid] = base + excl;
    offs[nodeBase + 2 * tid + 1] = base + excl + v0;
    if (g1) {
        atomicAdd(&dhist[v0 < 63 ? v0 : 63], 1);
        atomicAdd(&dhist[v1 < 63 ? v1 : 63], 1);
    }
    __syncthreads();
    for (int e = tid; e < cnt; e += 256) {
        int2 r = rec[e];
        int node = r.y & 511;
        int slot = base + atomicAdd(&ncur[node], 1);
        col[slot] = r.x;
    }
    if (g1 && tid < 64 && dhist[tid]) atomicAdd(&dbin[tid], dhist[tid]);
    if (tid == 0) {
        if (b == NB1 - 1) offs1[NN] = EE;
        if (b == NB1 + NB2 - 1) offs2[NN2] = EE2;
    }
}

// ---------------- iso argmax: LDS-staged coalesced reads ----------------
__global__ __launch_bounds__(256) void kiso(const float* __restrict__ iso, int* __restrict__ isoIdx) {
    __shared__ float srow[256 * 36];
    int tid = threadIdx.x;
    int base = blockIdx.x * 256;
    const float4* g4p = (const float4*)(iso + (size_t)base * 36);
#pragma unroll
    for (int i = tid; i < 2304; i += 256) ((float4*)srow)[i] = g4p[i];
    __syncthreads();
    const float* r = srow + tid * 36;
    int best = 0;
#pragma unroll
    for (int k = 0; k < 36; ++k)
        if (r[k] > 0.5f) best = k;
    isoIdx[base + tid] = best;
}

// ---------------- prep: embedding (bf16 out) + GIN weight prep + GraphConv weight prep ----------------
__global__ void kprepx(const float* __restrict__ x, const float* __restrict__ embW,
                       const float* __restrict__ embB, ushort_t* __restrict__ hbf,
                       const float* __restrict__ gW1, const float* __restrict__ gW2,
                       ushort_t* __restrict__ w1h, ushort_t* __restrict__ w1l,
                       ushort_t* __restrict__ w2h, ushort_t* __restrict__ w2l,
                       const float* __restrict__ i1rW, const float* __restrict__ i1tW,
                       const float* __restrict__ i2rW, const float* __restrict__ i2tW,
                       ushort_t* __restrict__ gcwh, ushort_t* __restrict__ gcwl) {
    int b = blockIdx.x;
    if (b < 12800) {
        int t = b * 256 + threadIdx.x;
        int n = t >> 6, d = t & 63;
        float acc = embB[d];
        const float4* xr4 = (const float4*)(x + (size_t)n * 40);
#pragma unroll
        for (int k4 = 0; k4 < 10; ++k4) {
            float4 xv = xr4[k4];
            acc = fmaf(xv.x, embW[(4 * k4 + 0) * 64 + d], acc);
            acc = fmaf(xv.y, embW[(4 * k4 + 1) * 64 + d], acc);
            acc = fmaf(xv.z, embW[(4 * k4 + 2) * 64 + d], acc);
            acc = fmaf(xv.w, embW[(4 * k4 + 3) * 64 + d], acc);
        }
        hbf[(size_t)n * 64 + d] = f2bf(fmaxf(acc, 0.f));
    } else if (b < 12840) {
        int t = (b - 12800) * 256 + threadIdx.x;
        int lane = t & 63, frag = t >> 6;
        int c15 = lane & 15, q = lane >> 4;
        if (frag < 80) {
            int kt = frag & 1, nt = (frag >> 1) & 7, l = frag >> 4;
            const float* W = gW1 + l * 8192;
            ushort_t* oh = w1h + ((size_t)frag * 64 + lane) * 8;
            ushort_t* ol = w1l + ((size_t)frag * 64 + lane) * 8;
            int kb = kt * 32 + q * 8, colw = nt * 16 + c15;
#pragma unroll
            for (int j = 0; j < 8; ++j) {
                ushort_t hi, lo; bsplit(W[(kb + j) * 128 + colw], hi, lo);
                oh[j] = hi; ol[j] = lo;
            }
        } else if (frag < 160) {
            int f = frag - 80;
            int kt = f & 3, nt = (f >> 2) & 3, l = f >> 4;
            const float* W = gW2 + l * 8192;
            ushort_t* oh = w2h + ((size_t)f * 64 + lane) * 8;
            ushort_t* ol = w2l + ((size_t)f * 64 + lane) * 8;
            int kb = kt * 32 + q * 8, colw = nt * 16 + c15;
#pragma unroll
            for (int j = 0; j < 8; ++j) {
                ushort_t hi, lo; bsplit(W[(kb + j) * 64 + colw], hi, lo);
                oh[j] = hi; ol[j] = lo;
            }
        }
    } else {
        // GraphConv weight prep: 4 matrices x 8 frags (K=64, N=64)
        int t = (b - 12840) * 256 + threadIdx.x;   // 0..2047
        int lane = t & 63, frag = t >> 6;          // frag 0..31
        int c15 = lane & 15, q = lane >> 4;
        int m = frag >> 3, f = frag & 7;
        int kt = f & 1, nt = f >> 1;
        const float* W = (m == 0) ? i1rW : (m == 1) ? i1tW : (m == 2) ? i2rW : i2tW;
        ushort_t* oh = gcwh + (size_t)m * 4096 + ((size_t)f * 64 + lane) * 8;
        ushort_t* ol = gcwl + (size_t)m * 4096 + ((size_t)f * 64 + lane) * 8;
        int kb = kt * 32 + q * 8, colw = nt * 16 + c15;
#pragma unroll
        for (int j = 0; j < 8; ++j) {
            ushort_t hi, lo; bsplit(W[(kb + j) * 64 + colw], hi, lo);
            oh[j] = hi; ol[j] = lo;
        }
    }
}

// two-level counting-sort placement; dstart computed inline from dbin (ascending)
__global__ __launch_bounds__(256) void kdegplace(const int* __restrict__ offs,
                                                 const int* __restrict__ dbin,
                                                 int* __restrict__ dcur,
                                                 int* __restrict__ perm) {
    __shared__ int lhist[64];
    __shared__ int lbase[64];
    __shared__ int sdstart[64];
    int tid = threadIdx.x;
    if (tid < 64) {
        lhist[tid] = 0;
        int v = dbin[tid];
        int incl = waveInclScan(v, tid);
        sdstart[tid] = incl - v;
    }
    __syncthreads();
    int n = blockIdx.x * 256 + tid;
    int d = offs[n + 1] - offs[n]; d = d < 63 ? d : 63;
    int lr = atomicAdd(&lhist[d], 1);
    __syncthreads();
    if (tid < 64) {
        int c = lhist[tid];
        lbase[tid] = c ? atomicAdd(&dcur[tid], c) : 0;
    }
    __syncthreads();
    perm[sdstart[d] + lbase[d] + lr] = n;
}

// ---------------- per-node BN+ReLU transform: bf16 raw -> bf16 (for next layer's gather) ----------------
__global__ __launch_bounds__(256) void ktrans(const ushort_t* __restrict__ hraw,
                                              ushort_t* __restrict__ hbf,
                                              const float* __restrict__ pst,
                                              const float* __restrict__ gamma,
                                              const float* __restrict__ beta) {
    __shared__ float sstat[128];
    __shared__ float sSC[64], sSH[64];
    int tid = threadIdx.x;
    if (tid < 128) {
        float s = 0.f;
        const float* p = pst + tid;
#pragma unroll
        for (int i = 0; i < 32; ++i) s += p[i * 128];
        sstat[tid] = s;
    }
    __syncthreads();
    if (tid < 64) {
        float mu = sstat[tid] * (1.f / NN);
        float var = sstat[64 + tid] * (1.f / NN) - mu * mu;
        float sc = gamma[tid] * rsqrtf(var + 1e-5f);
        sSC[tid] = sc; sSH[tid] = beta[tid] - mu * sc;
    }
    __syncthreads();
    int c = (tid & 15) * 4;
    float4 sc4 = *(const float4*)(sSC + c);
    float4 sh4 = *(const float4*)(sSH + c);
    const ushort4* hp = (const ushort4*)hraw;
    ushort4* op = (ushort4*)hbf;
    size_t base = (size_t)blockIdx.x * 1024 + tid;
#pragma unroll
    for (int r = 0; r < 4; ++r) {
        ushort4 v = hp[base + r * 256];
        ushort4 o;
        o.x = f2bf(fmaxf(fmaf(bf2f(v.x), sc4.x, sh4.x), 0.f));
        o.y = f2bf(fmaxf(fmaf(bf2f(v.y), sc4.y, sh4.y), 0.f));
        o.z = f2bf(fmaxf(fmaf(bf2f(v.z), sc4.z, sh4.z), 0.f));
        o.w = f2bf(fmaxf(fmaf(bf2f(v.w), sc4.w, sh4.w), 0.f));
        op[base + r * 256] = o;
    }
}

// ---------------- fused GIN layer: bf16 gather -> LDS -> MFMA MLP -> bf16 raw (or fp32 for LAST) + stats ----
template <int LAST>
__global__ __launch_bounds__(256) void kglayer(
    const ushort_t* __restrict__ hin, ushort_t* __restrict__ houtB,
    float* __restrict__ houtF,
    const int* __restrict__ perm,
    const int* __restrict__ offs, const int* __restrict__ col,
    const float* __restrict__ e1, const float* __restrict__ e2,
    const ushort_t* __restrict__ w1h, const ushort_t* __restrict__ w1l,
    const ushort_t* __restrict__ w2h, const ushort_t* __restrict__ w2l,
    const float* __restrict__ b1, const float* __restrict__ b2,
    float* __restrict__ pstout) {
    __shared__ float etab[13 * 64];
    __shared__ int sPerm[16];
    __shared__ float sMLP[16 * 132];   // sA stride-68 aliases front; sH stride-132
    float* sA = sMLP;
    float* sH = sMLP;
    int tid = threadIdx.x;
    if (tid < 16) sPerm[tid] = perm[blockIdx.x * 16 + tid];
    for (int idx = tid; idx < 13 * 64; idx += 256) {
        int ci = idx >> 6, dd = idx & 63;
        etab[idx] = e1[(ci / 3) * 64 + dd] + e2[(ci % 3) * 64 + dd];
    }
    __syncthreads();
    int lane = tid & 63, wv = tid >> 6;
    int c15 = lane & 15, q = lane >> 4;

    // ---- gather node n into sA (bf16 rows, 128 B each) ----
    {
        int n = sPerm[wv * 4 + q];
        int s0 = offs[n], s1 = offs[n + 1];
        ushort4 sx = *(const ushort4*)(hin + (size_t)n * 64 + 4 * c15);
        float4 et = *(const float4*)(etab + 12 * 64 + 4 * c15);
        float a0 = bf2f(sx.x) + et.x, a1 = bf2f(sx.y) + et.y;
        float a2 = bf2f(sx.z) + et.z, a3 = bf2f(sx.w) + et.w;
        int deg = s1 - s0;
        if (deg > 0) {
            const int* cp = col + s0;
            int nfull = deg >> 3, rem = deg & 7;
            int vv[8];
#pragma unroll
            for (int j = 0; j < 8; ++j) {
                int idx = j < deg ? j : deg - 1;
                vv[j] = cp[idx];
            }
            for (int it = 0; it < nfull; ++it) {
                ushort4 xv[8];
                float4 tv[8];
#pragma unroll
                for (int j = 0; j < 8; ++j) {
                    xv[j] = *(const ushort4*)(hin + (size_t)(vv[j] & 0xFFFF) * 64 + 4 * c15);
                    tv[j] = *(const float4*)(etab + (vv[j] >> 16) * 64 + 4 * c15);
                }
                int e8 = (it + 1) * 8;
                bool more = e8 < deg;
                int nx[8];
                if (more) {
#pragma unroll
                    for (int j = 0; j < 8; ++j) {
                        int idx = e8 + j; idx = idx < deg ? idx : deg - 1;
                        nx[j] = cp[idx];
                    }
                }
#pragma unroll
                for (int j = 0; j < 8; ++j) {
                    a0 += bf2f(xv[j].x) + tv[j].x;
                    a1 += bf2f(xv[j].y) + tv[j].y;
                    a2 += bf2f(xv[j].z) + tv[j].z;
                    a3 += bf2f(xv[j].w) + tv[j].w;
                }
                if (more) {
#pragma unroll
                    for (int j = 0; j < 8; ++j) vv[j] = nx[j];
                }
            }
            if (rem) {
                ushort4 xv[8];
                float4 tv[8];
#pragma unroll
                for (int j = 0; j < 8; ++j) {
                    xv[j] = *(const ushort4*)(hin + (size_t)(vv[j] & 0xFFFF) * 64 + 4 * c15);
                    tv[j] = *(const float4*)(etab + (vv[j] >> 16) * 64 + 4 * c15);
                }
#pragma unroll
                for (int j = 0; j < 8; ++j) {
                    float mm = (j < rem) ? 1.f : 0.f;
                    a0 = fmaf(bf2f(xv[j].x) + tv[j].x, mm, a0);
                    a1 = fmaf(bf2f(xv[j].y) + tv[j].y, mm, a1);
                    a2 = fmaf(bf2f(xv[j].z) + tv[j].z, mm, a2);
                    a3 = fmaf(bf2f(xv[j].w) + tv[j].w, mm, a3);
                }
            }
        }
        *(float4*)(sA + (wv * 4 + q) * 68 + 4 * c15) = make_float4(a0, a1, a2, a3);
    }
    __syncthreads();

    // ---- A-frags to regs (sA dies after next sync; sH aliases) ----
    bf16x8 ah[2], al[2];
#pragma unroll
    for (int kt = 0; kt < 2; ++kt) {
        const float* p = sA + c15 * 68 + kt * 32 + q * 8;
        float4 x0 = *(const float4*)p;
        float4 x1 = *(const float4*)(p + 4);
        float xs[8] = {x0.x, x0.y, x0.z, x0.w, x1.x, x1.y, x1.z, x1.w};
#pragma unroll
        for (int j = 0; j < 8; ++j) {
            ushort_t hi, lo; bsplit(xs[j], hi, lo);
            ah[kt][j] = (short)hi; al[kt][j] = (short)lo;
        }
    }
    __syncthreads();

    // ---- GEMM1: nt = 2wv+j ----
    f32x4 acc1[2];
#pragma unroll
    for (int j = 0; j < 2; ++j) { f32x4 z = {0.f, 0.f, 0.f, 0.f}; acc1[j] = z; }
#pragma unroll
    for (int kt = 0; kt < 2; ++kt) {
#pragma unroll
        for (int j = 0; j < 2; ++j) {
            int nt = 2 * wv + j;
            size_t fo = ((size_t)((nt * 2 + kt) * 64 + lane)) * 8;
            bf16x8 bh = *(const bf16x8*)(w1h + fo);
            bf16x8 bl = *(const bf16x8*)(w1l + fo);
            acc1[j] = __builtin_amdgcn_mfma_f32_16x16x32_bf16(ah[kt], bh, acc1[j], 0, 0, 0);
            acc1[j] = __builtin_amdgcn_mfma_f32_16x16x32_bf16(al[kt], bh, acc1[j], 0, 0, 0);
            acc1[j] = __builtin_amdgcn_mfma_f32_16x16x32_bf16(ah[kt], bl, acc1[j], 0, 0, 0);
        }
    }
#pragma unroll
    for (int j = 0; j < 2; ++j) {
        int nt = 2 * wv + j;
        float bias = b1[nt * 16 + c15];
#pragma unroll
        for (int rg = 0; rg < 4; ++rg)
            sH[(4 * q + rg) * 132 + nt * 16 + c15] = fmaxf(acc1[j][rg] + bias, 0.f);
    }
    __syncthreads();

    // ---- GEMM2: nt = wv ----
    f32x4 acc2 = {0.f, 0.f, 0.f, 0.f};
#pragma unroll
    for (int kt = 0; kt < 4; ++kt) {
        const float* p = sH + c15 * 132 + kt * 32 + q * 8;
        float4 x0 = *(const float4*)p;
        float4 x1 = *(const float4*)(p + 4);
        float xs[8] = {x0.x, x0.y, x0.z, x0.w, x1.x, x1.y, x1.z, x1.w};
        bf16x8 a2h, a2l;
#pragma unroll
        for (int j = 0; j < 8; ++j) {
            ushort_t hi, lo; bsplit(xs[j], hi, lo);
            a2h[j] = (short)hi; a2l[j] = (short)lo;
        }
        size_t fo = ((size_t)((wv * 4 + kt) * 64 + lane)) * 8;
        bf16x8 bh = *(const bf16x8*)(w2h + fo);
        bf16x8 bl = *(const bf16x8*)(w2l + fo);
        acc2 = __builtin_amdgcn_mfma_f32_16x16x32_bf16(a2h, bh, acc2, 0, 0, 0);
        acc2 = __builtin_amdgcn_mfma_f32_16x16x32_bf16(a2l, bh, acc2, 0, 0, 0);
        acc2 = __builtin_amdgcn_mfma_f32_16x16x32_bf16(a2h, bl, acc2, 0, 0, 0);
    }
    {
        float bias = b2[wv * 16 + c15];
        float s = 0.f, s2 = 0.f;
#pragma unroll
        for (int rg = 0; rg < 4; ++rg) {
            float v = acc2[rg] + bias;
            size_t oidx = (size_t)sPerm[4 * q + rg] * 64 + wv * 16 + c15;
            if (LAST) houtF[oidx] = v;
            else houtB[oidx] = f2bf(v);
            s += v; s2 += v * v;
        }
        s += __shfl_xor(s, 16, 64);  s += __shfl_xor(s, 32, 64);
        s2 += __shfl_xor(s2, 16, 64); s2 += __shfl_xor(s2, 32, 64);
        if (q == 0) {
            float* ps = pstout + (size_t)(blockIdx.x & 31) * 128;
            atomicAdd(&ps[wv * 16 + c15], s);
            atomicAdd(&ps[64 + wv * 16 + c15], s2);
        }
    }
}

// ---------------- GraphConv1 GEMMs via split-bf16 MFMA (writes bf16 yrel, fp32 yroot) ----------------
__global__ __launch_bounds__(256) void kgcmm1(const ushort_t* __restrict__ grh,
                                              const ushort_t* __restrict__ grl,
                                              const ushort_t* __restrict__ gth,
                                              const ushort_t* __restrict__ gtl,
                                              const float* __restrict__ WrelIso,
                                              const float* __restrict__ WrootIso,
                                              const int* __restrict__ isoIdx,
                                              ushort_t* __restrict__ Yrel,
                                              float* __restrict__ Yroot,
                                              const float* __restrict__ pst,
                                              const float* __restrict__ g4,
                                              const float* __restrict__ b4,
                                              const int* __restrict__ a0g,
                                              const float* __restrict__ h2src) {
    __shared__ float sX[64 * 68];
    __shared__ float sstat[128];
    __shared__ float sSC[64], sSH[64];
    int tid = threadIdx.x, blk = blockIdx.x;
    if (tid < 128) {
        float s = 0.f;
        const float* p = pst + tid;
#pragma unroll
        for (int i = 0; i < 32; ++i) s += p[i * 128];
        sstat[tid] = s;
    }
    __syncthreads();
    if (tid < 64) {
        float mu = sstat[tid] * (1.f / NN);
        float var = sstat[64 + tid] * (1.f / NN) - mu * mu;
        float sc = g4[tid] * rsqrtf(var + 1e-5f);
        sSC[tid] = sc;
        sSH[tid] = b4[tid] - mu * sc;
    }
    __syncthreads();
#pragma unroll
    for (int i = tid; i < 1024; i += 256) {
        int row = i >> 4, c = (i & 15) << 2;
        int grow = blk * 64 + row;
        int na = a0g[2 * grow], nb = a0g[2 * grow + 1];
        float4 va = *(const float4*)(h2src + (size_t)na * 64 + c);
        float4 vb = *(const float4*)(h2src + (size_t)nb * 64 + c);
        float4 v;
        v.x = 0.5f * (va.x + vb.x); v.y = 0.5f * (va.y + vb.y);
        v.z = 0.5f * (va.z + vb.z); v.w = 0.5f * (va.w + vb.w);
        v.x = fmaf(v.x, sSC[c], sSH[c]);
        v.y = fmaf(v.y, sSC[c + 1], sSH[c + 1]);
        v.z = fmaf(v.z, sSC[c + 2], sSH[c + 2]);
        v.w = fmaf(v.w, sSC[c + 3], sSH[c + 3]);
        float* p = sX + row * 68 + c;
        p[0] = v.x; p[1] = v.y; p[2] = v.z; p[3] = v.w;
    }
    __syncthreads();
    int lane = tid & 63, wv = tid >> 6;
    int c15 = lane & 15, q = lane >> 4;

    bf16x8 ah[2], al[2];
#pragma unroll
    for (int kt = 0; kt < 2; ++kt) {
        const float* p = sX + (16 * wv + c15) * 68 + kt * 32 + q * 8;
        float4 x0 = *(const float4*)p;
        float4 x1 = *(const float4*)(p + 4);
        float xs[8] = {x0.x, x0.y, x0.z, x0.w, x1.x, x1.y, x1.z, x1.w};
#pragma unroll
        for (int j = 0; j < 8; ++j) {
            ushort_t hi, lo; bsplit(xs[j], hi, lo);
            ah[kt][j] = (short)hi; al[kt][j] = (short)lo;
        }
    }

    f32x4 accR[4], accT[4];
#pragma unroll
    for (int nt = 0; nt < 4; ++nt) {
        f32x4 z = {0.f, 0.f, 0.f, 0.f};
        accR[nt] = z; accT[nt] = z;
    }
#pragma unroll
    for (int nt = 0; nt < 4; ++nt) {
#pragma unroll
        for (int kt = 0; kt < 2; ++kt) {
            size_t fo = ((size_t)((nt * 2 + kt) * 64 + lane)) * 8;
            bf16x8 bh = *(const bf16x8*)(grh + fo);
            bf16x8 bl = *(const bf16x8*)(grl + fo);
            accR[nt] = __builtin_amdgcn_mfma_f32_16x16x32_bf16(ah[kt], bh, accR[nt], 0, 0, 0);
            accR[nt] = __builtin_amdgcn_mfma_f32_16x16x32_bf16(al[kt], bh, accR[nt], 0, 0, 0);
            accR[nt] = __builtin_amdgcn_mfma_f32_16x16x32_bf16(ah[kt], bl, accR[nt], 0, 0, 0);
            bf16x8 ch = *(const bf16x8*)(gth + fo);
            bf16x8 cl = *(const bf16x8*)(gtl + fo);
            accT[nt] = __builtin_amdgcn_mfma_f32_16x16x32_bf16(ah[kt], ch, accT[nt], 0, 0, 0);
            accT[nt] = __builtin_amdgcn_mfma_f32_16x16x32_bf16(al[kt], ch, accT[nt], 0, 0, 0);
            accT[nt] = __builtin_amdgcn_mfma_f32_16x16x32_bf16(ah[kt], cl, accT[nt], 0, 0, 0);
        }
    }

    int rbase = blk * 64 + 16 * wv + 4 * q;
#pragma unroll
    for (int rg = 0; rg < 4; ++rg) {
        int row = rbase + rg;
        int ii = isoIdx[row];
        ushort_t* yr = Yrel + (size_t)row * 64;
        float* yt = Yroot + (size_t)row * 64;
        const float* er = WrelIso + (size_t)ii * 64;
        const float* et = WrootIso + (size_t)ii * 64;
#pragma unroll
        for (int nt = 0; nt < 4; ++nt) {
            int cc = nt * 16 + c15;
            yr[cc] = f2bf(accR[nt][rg] + er[cc]);
            yt[cc] = accT[nt][rg] + et[cc];
        }
    }
}

// ---------------- GraphConv2 fused: OUT = relu(AGG @ Wrel + brel + XP @ Wroot), AGG+XP bf16 ----------------
__global__ __launch_bounds__(256) void kgcmm2(const ushort_t* __restrict__ AGG,
                                              const ushort_t* __restrict__ XP,
                                              const ushort_t* __restrict__ grh,
                                              const ushort_t* __restrict__ grl,
                                              const ushort_t* __restrict__ gth,
                                              const ushort_t* __restrict__ gtl,
                                              const float* __restrict__ brel,
                                              float* __restrict__ OUT) {
    __shared__ float sA[64 * 68];
    __shared__ float sB[64 * 68];
    int tid = threadIdx.x, blk = blockIdx.x;
#pragma unroll
    for (int i = tid; i < 1024; i += 256) {
        int row = i >> 4, c = (i & 15) << 2;
        ushort4 va4 = ((const ushort4*)(AGG + (size_t)blk * 4096))[i];
        ushort4 vb4 = ((const ushort4*)(XP + (size_t)blk * 4096))[i];
        float* pa = sA + row * 68 + c;
        float* pb = sB + row * 68 + c;
        pa[0] = bf2f(va4.x); pa[1] = bf2f(va4.y); pa[2] = bf2f(va4.z); pa[3] = bf2f(va4.w);
        pb[0] = bf2f(vb4.x); pb[1] = bf2f(vb4.y); pb[2] = bf2f(vb4.z); pb[3] = bf2f(vb4.w);
    }
    __syncthreads();
    int lane = tid & 63, wv = tid >> 6;
    int c15 = lane & 15, q = lane >> 4;

    bf16x8 aAh[2], aBh[2];
#pragma unroll
    for (int kt = 0; kt < 2; ++kt) {
        const float* pa = sA + (16 * wv + c15) * 68 + kt * 32 + q * 8;
        const float* pb = sB + (16 * wv + c15) * 68 + kt * 32 + q * 8;
        float4 a0 = *(const float4*)pa;
        float4 a1 = *(const float4*)(pa + 4);
        float4 b0 = *(const float4*)pb;
        float4 b1 = *(const float4*)(pb + 4);
        float as[8] = {a0.x, a0.y, a0.z, a0.w, a1.x, a1.y, a1.z, a1.w};
        float bs[8] = {b0.x, b0.y, b0.z, b0.w, b1.x, b1.y, b1.z, b1.w};
#pragma unroll
        for (int j = 0; j < 8; ++j) {
            aAh[kt][j] = (short)f2bf(as[j]);   // bf16-exact: lo plane zero
            aBh[kt][j] = (short)f2bf(bs[j]);
        }
    }

    f32x4 acc[4];
#pragma unroll
    for (int nt = 0; nt < 4; ++nt) { f32x4 z = {0.f, 0.f, 0.f, 0.f}; acc[nt] = z; }
#pragma unroll
    for (int nt = 0; nt < 4; ++nt) {
#pragma unroll
        for (int kt = 0; kt < 2; ++kt) {
            size_t fo = ((size_t)((nt * 2 + kt) * 64 + lane)) * 8;
            bf16x8 bh = *(const bf16x8*)(grh + fo);
            bf16x8 bl = *(const bf16x8*)(grl + fo);
            acc[nt] = __builtin_amdgcn_mfma_f32_16x16x32_bf16(aAh[kt], bh, acc[nt], 0, 0, 0);
            acc[nt] = __builtin_amdgcn_mfma_f32_16x16x32_bf16(aAh[kt], bl, acc[nt], 0, 0, 0);
            bf16x8 ch = *(const bf16x8*)(gth + fo);
            bf16x8 cl = *(const bf16x8*)(gtl + fo);
            acc[nt] = __builtin_amdgcn_mfma_f32_16x16x32_bf16(aBh[kt], ch, acc[nt], 0, 0, 0);
            acc[nt] = __builtin_amdgcn_mfma_f32_16x16x32_bf16(aBh[kt], cl, acc[nt], 0, 0, 0);
        }
    }

    int rbase = blk * 64 + 16 * wv + 4 * q;
#pragma unroll
    for (int rg = 0; rg < 4; ++rg) {
        int row = rbase + rg;
        float* yo = OUT + (size_t)row * 64;
#pragma unroll
        for (int nt = 0; nt < 4; ++nt) {
            int cc = nt * 16 + c15;
            yo[cc] = fmaxf(acc[nt][rg] + brel[cc], 0.f);
        }
    }
}

// ---------------- GraphConv gather layer1: bf16 yrel gather + fp32 root+bias+relu -> bf16 xp ----------------
__global__ void kgather2(const ushort_t* __restrict__ yrel, const float* __restrict__ yroot,
                         const float* __restrict__ brel, const int* __restrict__ offs,
                         const int* __restrict__ col, ushort_t* __restrict__ out) {
    int t = blockIdx.x * 256 + threadIdx.x;
    int j = t >> 4, c = t & 15;
    int s0 = offs[j], s1 = offs[j + 1];
    float4 rt = *(const float4*)(yroot + (size_t)j * 64 + 4 * c);
    float4 bb = *(const float4*)(brel + 4 * c);
    float a0 = rt.x + bb.x, a1 = rt.y + bb.y, a2 = rt.z + bb.z, a3 = rt.w + bb.w;
    if (s0 < s1) {
        int vv[4];
#pragma unroll
        for (int jj = 0; jj < 4; ++jj) {
            int idx = s0 + jj; idx = idx < s1 ? idx : s1 - 1;
            vv[jj] = col[idx];
        }
        int e = s0;
        while (true) {
            int ne = e + 4;
            bool more = ne < s1;
            ushort4 xs[4];
#pragma unroll
            for (int jj = 0; jj < 4; ++jj)
                xs[jj] = *(const ushort4*)(yrel + (size_t)vv[jj] * 64 + 4 * c);
            int nx[4];
            if (more) {
#pragma unroll
                for (int jj = 0; jj < 4; ++jj) {
                    int idx = ne + jj; idx = idx < s1 ? idx : s1 - 1;
                    nx[jj] = col[idx];
                }
            }
#pragma unroll
            for (int jj = 0; jj < 4; ++jj) {
                float mm = (e + jj < s1) ? 1.f : 0.f;
                a0 = fmaf(bf2f(xs[jj].x), mm, a0);
                a1 = fmaf(bf2f(xs[jj].y), mm, a1);
                a2 = fmaf(bf2f(xs[jj].z), mm, a2);
                a3 = fmaf(bf2f(xs[jj].w), mm, a3);
            }
            if (!more) break;
            e = ne;
#pragma unroll
            for (int jj = 0; jj < 4; ++jj) vv[jj] = nx[jj];
        }
    }
    ushort4 o;
    o.x = f2bf(fmaxf(a0, 0.f));
    o.y = f2bf(fmaxf(a1, 0.f));
    o.z = f2bf(fmaxf(a2, 0.f));
    o.w = f2bf(fmaxf(a3, 0.f));
    *(ushort4*)(out + (size_t)j * 64 + 4 * c) = o;
}

// ---------------- GraphConv gather layer2: raw neighbor sums of bf16 xp -> bf16 agg ----------------
__global__ void kgather2raw(const ushort_t* __restrict__ xpsrc, const int* __restrict__ offs,
                            const int* __restrict__ col, ushort_t* __restrict__ agg) {
    int t = blockIdx.x * 256 + threadIdx.x;
    int j = t >> 4, c = t & 15;
    int s0 = offs[j], s1 = offs[j + 1];
    float a0 = 0.f, a1 = 0.f, a2 = 0.f, a3 = 0.f;
    if (s0 < s1) {
        int vv[4];
#pragma unroll
        for (int jj = 0; jj < 4; ++jj) {
            int idx = s0 + jj; idx = idx < s1 ? idx : s1 - 1;
            vv[jj] = col[idx];
        }
        int e = s0;
        while (true) {
            int ne = e + 4;
            bool more = ne < s1;
            ushort4 xs[4];
#pragma unroll
            for (int jj = 0; jj < 4; ++jj)
                xs[jj] = *(const ushort4*)(xpsrc + (size_t)vv[jj] * 64 + 4 * c);
            int nx[4];
            if (more) {
#pragma unroll
                for (int jj = 0; jj < 4; ++jj) {
                    int idx = ne + jj; idx = idx < s1 ? idx : s1 - 1;
                    nx[jj] = col[idx];
                }
            }
#pragma unroll
            for (int jj = 0; jj < 4; ++jj) {
                float mm = (e + jj < s1) ? 1.f : 0.f;
                a0 = fmaf(bf2f(xs[jj].x), mm, a0);
                a1 = fmaf(bf2f(xs[jj].y), mm, a1);
                a2 = fmaf(bf2f(xs[jj].z), mm, a2);
                a3 = fmaf(bf2f(xs[jj].w), mm, a3);
            }
            if (!more) break;
            e = ne;
#pragma unroll
            for (int jj = 0; jj < 4; ++jj) vv[jj] = nx[jj];
        }
    }
    ushort4 o;
    o.x = f2bf(a0); o.y = f2bf(a1); o.z = f2bf(a2); o.w = f2bf(a3);
    *(ushort4*)(agg + (size_t)j * 64 + 4 * c) = o;
}

// ---------------- per-graph mean pools (x1 gets final BN affine on the mean) ----------------
__global__ void kpoolg(const float* __restrict__ h2, const float* __restrict__ xp2,
                       const float* __restrict__ pst, const float* __restrict__ g4,
                       const float* __restrict__ b4, float* __restrict__ m) {
    __shared__ float sstat[128];
    __shared__ float red[4][64];
    int g = blockIdx.x, tid = threadIdx.x;
    if (tid < 128) {
        float s = 0.f;
        const float* p = pst + tid;
#pragma unroll
        for (int i = 0; i < 32; ++i) s += p[i * 128];
        sstat[tid] = s;
    }
    int wid = tid >> 6, d = tid & 63;
    float s1 = 0.f;
    for (int i = wid; i < 200; i += 4) s1 += h2[((size_t)g * 200 + i) * 64 + d];
    red[wid][d] = s1;
    __syncthreads();
    if (wid == 0) {
        float mean = (red[0][d] + red[1][d] + red[2][d] + red[3][d]) * (1.f / 200.f);
        float mu = sstat[d] * (1.f / NN);
        float var = sstat[64 + d] * (1.f / NN) - mu * mu;
        float sc = g4[d] * rsqrtf(var + 1e-5f);
        m[g * 128 + d] = fmaf(mean, sc, b4[d] - mu * sc);
    }
    __syncthreads();
    float s2 = 0.f;
    for (int i = wid; i < 400; i += 4) s2 += xp2[((size_t)g * 400 + i) * 64 + d];
    red[wid][d] = s2;
    __syncthreads();
    if (wid == 0) m[g * 128 + 64 + d] = (red[0][d] + red[1][d] + red[2][d] + red[3][d]) * (1.f / 400.f);
}

// ---------------- readout MLP ----------------
__global__ void kread(const float* __restrict__ m, const float* __restrict__ W0,
                      const float* __restrict__ b0, const float* __restrict__ W1,
                      const float* __restrict__ b1, const float* __restrict__ W2,
                      const float* __restrict__ b2, const float* __restrict__ lw,
                      const float* __restrict__ lb, float* __restrict__ out) {
    __shared__ float s0[64], s1[32], s2[16];
    int g = blockIdx.x, d = threadIdx.x;
    const float* mr = m + g * 128;
    float t = b0[d];
    for (int k = 0; k < 128; ++k) t = fmaf(mr[k], W0[k * 64 + d], t);
    s0[d] = fmaxf(t, 0.f);
    __syncthreads();
    if (d < 32) {
        float u = b1[d];
        for (int k = 0; k < 64; ++k) u = fmaf(s0[k], W1[k * 32 + d], u);
        s1[d] = fmaxf(u, 0.f);
    }
    __syncthreads();
    if (d < 16) {
        float u = b2[d];
        for (int k = 0; k < 32; ++k) u = fmaf(s1[k], W2[k * 16 + d], u);
        s2[d] = fmaxf(u, 0.f);
    }
    __syncthreads();
    if (d == 0) {
        float u = lb[0];
        for (int k = 0; k < 16; ++k) u = fmaf(s2[k], lw[k], u);
        out[g] = u;
    }
}

// ---------------- host ----------------
extern "C" void kernel_launch(void* const* d_in, const int* in_sizes, int n_in,
                              void* d_out, int out_size, void* d_ws, size_t ws_size,
                              hipStream_t stream) {
    if (ws_size < WS_NEEDED) return;

    const float* x    = (const float*)d_in[0];
    const int*   ei   = (const int*)d_in[1];
    const int*   ea   = (const int*)d_in[2];
    const float* iso  = (const float*)d_in[4];
    const int*   ei2  = (const int*)d_in[5];
    const int*   ai2  = (const int*)d_in[6];
    const float* embW = (const float*)d_in[8];
    const float* embB = (const float*)d_in[9];
    const float* gW1  = (const float*)d_in[10];
    const float* gB1  = (const float*)d_in[11];
    const float* gW2  = (const float*)d_in[12];
    const float* gB2  = (const float*)d_in[13];
    const float* ee1  = (const float*)d_in[14];
    const float* ee2  = (const float*)d_in[15];
    const float* bng  = (const float*)d_in[16];
    const float* bnb  = (const float*)d_in[17];
    const float* i1rW = (const float*)d_in[18];
    const float* i1rB = (const float*)d_in[19];
    const float* i1tW = (const float*)d_in[20];
    const float* i2rW = (const float*)d_in[21];
    const float* i2rB = (const float*)d_in[22];
    const float* i2tW = (const float*)d_in[23];
    const float* roW0 = (const float*)d_in[24];
    const float* roB0 = (const float*)d_in[25];
    const float* roW1 = (const float*)d_in[26];
    const float* roB1 = (const float*)d_in[27];
    const float* roW2 = (const float*)d_in[28];
    const float* roB2 = (const float*)d_in[29];
    const float* lW   = (const float*)d_in[30];
    const float* lB   = (const float*)d_in[31];
    float* out = (float*)d_out;

    char* ws = (char*)d_ws;
    ushort_t* hbf = (ushort_t*)(ws + OFF_H);   // bf16 gather source (BN+ReLU'd)
    ushort_t* hraw = (ushort_t*)(ws + OFF_AGG);// raw bf16 layer output
    float* h2     = (float*)(ws + OFF_H2);     // layer-4 raw fp32 output
    ushort_t* yrelb = (ushort_t*)(ws + OFF_H); // post-GIN: bf16 yrel (hbf dead)
    float* yroot  = (float*)(ws + OFF_YROOT);
    ushort_t* aggb = (ushort_t*)(ws + OFF_H);  // layer-2 bf16 gather output (yrelb dead)
    ushort_t* xpb = (ushort_t*)(ws + OFF_XP);  // bf16 xp
    float* xp2    = (float*)(ws + OFF_YROOT);  // layer-2 final output (26MB)
    int* offs1    = (int*)(ws + OFF_OFFS1);
    int* col1     = (int*)(ws + OFF_COL1);
    int* offs2    = (int*)(ws + OFF_OFFS2);
    int* col2     = (int*)(ws + OFF_COL2);
    int* isoIdx   = (int*)(ws + OFF_ISO);
    float* mbuf   = (float*)(ws + OFF_M);      // written by kpoolg AFTER gcw frags die
    ushort_t* w1h = (ushort_t*)(ws + OFF_YROOT);
    ushort_t* w1l = (ushort_t*)(ws + OFF_YROOT + 81920);
    ushort_t* w2h = (ushort_t*)(ws + OFF_YROOT + 163840);
    ushort_t* w2l = (ushort_t*)(ws + OFF_YROOT + 245760);
    ushort_t* gcwh = (ushort_t*)(ws + OFF_M);           // 4 matrices x 4096 ushorts
    ushort_t* gcwl = (ushort_t*)(ws + OFF_M + 32768);
    float* pstat2 = (float*)(ws + OFF_CUR1);   // zeroed by memset each launch
    int2* rec1    = (int2*)(ws + OFF_REC1);    // bucketed edge records (dead before xpb writes)
    int2* rec2    = (int2*)(ws + OFF_REC2);
    int* bucketCnt  = (int*)(ws + OFF_CNT1);   // zeroed
    int* perm     = (int*)(ws + OFF_PERM);
    int* dbin     = (int*)(ws + OFF_STATS);    // zeroed
    int* dcur     = dbin + 64;

    const int* src1 = ei;
    const int* dst1 = ei + EE;
    const int* src2 = ei2;
    const int* dst2 = ei2 + EE2;
    const int* a0   = ai2;

    hipMemsetAsync(ws + OFF_CNT1, 0, ZERO_BYTES, stream);

    // bucketed CSR build: LDS ranks + 90K global atomics (scan inlined into kbB)
    kbA<<<600, 256, 0, stream>>>(src1, dst1, ea, src2, dst2, bucketCnt, rec1, rec2);
    kiso<<<NN2 / 256, 256, 0, stream>>>(iso, isoIdx);
    kprepx<<<12848, 256, 0, stream>>>(x, embW, embB, hbf, gW1, gW2,
                                      w1h, w1l, w2h, w2l,
                                      i1rW, i1tW, i2rW, i2tW, gcwh, gcwl);
    kbB<<<300, 256, 0, stream>>>(bucketCnt, rec1, rec2,
                                 offs1, col1, offs2, col2, dbin);
    kdegplace<<<NN / 256, 256, 0, stream>>>(offs1, dbin, dcur, perm);

    // GIN layers: bf16 gather + MFMA MLP -> bf16 raw (fp32 for layer 4);
    // ktrans converts raw bf16 -> bf16 (BN+ReLU) for the next layer.
    for (int l = 0; l < LL; ++l) {
        if (l == LL - 1) {
            kglayer<1><<<NN / 16, 256, 0, stream>>>(
                hbf, nullptr, h2, perm, offs1, col1, ee1 + l * 384, ee2 + l * 192,
                w1h + (size_t)l * 8192, w1l + (size_t)l * 8192,
                w2h + (size_t)l * 8192, w2l + (size_t)l * 8192,
                gB1 + l * 128, gB2 + l * 64,
                pstat2 + (size_t)l * 4096);
        } else {
            kglayer<0><<<NN / 16, 256, 0, stream>>>(
                hbf, hraw, nullptr, perm, offs1, col1, ee1 + l * 384, ee2 + l * 192,
                w1h + (size_t)l * 8192, w1l + (size_t)l * 8192,
                w2h + (size_t)l * 8192, w2l + (size_t)l * 8192,
                gB1 + l * 128, gB2 + l * 64,
                pstat2 + (size_t)l * 4096);
            ktrans<<<800, 256, 0, stream>>>(hraw, hbf, pstat2 + (size_t)l * 4096,
                                            bng + l * 64, bnb + l * 64);
        }
    }

    // 2-set branch, layer 1 (avg-pool + final-layer BN fused into kgcmm1 staging; MFMA GEMMs)
    kgcmm1<<<NN2 / 64, 256, 0, stream>>>(gcwh, gcwl, gcwh + 4096, gcwl + 4096,
                                         i1rW + 64 * 64, i1tW + 64 * 64, isoIdx,
                                         yrelb, yroot,
                                         pstat2 + (size_t)4 * 4096,
                                         bng + 4 * 64, bnb + 4 * 64, a0, h2);
    kgather2<<<NN2 * 16 / 256, 256, 0, stream>>>(yrelb, yroot, i1rB, offs2, col2, xpb);
    // layer 2: gather-first, fused dual-GEMM single output
    kgather2raw<<<NN2 * 16 / 256, 256, 0, stream>>>(xpb, offs2, col2, aggb);
    kgcmm2<<<NN2 / 64, 256, 0, stream>>>(aggb, xpb,
                                         gcwh + 8192, gcwl + 8192, gcwh + 12288, gcwl + 12288,
                                         i2rB, xp2);

    // pools + readout
    kpoolg<<<GG, 256, 0, stream>>>(h2, xp2, pstat2 + (size_t)4 * 4096,
                                   bng + 4 * 64, bnb + 4 * 64, mbuf);
    kread<<<GG, 64, 0, stream>>>(mbuf, roW0, roB0, roW1, roB1, roW2, roB2, lW, lB, out);
}